// Round 1
// 1689.960 us; speedup vs baseline: 1.0424x; 1.0424x over previous
//
#include <hip/hip_runtime.h>
#include <hip/hip_bf16.h>

#define DOF 69
#define NL 6
#define NH 8
#define DMODEL 512
#define DFF 2048
#define HD 64
#define BB 8
#define TT 512
#define MTOK (BB*TT)   // 4096
#define EROWS 1040     // 2T-1 = 1023, padded
#define CATP 160       // padded concat pitch (K=138 rounded past 32-step reach)

// workspace layout (bytes) — 30.5 MB total
#define E_OFF     4096u
#define H_OFF     (512u*1024u)
#define HN_OFF    (H_OFF + 8u*1024u*1024u)
#define Q_OFF     (HN_OFF + 4u*1024u*1024u)
#define K_OFF     (Q_OFF + 4u*1024u*1024u)
#define V_OFF     (K_OFF + 4u*1024u*1024u)
#define WT_OFF    (V_OFF + 4u*1024u*1024u)   // 6 MB of bf16 B^T weights (per-layer reuse)

typedef const float* fp32p;
typedef __hip_bfloat16 bf16;
typedef const bf16* bf16p;
typedef __attribute__((ext_vector_type(8))) short bf16x8;  // 8 bf16 (4 VGPRs)
typedef __attribute__((ext_vector_type(4))) float f32x4;   // 4 fp32 acc

__device__ __forceinline__ float b2f(bf16 x){ return __bfloat162float(x); }

// ---------------- concat(x, mask) fp32 -> bf16, zero-padded to pitch CATP ----------------
__global__ __launch_bounds__(256)
void k_concat(fp32p x, fp32p mask, bf16* __restrict__ out){
    int idx = blockIdx.x*256 + threadIdx.x;
    if (idx >= MTOK*CATP) return;
    int row = idx / CATP, c = idx - row*CATP;
    float v = 0.f;
    if (c < DOF) v = x[(size_t)row*DOF + c];
    else if (c < 2*DOF) v = mask[(size_t)row*DOF + (c - DOF)];
    out[idx] = __float2bfloat16(v);
}

// ---------------- cast fp32 -> bf16 ----------------
__global__ __launch_bounds__(256)
void k_cast(const float* __restrict__ in, bf16* __restrict__ out){
    int idx = blockIdx.x*256 + threadIdx.x;
    if (idx >= MTOK*DMODEL) return;
    out[idx] = __float2bfloat16(in[idx]);
}

// ---------------- generic weight transpose-cast: W fp32 (K x N) -> WT bf16 (N x ldk) ----
// grid.x covers Kpad/32 (zero-fill k in [K,Kpad)), grid.y covers ceil(N/32)
__global__ __launch_bounds__(256)
void k_wt(fp32p W, int K, int N, bf16* __restrict__ WT, int ldk)
{
    __shared__ float s[32][33];
    const int k0 = blockIdx.x*32, n0 = blockIdx.y*32;
    const int c = threadIdx.x & 31, r0 = threadIdx.x >> 5;
    #pragma unroll
    for (int rr = r0; rr < 32; rr += 8) {
        int k = k0 + rr, n = n0 + c;
        s[rr][c] = (k < K && n < N) ? W[(size_t)k*N + n] : 0.f;
    }
    __syncthreads();
    #pragma unroll
    for (int rr = r0; rr < 32; rr += 8) {
        int n = n0 + rr;
        if (n < N) WT[(size_t)n*ldk + k0 + c] = __float2bfloat16(s[c][rr]);
    }
}

// ---------------- per-layer batched transpose: wq,wk,wv,wo,fw1,fw2 -> bf16 B^T ----------
// 3072 tile-blocks: [0,1024) = 4x 512x512 (wq,wk,wv,wo), [1024,2048) = fw1 512x2048,
// [2048,3072) = fw2 2048x512. All dims %32==0, no guards needed.
__global__ __launch_bounds__(256)
void k_wt6(fp32p wq, fp32p wk, fp32p wv, fp32p wo, fp32p fw1, fp32p fw2,
           bf16* __restrict__ qkvT, bf16* __restrict__ woT,
           bf16* __restrict__ f1T, bf16* __restrict__ f2T)
{
    __shared__ float s[32][33];
    const int t = blockIdx.x;
    fp32p src; bf16* dst; int N, ldk, k0, n0;
    if (t < 1024) {
        int seg = t >> 8, local = t & 255;
        N = 512; ldk = 512;
        k0 = (local & 15) * 32; n0 = (local >> 4) * 32;
        if      (seg == 0) { src = wq; dst = qkvT; }
        else if (seg == 1) { src = wk; dst = qkvT + 512*512; }
        else if (seg == 2) { src = wv; dst = qkvT + 2*512*512; }
        else               { src = wo; dst = woT; }
    } else if (t < 2048) {
        int local = t - 1024;
        N = 2048; ldk = 512;
        k0 = (local & 15) * 32; n0 = (local >> 4) * 32;
        src = fw1; dst = f1T;
    } else {
        int local = t - 2048;
        N = 512; ldk = 2048;
        k0 = (local >> 4) * 32; n0 = (local & 15) * 32;
        src = fw2; dst = f2T;
    }
    const int c = threadIdx.x & 31, r0 = threadIdx.x >> 5;
    #pragma unroll
    for (int rr = r0; rr < 32; rr += 8)
        s[rr][c] = src[(size_t)(k0+rr)*N + n0 + c];
    __syncthreads();
    #pragma unroll
    for (int rr = r0; rr < 32; rr += 8)
        dst[(size_t)(n0+rr)*ldk + k0 + c] = __float2bfloat16(s[c][rr]);
}

// ---------------- barrier-free MFMA GEMM, bf16 B^T operand ----------------
// C = epi(A @ B + bias); A bf16 (M x K) lda (lda%8==0, K%32==0),
// BT bf16 (N x ldk) = B transposed. Per-wave 64(M)x32(N) tile; block = 4 waves
// stacked in M (256 rows). No LDS, no barriers: A and B fragments are direct
// contiguous bf16x8 loads from L2-resident data. N-tail via col clamp + guard.
template<int PRELU, int RESID, int HASBIAS, int OUTF32>
__global__ __launch_bounds__(256)
void k_gemm(bf16p A, int lda,
            bf16p BT, int ldk,
            fp32p bias, size_t biasoff,
            fp32p alpha, size_t aidx,
            const float* __restrict__ resid,
            void* __restrict__ Cout, int ldc,
            int M, int N, int K)
{
    const int tid  = threadIdx.x;
    const int w    = tid >> 6;
    const int lane = tid & 63;
    const int qd   = lane >> 4;       // quad 0..3
    const int cl   = lane & 15;       // 0..15
    const int bm   = blockIdx.y * 256 + w * 64;
    const int bn   = blockIdx.x * 32;

    const int c0 = min(bn + cl,      N-1);
    const int c1 = min(bn + 16 + cl, N-1);
    const bf16* b0p = BT + (size_t)c0*ldk;
    const bf16* b1p = BT + (size_t)c1*ldk;

    f32x4 acc[4][2] = {};

    #pragma unroll 4
    for (int k0 = 0; k0 < K; k0 += 32) {
        const int koff = k0 + qd*8;
        bf16x8 bF0 = *(const bf16x8*)(b0p + koff);
        bf16x8 bF1 = *(const bf16x8*)(b1p + koff);
        #pragma unroll
        for (int mt = 0; mt < 4; ++mt) {
            bf16x8 aF = *(const bf16x8*)(A + (size_t)(bm + mt*16 + cl)*lda + koff);
            acc[mt][0] = __builtin_amdgcn_mfma_f32_16x16x32_bf16(aF, bF0, acc[mt][0], 0, 0, 0);
            acc[mt][1] = __builtin_amdgcn_mfma_f32_16x16x32_bf16(aF, bF1, acc[mt][1], 0, 0, 0);
        }
    }

    const float alp = PRELU ? alpha[aidx] : 0.f;
    #pragma unroll
    for (int nt = 0; nt < 2; ++nt) {
        int col = bn + nt*16 + cl;
        if (col < N) {
            float bv = HASBIAS ? bias[biasoff + col] : 0.f;
            #pragma unroll
            for (int mt = 0; mt < 4; ++mt) {
                #pragma unroll
                for (int r = 0; r < 4; ++r) {
                    int row = bm + mt*16 + qd*4 + r;
                    float c = acc[mt][nt][r] + bv;
                    if (PRELU) c = (c >= 0.f) ? c : alp*c;
                    if (RESID) c += resid[(size_t)row*ldc + col];
                    if (OUTF32) ((float*)Cout)[(size_t)row*ldc + col] = c;
                    else ((bf16*)Cout)[(size_t)row*ldc + col] = __float2bfloat16(c);
                }
            }
        }
    }
}

// ---------------- LayerNorm: fp32 in -> bf16 out ----------------
__global__ __launch_bounds__(256)
void k_layernorm(const float* __restrict__ x, fp32p g, fp32p b, bf16* __restrict__ out){
    __shared__ float red[256];
    const int row = blockIdx.x, tid = threadIdx.x;
    const float* xr = x + (size_t)row*DMODEL;
    float x0 = xr[tid], x1 = xr[tid+256];
    red[tid] = x0 + x1; __syncthreads();
    for (int o = 128; o > 0; o >>= 1) { if (tid < o) red[tid] += red[tid+o]; __syncthreads(); }
    float mean = red[0] * (1.f/DMODEL);
    __syncthreads();
    float d0 = x0 - mean, d1 = x1 - mean;
    red[tid] = d0*d0 + d1*d1; __syncthreads();
    for (int o = 128; o > 0; o >>= 1) { if (tid < o) red[tid] += red[tid+o]; __syncthreads(); }
    float inv = rsqrtf(red[0]*(1.f/DMODEL) + 1e-6f);
    out[(size_t)row*DMODEL + tid]     = __float2bfloat16(d0*inv*g[tid]     + b[tid]);
    out[(size_t)row*DMODEL + tid+256] = __float2bfloat16(d1*inv*g[tid+256] + b[tid+256]);
}

// ---------------- relative embedding E: (EROWS, HD) bf16, zero-padded ----------------
__global__ __launch_bounds__(64)
void k_relemb(fp32p w1, fp32p b1, fp32p a, fp32p w2, fp32p b2, bf16* __restrict__ Ebf){
    __shared__ float sH[DMODEL];
    const int r = blockIdx.x, tid = threadIdx.x;
    if (r >= 2*TT - 1) { Ebf[(size_t)r*HD + tid] = __float2bfloat16(0.f); return; }
    const float dist = (float)(r - (TT-1));
    const float al = a[0];
    for (int d = tid; d < DMODEL; d += 64) {
        float hv = dist * w1[d] + b1[d];
        sH[d] = (hv >= 0.f) ? hv : al*hv;
    }
    __syncthreads();
    float acc = b2[tid];
    for (int d = 0; d < DMODEL; ++d) acc += sH[d] * w2[(size_t)d*HD + tid];
    Ebf[(size_t)r*HD + tid] = __float2bfloat16(acc);
}

// ---------------- MFMA flash attention with relative-position skew ----------------
__global__ __launch_bounds__(256)
void k_attn(bf16p q, bf16p k, bf16p v, bf16p Ebf, bf16* __restrict__ o)
{
    __shared__ bf16  sVT[64][68];        // V^T tile: [d][j_local]
    __shared__ float sQE[4][16][100];    // per-wave qe tile
    __shared__ bf16  sP[4][16][68];      // per-wave P tile

    const int bid  = blockIdx.x;
    const int itile = bid & 7;
    const int h    = (bid >> 3) & 7;
    const int b    = bid >> 6;
    const int tid  = threadIdx.x;
    const int w    = tid >> 6;
    const int lane = tid & 63;
    const int qd   = lane >> 4;
    const int cl   = lane & 15;

    const int I = itile*64 + w*16;
    const size_t bh = ((size_t)b*TT)*DMODEL + (size_t)h*HD;

    bf16x8 qa0, qa1;
    {
        const bf16* qrow = q + bh + (size_t)(I + cl)*DMODEL;
        qa0 = *(const bf16x8*)(qrow + qd*8);
        qa1 = *(const bf16x8*)(qrow + 32 + qd*8);
    }

    f32x4 Oacc[4] = {};
    float m_i[4], l_i[4];
    #pragma unroll
    for (int r = 0; r < 4; ++r) { m_i[r] = -1e30f; l_i[r] = 0.f; }
    const float scale = 0.125f;

    for (int J = 0; J < TT; J += 64) {
        {
            int j = tid >> 2, dc = (tid & 3) * 16;
            const bf16* vrow = v + bh + (size_t)(J + j)*DMODEL + dc;
            bf16x8 v0 = *(const bf16x8*)(vrow);
            bf16x8 v1 = *(const bf16x8*)(vrow + 8);
            #pragma unroll
            for (int e = 0; e < 8; ++e) sVT[dc + e][j]     = ((const bf16*)&v0)[e];
            #pragma unroll
            for (int e = 0; e < 8; ++e) sVT[dc + 8 + e][j] = ((const bf16*)&v1)[e];
        }
        __syncthreads();

        f32x4 S[4];
        #pragma unroll
        for (int js = 0; js < 4; ++js) {
            const bf16* krow = k + bh + (size_t)(J + js*16 + cl)*DMODEL;
            bf16x8 kb0 = *(const bf16x8*)(krow + qd*8);
            bf16x8 kb1 = *(const bf16x8*)(krow + 32 + qd*8);
            f32x4 acc = {};
            acc = __builtin_amdgcn_mfma_f32_16x16x32_bf16(qa0, kb0, acc, 0, 0, 0);
            acc = __builtin_amdgcn_mfma_f32_16x16x32_bf16(qa1, kb1, acc, 0, 0, 0);
            S[js] = acc;
        }

        const int rbase = J - I + 496;
        #pragma unroll
        for (int nt = 0; nt < 6; ++nt) {
            const bf16* erow = Ebf + (size_t)(rbase + nt*16 + cl)*HD;
            bf16x8 eb0 = *(const bf16x8*)(erow + qd*8);
            bf16x8 eb1 = *(const bf16x8*)(erow + 32 + qd*8);
            f32x4 acc = {};
            acc = __builtin_amdgcn_mfma_f32_16x16x32_bf16(qa0, eb0, acc, 0, 0, 0);
            acc = __builtin_amdgcn_mfma_f32_16x16x32_bf16(qa1, eb1, acc, 0, 0, 0);
            #pragma unroll
            for (int r = 0; r < 4; ++r)
                sQE[w][qd*4 + r][nt*16 + cl] = acc[r];
        }

        float mnew[4];
        #pragma unroll
        for (int r = 0; r < 4; ++r) mnew[r] = m_i[r];
        #pragma unroll
        for (int js = 0; js < 4; ++js) {
            #pragma unroll
            for (int r = 0; r < 4; ++r) {
                int idx = js*16 + cl - (qd*4 + r) + 15;
                float s = S[js][r] + sQE[w][qd*4 + r][idx];
                S[js][r] = s;
                mnew[r] = fmaxf(mnew[r], s);
            }
        }
        #pragma unroll
        for (int r = 0; r < 4; ++r) {
            float mv = mnew[r];
            mv = fmaxf(mv, __shfl_xor(mv, 1));
            mv = fmaxf(mv, __shfl_xor(mv, 2));
            mv = fmaxf(mv, __shfl_xor(mv, 4));
            mv = fmaxf(mv, __shfl_xor(mv, 8));
            mnew[r] = mv;
        }
        float alpha[4], rsum[4];
        #pragma unroll
        for (int r = 0; r < 4; ++r) {
            alpha[r] = expf((m_i[r] - mnew[r]) * scale);
            m_i[r] = mnew[r];
            rsum[r] = 0.f;
        }
        #pragma unroll
        for (int js = 0; js < 4; ++js) {
            #pragma unroll
            for (int r = 0; r < 4; ++r) {
                float p = expf((S[js][r] - m_i[r]) * scale);
                rsum[r] += p;
                sP[w][qd*4 + r][js*16 + cl] = __float2bfloat16(p);
            }
        }
        #pragma unroll
        for (int r = 0; r < 4; ++r) {
            float sv = rsum[r];
            sv += __shfl_xor(sv, 1);
            sv += __shfl_xor(sv, 2);
            sv += __shfl_xor(sv, 4);
            sv += __shfl_xor(sv, 8);
            l_i[r] = l_i[r]*alpha[r] + sv;
        }

        bf16x8 pa0, pa1;
        {
            const bf16* pr = &sP[w][cl][0];
            #pragma unroll
            for (int e = 0; e < 8; ++e) ((short*)&pa0)[e] = ((const short*)pr)[qd*8 + e];
            #pragma unroll
            for (int e = 0; e < 8; ++e) ((short*)&pa1)[e] = ((const short*)pr)[32 + qd*8 + e];
        }

        #pragma unroll
        for (int nt = 0; nt < 4; ++nt) {
            #pragma unroll
            for (int r = 0; r < 4; ++r) Oacc[nt][r] *= alpha[r];
            bf16x8 vb0, vb1;
            const bf16* vr = &sVT[nt*16 + cl][0];
            #pragma unroll
            for (int e = 0; e < 8; ++e) ((short*)&vb0)[e] = ((const short*)vr)[qd*8 + e];
            #pragma unroll
            for (int e = 0; e < 8; ++e) ((short*)&vb1)[e] = ((const short*)vr)[32 + qd*8 + e];
            Oacc[nt] = __builtin_amdgcn_mfma_f32_16x16x32_bf16(pa0, vb0, Oacc[nt], 0, 0, 0);
            Oacc[nt] = __builtin_amdgcn_mfma_f32_16x16x32_bf16(pa1, vb1, Oacc[nt], 0, 0, 0);
        }
        __syncthreads();
    }

    #pragma unroll
    for (int nt = 0; nt < 4; ++nt) {
        #pragma unroll
        for (int r = 0; r < 4; ++r) {
            int row = qd*4 + r;
            float val = Oacc[nt][r] / l_i[r];
            o[bh + (size_t)(I + row)*DMODEL + nt*16 + cl] = __float2bfloat16(val);
        }
    }
}

// ---------------- output split + sigmoid (fp32 out) ----------------
__global__ __launch_bounds__(256)
void k_out(const float* __restrict__ y, float* __restrict__ out){
    int idx = blockIdx.x*256 + threadIdx.x;
    if (idx >= MTOK*73) return;
    int row = idx / 73, c = idx - row*73;
    float val = y[idx];
    if (c < DOF) out[(size_t)row*DOF + c] = val;
    else out[(size_t)MTOK*DOF + row*4 + (c-DOF)] = 1.f/(1.f + expf(-val));
}

extern "C" void kernel_launch(void* const* d_in, const int* in_sizes, int n_in,
                              void* d_out, int out_size, void* d_ws, size_t ws_size,
                              hipStream_t stream)
{
    fp32p x      = (fp32p)d_in[0];
    fp32p mask   = (fp32p)d_in[1];
    fp32p enc_w1 = (fp32p)d_in[2];
    fp32p enc_b1 = (fp32p)d_in[3];
    fp32p enc_a1 = (fp32p)d_in[4];
    fp32p enc_w2 = (fp32p)d_in[5];
    fp32p enc_b2 = (fp32p)d_in[6];
    fp32p enc_a2 = (fp32p)d_in[7];
    fp32p rel_w1 = (fp32p)d_in[8];
    fp32p rel_b1 = (fp32p)d_in[9];
    fp32p rel_a  = (fp32p)d_in[10];
    fp32p rel_w2 = (fp32p)d_in[11];
    fp32p rel_b2 = (fp32p)d_in[12];
    fp32p ln_g   = (fp32p)d_in[13];
    fp32p ln_b   = (fp32p)d_in[14];
    fp32p wq     = (fp32p)d_in[15];
    fp32p bq     = (fp32p)d_in[16];
    fp32p wk     = (fp32p)d_in[17];
    fp32p bk     = (fp32p)d_in[18];
    fp32p wv     = (fp32p)d_in[19];
    fp32p bv     = (fp32p)d_in[20];
    fp32p wo     = (fp32p)d_in[21];
    fp32p bo     = (fp32p)d_in[22];
    fp32p fw1    = (fp32p)d_in[23];
    fp32p fb1    = (fp32p)d_in[24];
    fp32p fa     = (fp32p)d_in[25];
    fp32p fw2    = (fp32p)d_in[26];
    fp32p fb2    = (fp32p)d_in[27];
    fp32p dec_w1 = (fp32p)d_in[28];
    fp32p dec_b1 = (fp32p)d_in[29];
    fp32p dec_a  = (fp32p)d_in[30];
    fp32p dec_w2 = (fp32p)d_in[31];
    fp32p dec_b2 = (fp32p)d_in[32];

    char* wsb = (char*)d_ws;
    bf16*  Ebf = (bf16*)(wsb + E_OFF);
    float* h   = (float*)(wsb + H_OFF);
    bf16*  hn  = (bf16*)(wsb + HN_OFF);
    bf16*  q   = (bf16*)(wsb + Q_OFF);
    bf16*  k   = (bf16*)(wsb + K_OFF);
    bf16*  v   = (bf16*)(wsb + V_OFF);
    bf16*  cat = q;            // encoder scratch (pitch CATP, 1.31 MB)
    bf16*  mid = q;            // ffn half, spans q+k slots (8 MB)
    bf16*  hb  = v;            // decoder bf16 cast of h
    float* y   = (float*)q;    // decoder logits fp32

    // transposed bf16 weights (per-layer reuse; enc/dec alias the same region)
    bf16* qkvT = (bf16*)(wsb + WT_OFF);          // 1536 x 512  (wq^T | wk^T | wv^T)
    bf16* woT  = qkvT + 3*512*512;               // 512 x 512
    bf16* f1T  = woT  + 512*512;                 // 2048 x 512
    bf16* f2T  = f1T  + 2048*512;                // 512 x 2048
    bf16* enc1T = qkvT;                          // 512 x 160 (zero-padded K)
    bf16* enc2T = qkvT + 512*160;                // 512 x 512
    bf16* dec1T = qkvT;                          // 512 x 512
    bf16* dec2T = qkvT + 512*512;                // 73 x 512

    dim3 gD(DMODEL/32, MTOK/256);    // 16 x 16 = 256 blocks
    dim3 gF(1024/32, MTOK/256);      // 32 x 16 = 512 blocks

    // encoder weight transposes + encoder
    k_wt<<<dim3(5,16), 256, 0, stream>>>(enc_w1, 2*DOF, DMODEL, enc1T, CATP);   // Kpad=160
    k_wt<<<dim3(16,16), 256, 0, stream>>>(enc_w2, DMODEL, DMODEL, enc2T, DMODEL);
    k_concat<<<(MTOK*CATP+255)/256, 256, 0, stream>>>(x, mask, cat);
    k_gemm<1,0,1,0><<<gD,256,0,stream>>>(cat, CATP, enc1T, CATP, enc_b1, 0, enc_a1, 0, nullptr, hn, DMODEL, MTOK, DMODEL, CATP);
    k_gemm<1,0,1,1><<<gD,256,0,stream>>>(hn, DMODEL, enc2T, DMODEL, enc_b2, 0, enc_a2, 0, nullptr, h, DMODEL, MTOK, DMODEL, DMODEL);
    k_relemb<<<EROWS, 64, 0, stream>>>(rel_w1, rel_b1, rel_a, rel_w2, rel_b2, Ebf);

    for (int l = 0; l < NL; ++l) {
        size_t oW  = (size_t)l*DMODEL*DMODEL;
        size_t oB  = (size_t)l*DMODEL;
        size_t oF1 = (size_t)l*DMODEL*DFF;
        size_t oBF1= (size_t)l*DFF;
        size_t oF2 = (size_t)l*DFF*DMODEL;

        k_wt6<<<3072, 256, 0, stream>>>(wq+oW, wk+oW, wv+oW, wo+oW, fw1+oF1, fw2+oF2,
                                        qkvT, woT, f1T, f2T);
        k_layernorm<<<MTOK, 256, 0, stream>>>(h, ln_g, ln_b, hn);
        k_gemm<0,0,1,0><<<gD,256,0,stream>>>(hn, DMODEL, qkvT,            DMODEL, bq, oB, nullptr, 0, nullptr, q, DMODEL, MTOK, DMODEL, DMODEL);
        k_gemm<0,0,1,0><<<gD,256,0,stream>>>(hn, DMODEL, qkvT + 512*512,  DMODEL, bk, oB, nullptr, 0, nullptr, k, DMODEL, MTOK, DMODEL, DMODEL);
        k_gemm<0,0,1,0><<<gD,256,0,stream>>>(hn, DMODEL, qkvT + 2*512*512,DMODEL, bv, oB, nullptr, 0, nullptr, v, DMODEL, MTOK, DMODEL, DMODEL);
        k_attn<<<BB*NH*(TT/64), 256, 0, stream>>>(q, k, v, Ebf, hn);
        k_gemm<0,1,1,1><<<gD,256,0,stream>>>(hn, DMODEL, woT, DMODEL, bo, oB, nullptr, 0, h, h, DMODEL, MTOK, DMODEL, DMODEL);
        k_layernorm<<<MTOK, 256, 0, stream>>>(h, ln_g, ln_b, hn);
        k_gemm<1,0,1,0><<<gF,256,0,stream>>>(hn, DMODEL, f1T,            DMODEL, fb1, oBF1,      fa, (size_t)l, nullptr, mid, 1024, MTOK, 1024, DMODEL);
        k_gemm<0,1,1,1><<<gD,256,0,stream>>>(mid, 1024, f2T,             DFF,    fb2, oB, nullptr, 0, h, h, DMODEL, MTOK, DMODEL, 1024);
        k_gemm<1,0,1,0><<<gF,256,0,stream>>>(hn, DMODEL, f1T + 1024*512, DMODEL, fb1, oBF1+1024, fa, (size_t)l, nullptr, mid, 1024, MTOK, 1024, DMODEL);
        k_gemm<0,1,0,1><<<gD,256,0,stream>>>(mid, 1024, f2T + 1024,      DFF,    nullptr, 0, nullptr, 0, h, h, DMODEL, MTOK, DMODEL, 1024);
    }

    // decoder weight transposes + decoder
    k_wt<<<dim3(16,16), 256, 0, stream>>>(dec_w1, DMODEL, DMODEL, dec1T, DMODEL);
    k_wt<<<dim3(16,3), 256, 0, stream>>>(dec_w2, DMODEL, DOF+4, dec2T, DMODEL);
    k_cast<<<(MTOK*DMODEL+255)/256, 256, 0, stream>>>(h, hb);
    k_gemm<1,0,1,0><<<gD,256,0,stream>>>(hb, DMODEL, dec1T, DMODEL, dec_b1, 0, dec_a, 0, nullptr, hn, DMODEL, MTOK, DMODEL, DMODEL);
    {
        dim3 g2((DOF+4+31)/32, MTOK/256);   // 3 x 16
        k_gemm<0,0,1,1><<<g2,256,0,stream>>>(hn, DMODEL, dec2T, DMODEL, dec_b2, 0, nullptr, 0, nullptr, y, DOF+4, MTOK, DOF+4, DMODEL);
    }
    k_out<<<(MTOK*73+255)/256, 256, 0, stream>>>(y, (float*)d_out);
}

// Round 2
// 1674.779 us; speedup vs baseline: 1.0518x; 1.0091x over previous
//
#include <hip/hip_runtime.h>
#include <hip/hip_bf16.h>

#define DOF 69
#define NL 6
#define NH 8
#define DMODEL 512
#define DFF 2048
#define HD 64
#define BB 8
#define TT 512
#define MTOK (BB*TT)   // 4096
#define EROWS 1040     // 2T-1 = 1023, padded
#define CATP 160       // padded concat pitch (K=138 rounded past 32-step reach)
#define QKVP 1536      // fused qkv row pitch

// workspace layout (bytes) — 34.5 MB total
#define E_OFF     4096u
#define H_OFF     (512u*1024u)
#define HN_OFF    (H_OFF + 8u*1024u*1024u)
#define QKV_OFF   (HN_OFF + 4u*1024u*1024u)      // 16 MB region: qkv (12MB) / mid (16MB) / scratch
#define WT_OFF    (QKV_OFF + 16u*1024u*1024u)    // 6 MB of bf16 B^T weights (per-layer reuse)

typedef const float* fp32p;
typedef __hip_bfloat16 bf16;
typedef const bf16* bf16p;
typedef __attribute__((ext_vector_type(8))) short bf16x8;  // 8 bf16 (4 VGPRs)
typedef __attribute__((ext_vector_type(4))) float f32x4;   // 4 fp32 acc

__device__ __forceinline__ float b2f(bf16 x){ return __bfloat162float(x); }

// ---------------- concat(x, mask) fp32 -> bf16, zero-padded to pitch CATP ----------------
__global__ __launch_bounds__(256)
void k_concat(fp32p x, fp32p mask, bf16* __restrict__ out){
    int idx = blockIdx.x*256 + threadIdx.x;
    if (idx >= MTOK*CATP) return;
    int row = idx / CATP, c = idx - row*CATP;
    float v = 0.f;
    if (c < DOF) v = x[(size_t)row*DOF + c];
    else if (c < 2*DOF) v = mask[(size_t)row*DOF + (c - DOF)];
    out[idx] = __float2bfloat16(v);
}

// ---------------- cast fp32 -> bf16 ----------------
__global__ __launch_bounds__(256)
void k_cast(const float* __restrict__ in, bf16* __restrict__ out){
    int idx = blockIdx.x*256 + threadIdx.x;
    if (idx >= MTOK*DMODEL) return;
    out[idx] = __float2bfloat16(in[idx]);
}

// ---------------- generic weight transpose-cast: W fp32 (K x N) -> WT bf16 (N x ldk) ----
__global__ __launch_bounds__(256)
void k_wt(fp32p W, int K, int N, bf16* __restrict__ WT, int ldk)
{
    __shared__ float s[32][33];
    const int k0 = blockIdx.x*32, n0 = blockIdx.y*32;
    const int c = threadIdx.x & 31, r0 = threadIdx.x >> 5;
    #pragma unroll
    for (int rr = r0; rr < 32; rr += 8) {
        int k = k0 + rr, n = n0 + c;
        s[rr][c] = (k < K && n < N) ? W[(size_t)k*N + n] : 0.f;
    }
    __syncthreads();
    #pragma unroll
    for (int rr = r0; rr < 32; rr += 8) {
        int n = n0 + rr;
        if (n < N) WT[(size_t)n*ldk + k0 + c] = __float2bfloat16(s[c][rr]);
    }
}

// ---------------- per-layer batched transpose: wq,wk,wv,wo,fw1,fw2 -> bf16 B^T ----------
__global__ __launch_bounds__(256)
void k_wt6(fp32p wq, fp32p wk, fp32p wv, fp32p wo, fp32p fw1, fp32p fw2,
           bf16* __restrict__ qkvT, bf16* __restrict__ woT,
           bf16* __restrict__ f1T, bf16* __restrict__ f2T)
{
    __shared__ float s[32][33];
    const int t = blockIdx.x;
    fp32p src; bf16* dst; int N, ldk, k0, n0;
    if (t < 1024) {
        int seg = t >> 8, local = t & 255;
        N = 512; ldk = 512;
        k0 = (local & 15) * 32; n0 = (local >> 4) * 32;
        if      (seg == 0) { src = wq; dst = qkvT; }
        else if (seg == 1) { src = wk; dst = qkvT + 512*512; }
        else if (seg == 2) { src = wv; dst = qkvT + 2*512*512; }
        else               { src = wo; dst = woT; }
    } else if (t < 2048) {
        int local = t - 1024;
        N = 2048; ldk = 512;
        k0 = (local & 15) * 32; n0 = (local >> 4) * 32;
        src = fw1; dst = f1T;
    } else {
        int local = t - 2048;
        N = 512; ldk = 2048;
        k0 = (local >> 4) * 32; n0 = (local & 15) * 32;
        src = fw2; dst = f2T;
    }
    const int c = threadIdx.x & 31, r0 = threadIdx.x >> 5;
    #pragma unroll
    for (int rr = r0; rr < 32; rr += 8)
        s[rr][c] = src[(size_t)(k0+rr)*N + n0 + c];
    __syncthreads();
    #pragma unroll
    for (int rr = r0; rr < 32; rr += 8)
        dst[(size_t)(n0+rr)*ldk + k0 + c] = __float2bfloat16(s[c][rr]);
}

// ---------------- barrier-free MFMA GEMM, bf16 B^T operand, K-pipelined ----------------
// C = epi(A @ B + bias); A bf16 (M x K) lda; BT bf16 (N x ldk). Per-wave MT*16(M)x32(N)
// tile; block = 4 waves stacked in M (MT*64 rows). No LDS, no barriers. Explicit
// double-buffered K-step fragment prefetch keeps ~6 loads in flight under each MFMA
// cluster. BIAS: 0=none, 1=bias[], 3=segment-select of {bias,bias2,bias3} by col/512.
template<int PRELU, int RESID, int BIAS, int OUTF32, int MT>
__global__ __launch_bounds__(256)
void k_gemm(bf16p A, int lda,
            bf16p BT, int ldk,
            fp32p bias, fp32p bias2, fp32p bias3, size_t biasoff,
            fp32p alpha, size_t aidx,
            const float* __restrict__ resid,
            void* __restrict__ Cout, int ldc,
            int M, int N, int K)
{
    const int tid  = threadIdx.x;
    const int w    = tid >> 6;
    const int lane = tid & 63;
    const int qd   = lane >> 4;       // quad 0..3
    const int cl   = lane & 15;       // 0..15
    const int bm   = blockIdx.y * (MT*64) + w * (MT*16);
    const int bn   = blockIdx.x * 32;

    const int c0 = min(bn + cl,      N-1);
    const int c1 = min(bn + 16 + cl, N-1);
    const bf16* b0p = BT + (size_t)c0*ldk;
    const bf16* b1p = BT + (size_t)c1*ldk;
    const bf16* aptr[MT];
    #pragma unroll
    for (int mt = 0; mt < MT; ++mt)
        aptr[mt] = A + (size_t)(bm + mt*16 + cl)*lda;

    f32x4 acc[MT][2] = {};
    const int qoff = qd*8;

    bf16x8 aX[MT], aY[MT], bX0, bX1, bY0, bY1;
    bX0 = *(const bf16x8*)(b0p + qoff);
    bX1 = *(const bf16x8*)(b1p + qoff);
    #pragma unroll
    for (int mt = 0; mt < MT; ++mt) aX[mt] = *(const bf16x8*)(aptr[mt] + qoff);

    int k0 = 0;
    for (; k0 + 64 <= K; k0 += 64) {
        const int k1 = k0 + 32 + qoff;
        bY0 = *(const bf16x8*)(b0p + k1);
        bY1 = *(const bf16x8*)(b1p + k1);
        #pragma unroll
        for (int mt = 0; mt < MT; ++mt) aY[mt] = *(const bf16x8*)(aptr[mt] + k1);
        #pragma unroll
        for (int mt = 0; mt < MT; ++mt) {
            acc[mt][0] = __builtin_amdgcn_mfma_f32_16x16x32_bf16(aX[mt], bX0, acc[mt][0], 0, 0, 0);
            acc[mt][1] = __builtin_amdgcn_mfma_f32_16x16x32_bf16(aX[mt], bX1, acc[mt][1], 0, 0, 0);
        }
        if (k0 + 64 < K) {
            const int k2 = k0 + 64 + qoff;
            bX0 = *(const bf16x8*)(b0p + k2);
            bX1 = *(const bf16x8*)(b1p + k2);
            #pragma unroll
            for (int mt = 0; mt < MT; ++mt) aX[mt] = *(const bf16x8*)(aptr[mt] + k2);
        }
        #pragma unroll
        for (int mt = 0; mt < MT; ++mt) {
            acc[mt][0] = __builtin_amdgcn_mfma_f32_16x16x32_bf16(aY[mt], bY0, acc[mt][0], 0, 0, 0);
            acc[mt][1] = __builtin_amdgcn_mfma_f32_16x16x32_bf16(aY[mt], bY1, acc[mt][1], 0, 0, 0);
        }
    }
    if (k0 < K) {   // K%64==32 tail (aX holds fragments at k0)
        #pragma unroll
        for (int mt = 0; mt < MT; ++mt) {
            acc[mt][0] = __builtin_amdgcn_mfma_f32_16x16x32_bf16(aX[mt], bX0, acc[mt][0], 0, 0, 0);
            acc[mt][1] = __builtin_amdgcn_mfma_f32_16x16x32_bf16(aX[mt], bX1, acc[mt][1], 0, 0, 0);
        }
    }

    const float alp = PRELU ? alpha[aidx] : 0.f;
    fp32p bsel = bias;
    if (BIAS == 3) bsel = (bn < 512) ? bias : ((bn < 1024) ? bias2 : bias3);
    #pragma unroll
    for (int nt = 0; nt < 2; ++nt) {
        int col = bn + nt*16 + cl;
        if (col < N) {
            float bv = 0.f;
            if (BIAS == 1) bv = bsel[biasoff + col];
            if (BIAS == 3) bv = bsel[biasoff + (col & 511)];
            #pragma unroll
            for (int mt = 0; mt < MT; ++mt) {
                #pragma unroll
                for (int r = 0; r < 4; ++r) {
                    int row = bm + mt*16 + qd*4 + r;
                    float c = acc[mt][nt][r] + bv;
                    if (PRELU) c = (c >= 0.f) ? c : alp*c;
                    if (RESID) c += resid[(size_t)row*ldc + col];
                    if (OUTF32) ((float*)Cout)[(size_t)row*ldc + col] = c;
                    else ((bf16*)Cout)[(size_t)row*ldc + col] = __float2bfloat16(c);
                }
            }
        }
    }
}

// ---------------- LayerNorm: fp32 in -> bf16 out ----------------
__global__ __launch_bounds__(256)
void k_layernorm(const float* __restrict__ x, fp32p g, fp32p b, bf16* __restrict__ out){
    __shared__ float red[256];
    const int row = blockIdx.x, tid = threadIdx.x;
    const float* xr = x + (size_t)row*DMODEL;
    float x0 = xr[tid], x1 = xr[tid+256];
    red[tid] = x0 + x1; __syncthreads();
    for (int o = 128; o > 0; o >>= 1) { if (tid < o) red[tid] += red[tid+o]; __syncthreads(); }
    float mean = red[0] * (1.f/DMODEL);
    __syncthreads();
    float d0 = x0 - mean, d1 = x1 - mean;
    red[tid] = d0*d0 + d1*d1; __syncthreads();
    for (int o = 128; o > 0; o >>= 1) { if (tid < o) red[tid] += red[tid+o]; __syncthreads(); }
    float inv = rsqrtf(red[0]*(1.f/DMODEL) + 1e-6f);
    out[(size_t)row*DMODEL + tid]     = __float2bfloat16(d0*inv*g[tid]     + b[tid]);
    out[(size_t)row*DMODEL + tid+256] = __float2bfloat16(d1*inv*g[tid+256] + b[tid+256]);
}

// ---------------- relative embedding E: (EROWS, HD) bf16, zero-padded ----------------
__global__ __launch_bounds__(64)
void k_relemb(fp32p w1, fp32p b1, fp32p a, fp32p w2, fp32p b2, bf16* __restrict__ Ebf){
    __shared__ float sH[DMODEL];
    const int r = blockIdx.x, tid = threadIdx.x;
    if (r >= 2*TT - 1) { Ebf[(size_t)r*HD + tid] = __float2bfloat16(0.f); return; }
    const float dist = (float)(r - (TT-1));
    const float al = a[0];
    for (int d = tid; d < DMODEL; d += 64) {
        float hv = dist * w1[d] + b1[d];
        sH[d] = (hv >= 0.f) ? hv : al*hv;
    }
    __syncthreads();
    float acc = b2[tid];
    for (int d = 0; d < DMODEL; ++d) acc += sH[d] * w2[(size_t)d*HD + tid];
    Ebf[(size_t)r*HD + tid] = __float2bfloat16(acc);
}

// ---------------- MFMA flash attention with relative-position skew ----------------
// q,k,v have row pitch qp (fused qkv buffer); output o has pitch DMODEL.
__global__ __launch_bounds__(256)
void k_attn(bf16p q, bf16p k, bf16p v, bf16p Ebf, bf16* __restrict__ o, int qp)
{
    __shared__ bf16  sVT[64][68];        // V^T tile: [d][j_local]
    __shared__ float sQE[4][16][100];    // per-wave qe tile
    __shared__ bf16  sP[4][16][68];      // per-wave P tile

    const int bid  = blockIdx.x;
    const int itile = bid & 7;
    const int h    = (bid >> 3) & 7;
    const int b    = bid >> 6;
    const int tid  = threadIdx.x;
    const int w    = tid >> 6;
    const int lane = tid & 63;
    const int qd   = lane >> 4;
    const int cl   = lane & 15;

    const int I = itile*64 + w*16;
    const size_t bh = ((size_t)b*TT)*qp + (size_t)h*HD;
    const size_t bo = ((size_t)b*TT)*DMODEL + (size_t)h*HD;

    bf16x8 qa0, qa1;
    {
        const bf16* qrow = q + bh + (size_t)(I + cl)*qp;
        qa0 = *(const bf16x8*)(qrow + qd*8);
        qa1 = *(const bf16x8*)(qrow + 32 + qd*8);
    }

    f32x4 Oacc[4] = {};
    float m_i[4], l_i[4];
    #pragma unroll
    for (int r = 0; r < 4; ++r) { m_i[r] = -1e30f; l_i[r] = 0.f; }
    const float scale = 0.125f;

    for (int J = 0; J < TT; J += 64) {
        {
            int j = tid >> 2, dc = (tid & 3) * 16;
            const bf16* vrow = v + bh + (size_t)(J + j)*qp + dc;
            bf16x8 v0 = *(const bf16x8*)(vrow);
            bf16x8 v1 = *(const bf16x8*)(vrow + 8);
            #pragma unroll
            for (int e = 0; e < 8; ++e) sVT[dc + e][j]     = ((const bf16*)&v0)[e];
            #pragma unroll
            for (int e = 0; e < 8; ++e) sVT[dc + 8 + e][j] = ((const bf16*)&v1)[e];
        }
        __syncthreads();

        f32x4 S[4];
        #pragma unroll
        for (int js = 0; js < 4; ++js) {
            const bf16* krow = k + bh + (size_t)(J + js*16 + cl)*qp;
            bf16x8 kb0 = *(const bf16x8*)(krow + qd*8);
            bf16x8 kb1 = *(const bf16x8*)(krow + 32 + qd*8);
            f32x4 acc = {};
            acc = __builtin_amdgcn_mfma_f32_16x16x32_bf16(qa0, kb0, acc, 0, 0, 0);
            acc = __builtin_amdgcn_mfma_f32_16x16x32_bf16(qa1, kb1, acc, 0, 0, 0);
            S[js] = acc;
        }

        const int rbase = J - I + 496;
        #pragma unroll
        for (int nt = 0; nt < 6; ++nt) {
            const bf16* erow = Ebf + (size_t)(rbase + nt*16 + cl)*HD;
            bf16x8 eb0 = *(const bf16x8*)(erow + qd*8);
            bf16x8 eb1 = *(const bf16x8*)(erow + 32 + qd*8);
            f32x4 acc = {};
            acc = __builtin_amdgcn_mfma_f32_16x16x32_bf16(qa0, eb0, acc, 0, 0, 0);
            acc = __builtin_amdgcn_mfma_f32_16x16x32_bf16(qa1, eb1, acc, 0, 0, 0);
            #pragma unroll
            for (int r = 0; r < 4; ++r)
                sQE[w][qd*4 + r][nt*16 + cl] = acc[r];
        }

        float mnew[4];
        #pragma unroll
        for (int r = 0; r < 4; ++r) mnew[r] = m_i[r];
        #pragma unroll
        for (int js = 0; js < 4; ++js) {
            #pragma unroll
            for (int r = 0; r < 4; ++r) {
                int idx = js*16 + cl - (qd*4 + r) + 15;
                float s = S[js][r] + sQE[w][qd*4 + r][idx];
                S[js][r] = s;
                mnew[r] = fmaxf(mnew[r], s);
            }
        }
        #pragma unroll
        for (int r = 0; r < 4; ++r) {
            float mv = mnew[r];
            mv = fmaxf(mv, __shfl_xor(mv, 1));
            mv = fmaxf(mv, __shfl_xor(mv, 2));
            mv = fmaxf(mv, __shfl_xor(mv, 4));
            mv = fmaxf(mv, __shfl_xor(mv, 8));
            mnew[r] = mv;
        }
        float alpha[4], rsum[4];
        #pragma unroll
        for (int r = 0; r < 4; ++r) {
            alpha[r] = expf((m_i[r] - mnew[r]) * scale);
            m_i[r] = mnew[r];
            rsum[r] = 0.f;
        }
        #pragma unroll
        for (int js = 0; js < 4; ++js) {
            #pragma unroll
            for (int r = 0; r < 4; ++r) {
                float p = expf((S[js][r] - m_i[r]) * scale);
                rsum[r] += p;
                sP[w][qd*4 + r][js*16 + cl] = __float2bfloat16(p);
            }
        }
        #pragma unroll
        for (int r = 0; r < 4; ++r) {
            float sv = rsum[r];
            sv += __shfl_xor(sv, 1);
            sv += __shfl_xor(sv, 2);
            sv += __shfl_xor(sv, 4);
            sv += __shfl_xor(sv, 8);
            l_i[r] = l_i[r]*alpha[r] + sv;
        }

        bf16x8 pa0, pa1;
        {
            const bf16* pr = &sP[w][cl][0];
            #pragma unroll
            for (int e = 0; e < 8; ++e) ((short*)&pa0)[e] = ((const short*)pr)[qd*8 + e];
            #pragma unroll
            for (int e = 0; e < 8; ++e) ((short*)&pa1)[e] = ((const short*)pr)[32 + qd*8 + e];
        }

        #pragma unroll
        for (int nt = 0; nt < 4; ++nt) {
            #pragma unroll
            for (int r = 0; r < 4; ++r) Oacc[nt][r] *= alpha[r];
            bf16x8 vb0, vb1;
            const bf16* vr = &sVT[nt*16 + cl][0];
            #pragma unroll
            for (int e = 0; e < 8; ++e) ((short*)&vb0)[e] = ((const short*)vr)[qd*8 + e];
            #pragma unroll
            for (int e = 0; e < 8; ++e) ((short*)&vb1)[e] = ((const short*)vr)[32 + qd*8 + e];
            Oacc[nt] = __builtin_amdgcn_mfma_f32_16x16x32_bf16(pa0, vb0, Oacc[nt], 0, 0, 0);
            Oacc[nt] = __builtin_amdgcn_mfma_f32_16x16x32_bf16(pa1, vb1, Oacc[nt], 0, 0, 0);
        }
        __syncthreads();
    }

    #pragma unroll
    for (int nt = 0; nt < 4; ++nt) {
        #pragma unroll
        for (int r = 0; r < 4; ++r) {
            int row = qd*4 + r;
            float val = Oacc[nt][r] / l_i[r];
            o[bo + (size_t)(I + row)*DMODEL + nt*16 + cl] = __float2bfloat16(val);
        }
    }
}

// ---------------- output split + sigmoid (fp32 out) ----------------
__global__ __launch_bounds__(256)
void k_out(const float* __restrict__ y, float* __restrict__ out){
    int idx = blockIdx.x*256 + threadIdx.x;
    if (idx >= MTOK*73) return;
    int row = idx / 73, c = idx - row*73;
    float val = y[idx];
    if (c < DOF) out[(size_t)row*DOF + c] = val;
    else out[(size_t)MTOK*DOF + row*4 + (c-DOF)] = 1.f/(1.f + expf(-val));
}

extern "C" void kernel_launch(void* const* d_in, const int* in_sizes, int n_in,
                              void* d_out, int out_size, void* d_ws, size_t ws_size,
                              hipStream_t stream)
{
    fp32p x      = (fp32p)d_in[0];
    fp32p mask   = (fp32p)d_in[1];
    fp32p enc_w1 = (fp32p)d_in[2];
    fp32p enc_b1 = (fp32p)d_in[3];
    fp32p enc_a1 = (fp32p)d_in[4];
    fp32p enc_w2 = (fp32p)d_in[5];
    fp32p enc_b2 = (fp32p)d_in[6];
    fp32p enc_a2 = (fp32p)d_in[7];
    fp32p rel_w1 = (fp32p)d_in[8];
    fp32p rel_b1 = (fp32p)d_in[9];
    fp32p rel_a  = (fp32p)d_in[10];
    fp32p rel_w2 = (fp32p)d_in[11];
    fp32p rel_b2 = (fp32p)d_in[12];
    fp32p ln_g   = (fp32p)d_in[13];
    fp32p ln_b   = (fp32p)d_in[14];
    fp32p wq     = (fp32p)d_in[15];
    fp32p bq     = (fp32p)d_in[16];
    fp32p wk     = (fp32p)d_in[17];
    fp32p bk     = (fp32p)d_in[18];
    fp32p wv     = (fp32p)d_in[19];
    fp32p bv     = (fp32p)d_in[20];
    fp32p wo     = (fp32p)d_in[21];
    fp32p bo     = (fp32p)d_in[22];
    fp32p fw1    = (fp32p)d_in[23];
    fp32p fb1    = (fp32p)d_in[24];
    fp32p fa     = (fp32p)d_in[25];
    fp32p fw2    = (fp32p)d_in[26];
    fp32p fb2    = (fp32p)d_in[27];
    fp32p dec_w1 = (fp32p)d_in[28];
    fp32p dec_b1 = (fp32p)d_in[29];
    fp32p dec_a  = (fp32p)d_in[30];
    fp32p dec_w2 = (fp32p)d_in[31];
    fp32p dec_b2 = (fp32p)d_in[32];

    char* wsb = (char*)d_ws;
    bf16*  Ebf  = (bf16*)(wsb + E_OFF);
    float* h    = (float*)(wsb + H_OFF);
    bf16*  hn   = (bf16*)(wsb + HN_OFF);
    bf16*  qkvb = (bf16*)(wsb + QKV_OFF);    // 4096 x 1536 bf16 (q|k|v fused)
    bf16*  mid  = qkvb;                      // ffn mid 4096 x 2048 bf16 (aliases dead qkv)
    bf16*  cat  = qkvb;                      // encoder scratch (pitch CATP)
    bf16*  hb   = qkvb;                      // decoder bf16 cast of h
    float* y    = (float*)qkvb;              // decoder logits fp32

    // transposed bf16 weights (per-layer reuse; enc/dec alias the same region)
    bf16* qkvT = (bf16*)(wsb + WT_OFF);          // 1536 x 512  (wq^T | wk^T | wv^T)
    bf16* woT  = qkvT + 3*512*512;               // 512 x 512
    bf16* f1T  = woT  + 512*512;                 // 2048 x 512
    bf16* f2T  = f1T  + 2048*512;                // 512 x 2048
    bf16* enc1T = qkvT;                          // 512 x 160 (zero-padded K)
    bf16* enc2T = qkvT + 512*160;                // 512 x 512
    bf16* dec1T = qkvT;                          // 512 x 512
    bf16* dec2T = qkvT + 512*512;                // 73 x 512

    dim3 g512(16, 32);     // N=512 GEMMs, MT=2 (128-row blocks) -> 512 blocks
    dim3 gQKV(48, 16);     // N=1536, MT=4 -> 768 blocks
    dim3 gF1(64, 16);      // N=2048, MT=4 -> 1024 blocks

    // encoder weight transposes + encoder
    k_wt<<<dim3(5,16), 256, 0, stream>>>(enc_w1, 2*DOF, DMODEL, enc1T, CATP);   // Kpad=160
    k_wt<<<dim3(16,16), 256, 0, stream>>>(enc_w2, DMODEL, DMODEL, enc2T, DMODEL);
    k_concat<<<(MTOK*CATP+255)/256, 256, 0, stream>>>(x, mask, cat);
    k_gemm<1,0,1,0,2><<<g512,256,0,stream>>>(cat, CATP, enc1T, CATP, enc_b1, nullptr, nullptr, 0, enc_a1, 0, nullptr, hn, DMODEL, MTOK, DMODEL, CATP);
    k_gemm<1,0,1,1,2><<<g512,256,0,stream>>>(hn, DMODEL, enc2T, DMODEL, enc_b2, nullptr, nullptr, 0, enc_a2, 0, nullptr, h, DMODEL, MTOK, DMODEL, DMODEL);
    k_relemb<<<EROWS, 64, 0, stream>>>(rel_w1, rel_b1, rel_a, rel_w2, rel_b2, Ebf);

    for (int l = 0; l < NL; ++l) {
        size_t oW  = (size_t)l*DMODEL*DMODEL;
        size_t oB  = (size_t)l*DMODEL;
        size_t oF1 = (size_t)l*DMODEL*DFF;
        size_t oBF1= (size_t)l*DFF;
        size_t oF2 = (size_t)l*DFF*DMODEL;

        k_wt6<<<3072, 256, 0, stream>>>(wq+oW, wk+oW, wv+oW, wo+oW, fw1+oF1, fw2+oF2,
                                        qkvT, woT, f1T, f2T);
        k_layernorm<<<MTOK, 256, 0, stream>>>(h, ln_g, ln_b, hn);
        // fused QKV: N=1536, per-segment bias select
        k_gemm<0,0,3,0,4><<<gQKV,256,0,stream>>>(hn, DMODEL, qkvT, DMODEL, bq, bk, bv, oB, nullptr, 0, nullptr, qkvb, QKVP, MTOK, QKVP, DMODEL);
        k_attn<<<BB*NH*(TT/64), 256, 0, stream>>>(qkvb, qkvb + 512, qkvb + 1024, Ebf, hn, QKVP);
        k_gemm<0,1,1,1,2><<<g512,256,0,stream>>>(hn, DMODEL, woT, DMODEL, bo, nullptr, nullptr, oB, nullptr, 0, h, h, DMODEL, MTOK, DMODEL, DMODEL);
        k_layernorm<<<MTOK, 256, 0, stream>>>(h, ln_g, ln_b, hn);
        // fused FFN: f1 full N=2048 -> mid; f2 full K=2048 -> h (+resid)
        k_gemm<1,0,1,0,4><<<gF1,256,0,stream>>>(hn, DMODEL, f1T, DMODEL, fb1, nullptr, nullptr, oBF1, fa, (size_t)l, nullptr, mid, DFF, MTOK, DFF, DMODEL);
        k_gemm<0,1,1,1,2><<<g512,256,0,stream>>>(mid, DFF, f2T, DFF, fb2, nullptr, nullptr, oB, nullptr, 0, h, h, DMODEL, MTOK, DMODEL, DFF);
    }

    // decoder weight transposes + decoder
    k_wt<<<dim3(16,16), 256, 0, stream>>>(dec_w1, DMODEL, DMODEL, dec1T, DMODEL);
    k_wt<<<dim3(16,3), 256, 0, stream>>>(dec_w2, DMODEL, DOF+4, dec2T, DMODEL);
    k_cast<<<(MTOK*DMODEL+255)/256, 256, 0, stream>>>(h, hb);
    k_gemm<1,0,1,0,2><<<g512,256,0,stream>>>(hb, DMODEL, dec1T, DMODEL, dec_b1, nullptr, nullptr, 0, dec_a, 0, nullptr, hn, DMODEL, MTOK, DMODEL, DMODEL);
    {
        dim3 g2(3, 32);   // N=73, MT=2
        k_gemm<0,0,1,1,2><<<g2,256,0,stream>>>(hn, DMODEL, dec2T, DMODEL, dec_b2, nullptr, nullptr, 0, nullptr, 0, nullptr, y, DOF+4, MTOK, DOF+4, DMODEL);
    }
    k_out<<<(MTOK*73+255)/256, 256, 0, stream>>>(y, (float*)d_out);
}

// Round 3
// 1219.664 us; speedup vs baseline: 1.4443x; 1.3731x over previous
//
#include <hip/hip_runtime.h>
#include <hip/hip_bf16.h>

#define DOF 69
#define NL 6
#define NH 8
#define DMODEL 512
#define DFF 2048
#define HD 64
#define BB 8
#define TT 512
#define MTOK (BB*TT)   // 4096
#define EROWS 1040     // 2T-1 = 1023, padded
#define CATP 160       // padded concat pitch (K=138 rounded to 32)
#define QKVP 1536      // fused qkv row pitch

// workspace layout (bytes) — 34.5 MB total
#define E_OFF     4096u
#define H_OFF     (512u*1024u)
#define HN_OFF    (H_OFF + 8u*1024u*1024u)
#define QKV_OFF   (HN_OFF + 4u*1024u*1024u)      // 16 MB region: qkv (12MB) / mid (16MB) / scratch
#define WT_OFF    (QKV_OFF + 16u*1024u*1024u)    // 6 MB of bf16 B^T weights (per-layer reuse)

typedef const float* fp32p;
typedef __hip_bfloat16 bf16;
typedef const bf16* bf16p;
typedef __attribute__((ext_vector_type(8))) short bf16x8;  // 8 bf16 (4 VGPRs)
typedef __attribute__((ext_vector_type(4))) float f32x4;   // 4 fp32 acc

typedef __attribute__((address_space(1))) const void as1_cvoid;
typedef __attribute__((address_space(3))) void       as3_void;

__device__ __forceinline__ void gload16(const bf16* g, const bf16* l){
    __builtin_amdgcn_global_load_lds((as1_cvoid*)g, (as3_void*)l, 16, 0, 0);
}

__device__ __forceinline__ float b2f(bf16 x){ return __bfloat162float(x); }

// ---------------- concat(x, mask) fp32 -> bf16, zero-padded to pitch CATP ----------------
__global__ __launch_bounds__(256)
void k_concat(fp32p x, fp32p mask, bf16* __restrict__ out){
    int idx = blockIdx.x*256 + threadIdx.x;
    if (idx >= MTOK*CATP) return;
    int row = idx / CATP, c = idx - row*CATP;
    float v = 0.f;
    if (c < DOF) v = x[(size_t)row*DOF + c];
    else if (c < 2*DOF) v = mask[(size_t)row*DOF + (c - DOF)];
    out[idx] = __float2bfloat16(v);
}

// ---------------- cast fp32 -> bf16 ----------------
__global__ __launch_bounds__(256)
void k_cast(const float* __restrict__ in, bf16* __restrict__ out){
    int idx = blockIdx.x*256 + threadIdx.x;
    if (idx >= MTOK*DMODEL) return;
    out[idx] = __float2bfloat16(in[idx]);
}

// ---------------- generic weight transpose-cast: W fp32 (K x N) -> WT bf16 (N x ldk) ----
__global__ __launch_bounds__(256)
void k_wt(fp32p W, int K, int N, bf16* __restrict__ WT, int ldk)
{
    __shared__ float s[32][33];
    const int k0 = blockIdx.x*32, n0 = blockIdx.y*32;
    const int c = threadIdx.x & 31, r0 = threadIdx.x >> 5;
    #pragma unroll
    for (int rr = r0; rr < 32; rr += 8) {
        int k = k0 + rr, n = n0 + c;
        s[rr][c] = (k < K && n < N) ? W[(size_t)k*N + n] : 0.f;
    }
    __syncthreads();
    #pragma unroll
    for (int rr = r0; rr < 32; rr += 8) {
        int n = n0 + rr;
        if (n < N) WT[(size_t)n*ldk + k0 + c] = __float2bfloat16(s[c][rr]);
    }
}

// ---------------- per-layer batched transpose: wq,wk,wv,wo,fw1,fw2 -> bf16 B^T ----------
__global__ __launch_bounds__(256)
void k_wt6(fp32p wq, fp32p wk, fp32p wv, fp32p wo, fp32p fw1, fp32p fw2,
           bf16* __restrict__ qkvT, bf16* __restrict__ woT,
           bf16* __restrict__ f1T, bf16* __restrict__ f2T)
{
    __shared__ float s[32][33];
    const int t = blockIdx.x;
    fp32p src; bf16* dst; int N, ldk, k0, n0;
    if (t < 1024) {
        int seg = t >> 8, local = t & 255;
        N = 512; ldk = 512;
        k0 = (local & 15) * 32; n0 = (local >> 4) * 32;
        if      (seg == 0) { src = wq; dst = qkvT; }
        else if (seg == 1) { src = wk; dst = qkvT + 512*512; }
        else if (seg == 2) { src = wv; dst = qkvT + 2*512*512; }
        else               { src = wo; dst = woT; }
    } else if (t < 2048) {
        int local = t - 1024;
        N = 2048; ldk = 512;
        k0 = (local & 15) * 32; n0 = (local >> 4) * 32;
        src = fw1; dst = f1T;
    } else {
        int local = t - 2048;
        N = 512; ldk = 2048;
        k0 = (local >> 4) * 32; n0 = (local & 15) * 32;
        src = fw2; dst = f2T;
    }
    const int c = threadIdx.x & 31, r0 = threadIdx.x >> 5;
    #pragma unroll
    for (int rr = r0; rr < 32; rr += 8)
        s[rr][c] = src[(size_t)(k0+rr)*N + n0 + c];
    __syncthreads();
    #pragma unroll
    for (int rr = r0; rr < 32; rr += 8)
        dst[(size_t)(n0+rr)*ldk + k0 + c] = __float2bfloat16(s[c][rr]);
}

// ---------------- LDS-tiled MFMA GEMM (m97 structure + 2-phase pipeline) ----------------
// C = epi(A @ B + bias); A bf16 (M x K) lda; BT bf16 (N x ldk) = B^T.
// Block = 256 threads (4 waves, 2x2 wave grid), tile BM x BN, BK=32.
// global_load_lds (16B) stages A/B tiles into double-buffered linear LDS; chunk-XOR
// swizzle applied on the GLOBAL source and on the LDS READ (both-sides involution,
// rule #21) -> ds_read_b128 fragment loads are ~2-way (free).
// One barrier per K-step: stage(k+1) issued before compute(k) (T3 minimum 2-phase).
// Requires: K%32==0, M%BM==0; N-tail handled by B-row clamp + col guard.
// BIAS: 0=none, 1=bias[], 3=segment-select of {bias,bias2,bias3} by col/512.
template<int BM, int BN, int PRELU, int RESID, int BIAS, int OUTF32>
__global__ __launch_bounds__(256)
void k_gemm(bf16p A, int lda,
            bf16p BT, int ldk,
            fp32p bias, fp32p bias2, fp32p bias3, size_t biasoff,
            fp32p alpha, size_t aidx,
            const float* __restrict__ resid,
            void* __restrict__ Cout, int ldc,
            int M, int N, int K)
{
    constexpr int MF = BM/32;   // m-fragments per wave
    constexpr int NF = BN/32;   // n-fragments per wave
    constexpr int AI = BM/64;   // A stage issues per wave (16 rows each)
    constexpr int BI = BN/64;   // B stage issues per wave

    __shared__ bf16 sA[2][BM*32];
    __shared__ bf16 sB[2][BN*32];

    const int tid  = threadIdx.x;
    const int w    = tid >> 6;
    const int lane = tid & 63;
    const int qd   = lane >> 4;
    const int cl   = lane & 15;
    const int wr   = w >> 1;
    const int wc   = w & 1;
    const int bm   = blockIdx.y * BM;
    const int bn   = blockIdx.x * BN;

    // chunk-XOR swizzle: LDS tile row r stores global 16B-chunk (pos ^ ((r>>1)&3)) at pos.
    const int sc = (lane & 3) ^ ((lane >> 3) & 3);    // source chunk for linear-dest staging
    const int rc = qd ^ ((cl >> 1) & 3);              // read chunk for fragment loads

    // staging global pointers (lane -> row lane>>2 within 16-row group, chunk sc)
    const bf16* aG = A + (size_t)(bm + w*(BM/4) + (lane >> 2))*lda + sc*8;
    const bf16* bG[BI];
    #pragma unroll
    for (int i = 0; i < BI; ++i) {
        int rrow = min(bn + w*(BN/4) + i*16 + (lane >> 2), N-1);
        bG[i] = BT + (size_t)rrow*ldk + sc*8;
    }

    f32x4 acc[MF][NF] = {};

    auto stage = [&](int p, int k0){
        #pragma unroll
        for (int i = 0; i < AI; ++i)
            gload16(aG + (size_t)(i*16)*lda + k0, &sA[p][(w*(BM/4) + i*16)*32]);
        #pragma unroll
        for (int i = 0; i < BI; ++i)
            gload16(bG[i] + k0, &sB[p][(w*(BN/4) + i*16)*32]);
    };

    stage(0, 0);
    int p = 0;
    for (int k0 = 0; k0 < K; k0 += 32) {
        __syncthreads();                       // drains vmcnt: buf[p] ready
        if (k0 + 32 < K) stage(p^1, k0 + 32);  // issue next tile under compute
        bf16x8 aF[MF], bF[NF];
        #pragma unroll
        for (int mt = 0; mt < MF; ++mt)
            aF[mt] = *(const bf16x8*)(&sA[p][(wr*(BM/2) + mt*16 + cl)*32 + rc*8]);
        #pragma unroll
        for (int nt = 0; nt < NF; ++nt)
            bF[nt] = *(const bf16x8*)(&sB[p][(wc*(BN/2) + nt*16 + cl)*32 + rc*8]);
        #pragma unroll
        for (int mt = 0; mt < MF; ++mt)
            #pragma unroll
            for (int nt = 0; nt < NF; ++nt)
                acc[mt][nt] = __builtin_amdgcn_mfma_f32_16x16x32_bf16(aF[mt], bF[nt], acc[mt][nt], 0, 0, 0);
        p ^= 1;
    }

    const float alp = PRELU ? alpha[aidx] : 0.f;
    fp32p bsel = bias;
    if (BIAS == 3) bsel = (bn < 512) ? bias : ((bn < 1024) ? bias2 : bias3);
    #pragma unroll
    for (int nt = 0; nt < NF; ++nt) {
        int col = bn + wc*(BN/2) + nt*16 + cl;
        if (col < N) {
            float bv = 0.f;
            if (BIAS == 1) bv = bsel[biasoff + col];
            if (BIAS == 3) bv = bsel[biasoff + (col & 511)];
            #pragma unroll
            for (int mt = 0; mt < MF; ++mt) {
                #pragma unroll
                for (int r = 0; r < 4; ++r) {
                    int row = bm + wr*(BM/2) + mt*16 + qd*4 + r;
                    float c = acc[mt][nt][r] + bv;
                    if (PRELU) c = (c >= 0.f) ? c : alp*c;
                    if (RESID) c += resid[(size_t)row*ldc + col];
                    if (OUTF32) ((float*)Cout)[(size_t)row*ldc + col] = c;
                    else ((bf16*)Cout)[(size_t)row*ldc + col] = __float2bfloat16(c);
                }
            }
        }
    }
}

// ---------------- LayerNorm: fp32 in -> bf16 out ----------------
__global__ __launch_bounds__(256)
void k_layernorm(const float* __restrict__ x, fp32p g, fp32p b, bf16* __restrict__ out){
    __shared__ float red[256];
    const int row = blockIdx.x, tid = threadIdx.x;
    const float* xr = x + (size_t)row*DMODEL;
    float x0 = xr[tid], x1 = xr[tid+256];
    red[tid] = x0 + x1; __syncthreads();
    for (int o = 128; o > 0; o >>= 1) { if (tid < o) red[tid] += red[tid+o]; __syncthreads(); }
    float mean = red[0] * (1.f/DMODEL);
    __syncthreads();
    float d0 = x0 - mean, d1 = x1 - mean;
    red[tid] = d0*d0 + d1*d1; __syncthreads();
    for (int o = 128; o > 0; o >>= 1) { if (tid < o) red[tid] += red[tid+o]; __syncthreads(); }
    float inv = rsqrtf(red[0]*(1.f/DMODEL) + 1e-6f);
    out[(size_t)row*DMODEL + tid]     = __float2bfloat16(d0*inv*g[tid]     + b[tid]);
    out[(size_t)row*DMODEL + tid+256] = __float2bfloat16(d1*inv*g[tid+256] + b[tid+256]);
}

// ---------------- relative embedding E: (EROWS, HD) bf16, zero-padded ----------------
__global__ __launch_bounds__(64)
void k_relemb(fp32p w1, fp32p b1, fp32p a, fp32p w2, fp32p b2, bf16* __restrict__ Ebf){
    __shared__ float sH[DMODEL];
    const int r = blockIdx.x, tid = threadIdx.x;
    if (r >= 2*TT - 1) { Ebf[(size_t)r*HD + tid] = __float2bfloat16(0.f); return; }
    const float dist = (float)(r - (TT-1));
    const float al = a[0];
    for (int d = tid; d < DMODEL; d += 64) {
        float hv = dist * w1[d] + b1[d];
        sH[d] = (hv >= 0.f) ? hv : al*hv;
    }
    __syncthreads();
    float acc = b2[tid];
    for (int d = 0; d < DMODEL; ++d) acc += sH[d] * w2[(size_t)d*HD + tid];
    Ebf[(size_t)r*HD + tid] = __float2bfloat16(acc);
}

// ---------------- MFMA flash attention with relative-position skew ----------------
// q,k,v have row pitch qp (fused qkv buffer); output o has pitch DMODEL.
__global__ __launch_bounds__(256)
void k_attn(bf16p q, bf16p k, bf16p v, bf16p Ebf, bf16* __restrict__ o, int qp)
{
    __shared__ bf16  sVT[64][68];        // V^T tile: [d][j_local]
    __shared__ float sQE[4][16][100];    // per-wave qe tile
    __shared__ bf16  sP[4][16][68];      // per-wave P tile

    const int bid  = blockIdx.x;
    const int itile = bid & 7;
    const int h    = (bid >> 3) & 7;
    const int b    = bid >> 6;
    const int tid  = threadIdx.x;
    const int w    = tid >> 6;
    const int lane = tid & 63;
    const int qd   = lane >> 4;
    const int cl   = lane & 15;

    const int I = itile*64 + w*16;
    const size_t bh = ((size_t)b*TT)*qp + (size_t)h*HD;
    const size_t bo = ((size_t)b*TT)*DMODEL + (size_t)h*HD;

    bf16x8 qa0, qa1;
    {
        const bf16* qrow = q + bh + (size_t)(I + cl)*qp;
        qa0 = *(const bf16x8*)(qrow + qd*8);
        qa1 = *(const bf16x8*)(qrow + 32 + qd*8);
    }

    f32x4 Oacc[4] = {};
    float m_i[4], l_i[4];
    #pragma unroll
    for (int r = 0; r < 4; ++r) { m_i[r] = -1e30f; l_i[r] = 0.f; }
    const float scale = 0.125f;

    for (int J = 0; J < TT; J += 64) {
        {
            int j = tid >> 2, dc = (tid & 3) * 16;
            const bf16* vrow = v + bh + (size_t)(J + j)*qp + dc;
            bf16x8 v0 = *(const bf16x8*)(vrow);
            bf16x8 v1 = *(const bf16x8*)(vrow + 8);
            #pragma unroll
            for (int e = 0; e < 8; ++e) sVT[dc + e][j]     = ((const bf16*)&v0)[e];
            #pragma unroll
            for (int e = 0; e < 8; ++e) sVT[dc + 8 + e][j] = ((const bf16*)&v1)[e];
        }
        __syncthreads();

        f32x4 S[4];
        #pragma unroll
        for (int js = 0; js < 4; ++js) {
            const bf16* krow = k + bh + (size_t)(J + js*16 + cl)*qp;
            bf16x8 kb0 = *(const bf16x8*)(krow + qd*8);
            bf16x8 kb1 = *(const bf16x8*)(krow + 32 + qd*8);
            f32x4 acc = {};
            acc = __builtin_amdgcn_mfma_f32_16x16x32_bf16(qa0, kb0, acc, 0, 0, 0);
            acc = __builtin_amdgcn_mfma_f32_16x16x32_bf16(qa1, kb1, acc, 0, 0, 0);
            S[js] = acc;
        }

        const int rbase = J - I + 496;
        #pragma unroll
        for (int nt = 0; nt < 6; ++nt) {
            const bf16* erow = Ebf + (size_t)(rbase + nt*16 + cl)*HD;
            bf16x8 eb0 = *(const bf16x8*)(erow + qd*8);
            bf16x8 eb1 = *(const bf16x8*)(erow + 32 + qd*8);
            f32x4 acc = {};
            acc = __builtin_amdgcn_mfma_f32_16x16x32_bf16(qa0, eb0, acc, 0, 0, 0);
            acc = __builtin_amdgcn_mfma_f32_16x16x32_bf16(qa1, eb1, acc, 0, 0, 0);
            #pragma unroll
            for (int r = 0; r < 4; ++r)
                sQE[w][qd*4 + r][nt*16 + cl] = acc[r];
        }

        float mnew[4];
        #pragma unroll
        for (int r = 0; r < 4; ++r) mnew[r] = m_i[r];
        #pragma unroll
        for (int js = 0; js < 4; ++js) {
            #pragma unroll
            for (int r = 0; r < 4; ++r) {
                int idx = js*16 + cl - (qd*4 + r) + 15;
                float s = S[js][r] + sQE[w][qd*4 + r][idx];
                S[js][r] = s;
                mnew[r] = fmaxf(mnew[r], s);
            }
        }
        #pragma unroll
        for (int r = 0; r < 4; ++r) {
            float mv = mnew[r];
            mv = fmaxf(mv, __shfl_xor(mv, 1));
            mv = fmaxf(mv, __shfl_xor(mv, 2));
            mv = fmaxf(mv, __shfl_xor(mv, 4));
            mv = fmaxf(mv, __shfl_xor(mv, 8));
            mnew[r] = mv;
        }
        float alpha[4], rsum[4];
        #pragma unroll
        for (int r = 0; r < 4; ++r) {
            alpha[r] = expf((m_i[r] - mnew[r]) * scale);
            m_i[r] = mnew[r];
            rsum[r] = 0.f;
        }
        #pragma unroll
        for (int js = 0; js < 4; ++js) {
            #pragma unroll
            for (int r = 0; r < 4; ++r) {
                float p = expf((S[js][r] - m_i[r]) * scale);
                rsum[r] += p;
                sP[w][qd*4 + r][js*16 + cl] = __float2bfloat16(p);
            }
        }
        #pragma unroll
        for (int r = 0; r < 4; ++r) {
            float sv = rsum[r];
            sv += __shfl_xor(sv, 1);
            sv += __shfl_xor(sv, 2);
            sv += __shfl_xor(sv, 4);
            sv += __shfl_xor(sv, 8);
            l_i[r] = l_i[r]*alpha[r] + sv;
        }

        bf16x8 pa0, pa1;
        {
            const bf16* pr = &sP[w][cl][0];
            #pragma unroll
            for (int e = 0; e < 8; ++e) ((short*)&pa0)[e] = ((const short*)pr)[qd*8 + e];
            #pragma unroll
            for (int e = 0; e < 8; ++e) ((short*)&pa1)[e] = ((const short*)pr)[32 + qd*8 + e];
        }

        #pragma unroll
        for (int nt = 0; nt < 4; ++nt) {
            #pragma unroll
            for (int r = 0; r < 4; ++r) Oacc[nt][r] *= alpha[r];
            bf16x8 vb0, vb1;
            const bf16* vr = &sVT[nt*16 + cl][0];
            #pragma unroll
            for (int e = 0; e < 8; ++e) ((short*)&vb0)[e] = ((const short*)vr)[qd*8 + e];
            #pragma unroll
            for (int e = 0; e < 8; ++e) ((short*)&vb1)[e] = ((const short*)vr)[32 + qd*8 + e];
            Oacc[nt] = __builtin_amdgcn_mfma_f32_16x16x32_bf16(pa0, vb0, Oacc[nt], 0, 0, 0);
            Oacc[nt] = __builtin_amdgcn_mfma_f32_16x16x32_bf16(pa1, vb1, Oacc[nt], 0, 0, 0);
        }
        __syncthreads();
    }

    #pragma unroll
    for (int nt = 0; nt < 4; ++nt) {
        #pragma unroll
        for (int r = 0; r < 4; ++r) {
            int row = qd*4 + r;
            float val = Oacc[nt][r] / l_i[r];
            o[bo + (size_t)(I + row)*DMODEL + nt*16 + cl] = __float2bfloat16(val);
        }
    }
}

// ---------------- output split + sigmoid (fp32 out) ----------------
__global__ __launch_bounds__(256)
void k_out(const float* __restrict__ y, float* __restrict__ out){
    int idx = blockIdx.x*256 + threadIdx.x;
    if (idx >= MTOK*73) return;
    int row = idx / 73, c = idx - row*73;
    float val = y[idx];
    if (c < DOF) out[(size_t)row*DOF + c] = val;
    else out[(size_t)MTOK*DOF + row*4 + (c-DOF)] = 1.f/(1.f + expf(-val));
}

extern "C" void kernel_launch(void* const* d_in, const int* in_sizes, int n_in,
                              void* d_out, int out_size, void* d_ws, size_t ws_size,
                              hipStream_t stream)
{
    fp32p x      = (fp32p)d_in[0];
    fp32p mask   = (fp32p)d_in[1];
    fp32p enc_w1 = (fp32p)d_in[2];
    fp32p enc_b1 = (fp32p)d_in[3];
    fp32p enc_a1 = (fp32p)d_in[4];
    fp32p enc_w2 = (fp32p)d_in[5];
    fp32p enc_b2 = (fp32p)d_in[6];
    fp32p enc_a2 = (fp32p)d_in[7];
    fp32p rel_w1 = (fp32p)d_in[8];
    fp32p rel_b1 = (fp32p)d_in[9];
    fp32p rel_a  = (fp32p)d_in[10];
    fp32p rel_w2 = (fp32p)d_in[11];
    fp32p rel_b2 = (fp32p)d_in[12];
    fp32p ln_g   = (fp32p)d_in[13];
    fp32p ln_b   = (fp32p)d_in[14];
    fp32p wq     = (fp32p)d_in[15];
    fp32p bq     = (fp32p)d_in[16];
    fp32p wk     = (fp32p)d_in[17];
    fp32p bk     = (fp32p)d_in[18];
    fp32p wv     = (fp32p)d_in[19];
    fp32p bv     = (fp32p)d_in[20];
    fp32p wo     = (fp32p)d_in[21];
    fp32p bo     = (fp32p)d_in[22];
    fp32p fw1    = (fp32p)d_in[23];
    fp32p fb1    = (fp32p)d_in[24];
    fp32p fa     = (fp32p)d_in[25];
    fp32p fw2    = (fp32p)d_in[26];
    fp32p fb2    = (fp32p)d_in[27];
    fp32p dec_w1 = (fp32p)d_in[28];
    fp32p dec_b1 = (fp32p)d_in[29];
    fp32p dec_a  = (fp32p)d_in[30];
    fp32p dec_w2 = (fp32p)d_in[31];
    fp32p dec_b2 = (fp32p)d_in[32];

    char* wsb = (char*)d_ws;
    bf16*  Ebf  = (bf16*)(wsb + E_OFF);
    float* h    = (float*)(wsb + H_OFF);
    bf16*  hn   = (bf16*)(wsb + HN_OFF);
    bf16*  qkvb = (bf16*)(wsb + QKV_OFF);    // 4096 x 1536 bf16 (q|k|v fused)
    bf16*  mid  = qkvb;                      // ffn mid 4096 x 2048 bf16 (aliases dead qkv)
    bf16*  cat  = qkvb;                      // encoder scratch (pitch CATP)
    bf16*  hb   = qkvb;                      // decoder bf16 cast of h
    float* y    = (float*)qkvb;              // decoder logits fp32

    // transposed bf16 weights (per-layer reuse; enc/dec alias the same region)
    bf16* qkvT = (bf16*)(wsb + WT_OFF);          // 1536 x 512  (wq^T | wk^T | wv^T)
    bf16* woT  = qkvT + 3*512*512;               // 512 x 512
    bf16* f1T  = woT  + 512*512;                 // 2048 x 512
    bf16* f2T  = f1T  + 2048*512;                // 512 x 2048
    bf16* enc1T = qkvT;                          // 512 x 160 (zero-padded K)
    bf16* enc2T = qkvT + 512*160;                // 512 x 512
    bf16* dec1T = qkvT;                          // 512 x 512
    bf16* dec2T = qkvT + 512*512;                // 73 x 512

    dim3 g512(8, 32);      // N=512: BM=128 BN=64  -> 256 blocks (1/CU)
    dim3 gQKV(12, 32);     // N=1536: BM=128 BN=128 -> 384 blocks
    dim3 gF1(16, 32);      // N=2048: BM=128 BN=128 -> 512 blocks

    // encoder weight transposes + encoder
    k_wt<<<dim3(5,16), 256, 0, stream>>>(enc_w1, 2*DOF, DMODEL, enc1T, CATP);   // Kpad=160
    k_wt<<<dim3(16,16), 256, 0, stream>>>(enc_w2, DMODEL, DMODEL, enc2T, DMODEL);
    k_concat<<<(MTOK*CATP+255)/256, 256, 0, stream>>>(x, mask, cat);
    k_gemm<128,64,1,0,1,0><<<g512,256,0,stream>>>(cat, CATP, enc1T, CATP, enc_b1, nullptr, nullptr, 0, enc_a1, 0, nullptr, hn, DMODEL, MTOK, DMODEL, CATP);
    k_gemm<128,64,1,0,1,1><<<g512,256,0,stream>>>(hn, DMODEL, enc2T, DMODEL, enc_b2, nullptr, nullptr, 0, enc_a2, 0, nullptr, h, DMODEL, MTOK, DMODEL, DMODEL);
    k_relemb<<<EROWS, 64, 0, stream>>>(rel_w1, rel_b1, rel_a, rel_w2, rel_b2, Ebf);

    for (int l = 0; l < NL; ++l) {
        size_t oW  = (size_t)l*DMODEL*DMODEL;
        size_t oB  = (size_t)l*DMODEL;
        size_t oF1 = (size_t)l*DMODEL*DFF;
        size_t oBF1= (size_t)l*DFF;
        size_t oF2 = (size_t)l*DFF*DMODEL;

        k_wt6<<<3072, 256, 0, stream>>>(wq+oW, wk+oW, wv+oW, wo+oW, fw1+oF1, fw2+oF2,
                                        qkvT, woT, f1T, f2T);
        k_layernorm<<<MTOK, 256, 0, stream>>>(h, ln_g, ln_b, hn);
        // fused QKV: N=1536, per-segment bias select
        k_gemm<128,128,0,0,3,0><<<gQKV,256,0,stream>>>(hn, DMODEL, qkvT, DMODEL, bq, bk, bv, oB, nullptr, 0, nullptr, qkvb, QKVP, MTOK, QKVP, DMODEL);
        k_attn<<<BB*NH*(TT/64), 256, 0, stream>>>(qkvb, qkvb + 512, qkvb + 1024, Ebf, hn, QKVP);
        k_gemm<128,64,0,1,1,1><<<g512,256,0,stream>>>(hn, DMODEL, woT, DMODEL, bo, nullptr, nullptr, oB, nullptr, 0, h, h, DMODEL, MTOK, DMODEL, DMODEL);
        k_layernorm<<<MTOK, 256, 0, stream>>>(h, ln_g, ln_b, hn);
        // fused FFN: f1 full N=2048 -> mid; f2 full K=2048 -> h (+resid)
        k_gemm<128,128,1,0,1,0><<<gF1,256,0,stream>>>(hn, DMODEL, f1T, DMODEL, fb1, nullptr, nullptr, oBF1, fa, (size_t)l, nullptr, mid, DFF, MTOK, DFF, DMODEL);
        k_gemm<128,64,0,1,1,1><<<g512,256,0,stream>>>(mid, DFF, f2T, DFF, fb2, nullptr, nullptr, oB, nullptr, 0, h, h, DMODEL, MTOK, DMODEL, DFF);
    }

    // decoder weight transposes + decoder
    k_wt<<<dim3(16,16), 256, 0, stream>>>(dec_w1, DMODEL, DMODEL, dec1T, DMODEL);
    k_wt<<<dim3(16,3), 256, 0, stream>>>(dec_w2, DMODEL, DOF+4, dec2T, DMODEL);
    k_cast<<<(MTOK*DMODEL+255)/256, 256, 0, stream>>>(h, hb);
    k_gemm<128,64,1,0,1,0><<<g512,256,0,stream>>>(hb, DMODEL, dec1T, DMODEL, dec_b1, nullptr, nullptr, 0, dec_a, 0, nullptr, hn, DMODEL, MTOK, DMODEL, DMODEL);
    {
        dim3 g2(2, 32);   // N=73: BN=64 -> 2 col tiles
        k_gemm<128,64,0,0,1,1><<<g2,256,0,stream>>>(hn, DMODEL, dec2T, DMODEL, dec_b2, nullptr, nullptr, 0, nullptr, 0, nullptr, y, DOF+4, MTOK, DOF+4, DMODEL);
    }
    k_out<<<(MTOK*73+255)/256, 256, 0, stream>>>(y, (float*)d_out);
}

// Round 4
// 1190.220 us; speedup vs baseline: 1.4800x; 1.0247x over previous
//
#include <hip/hip_runtime.h>
#include <hip/hip_bf16.h>

#define DOF 69
#define NL 6
#define NH 8
#define DMODEL 512
#define DFF 2048
#define HD 64
#define BB 8
#define TT 512
#define MTOK (BB*TT)   // 4096
#define EROWS 1040     // 2T-1 = 1023, padded
#define CATP 160       // padded concat pitch (K=138 rounded to 32)
#define QKP 1024       // fused q|k row pitch (v split out transposed)

// workspace layout (bytes) — 34.5 MB total
#define E_OFF     4096u
#define H_OFF     (512u*1024u)
#define HN_OFF    (H_OFF + 8u*1024u*1024u)
#define QKV_OFF   (HN_OFF + 4u*1024u*1024u)      // 16 MB region: qk(8MB)+VT(4MB) / mid(16MB) / scratch
#define WT_OFF    (QKV_OFF + 16u*1024u*1024u)    // 6 MB of bf16 B^T weights (per-layer reuse)

typedef const float* fp32p;
typedef __hip_bfloat16 bf16;
typedef const bf16* bf16p;
typedef __attribute__((ext_vector_type(8))) short bf16x8;  // 8 bf16 (4 VGPRs)
typedef __attribute__((ext_vector_type(4))) short s16x4;   // 4 bf16 (8B store)
typedef __attribute__((ext_vector_type(4))) float f32x4;   // 4 fp32 acc

typedef __attribute__((address_space(1))) const void as1_cvoid;
typedef __attribute__((address_space(3))) void       as3_void;

__device__ __forceinline__ void gload16(const bf16* g, const bf16* l){
    __builtin_amdgcn_global_load_lds((as1_cvoid*)g, (as3_void*)l, 16, 0, 0);
}

__device__ __forceinline__ float b2f(bf16 x){ return __bfloat162float(x); }

// ---------------- concat(x, mask) fp32 -> bf16, zero-padded to pitch CATP ----------------
__global__ __launch_bounds__(256)
void k_concat(fp32p x, fp32p mask, bf16* __restrict__ out){
    int idx = blockIdx.x*256 + threadIdx.x;
    if (idx >= MTOK*CATP) return;
    int row = idx / CATP, c = idx - row*CATP;
    float v = 0.f;
    if (c < DOF) v = x[(size_t)row*DOF + c];
    else if (c < 2*DOF) v = mask[(size_t)row*DOF + (c - DOF)];
    out[idx] = __float2bfloat16(v);
}

// ---------------- cast fp32 -> bf16 ----------------
__global__ __launch_bounds__(256)
void k_cast(const float* __restrict__ in, bf16* __restrict__ out){
    int idx = blockIdx.x*256 + threadIdx.x;
    if (idx >= MTOK*DMODEL) return;
    out[idx] = __float2bfloat16(in[idx]);
}

// ---------------- generic weight transpose-cast: W fp32 (K x N) -> WT bf16 (N x ldk) ----
__global__ __launch_bounds__(256)
void k_wt(fp32p W, int K, int N, bf16* __restrict__ WT, int ldk)
{
    __shared__ float s[32][33];
    const int k0 = blockIdx.x*32, n0 = blockIdx.y*32;
    const int c = threadIdx.x & 31, r0 = threadIdx.x >> 5;
    #pragma unroll
    for (int rr = r0; rr < 32; rr += 8) {
        int k = k0 + rr, n = n0 + c;
        s[rr][c] = (k < K && n < N) ? W[(size_t)k*N + n] : 0.f;
    }
    __syncthreads();
    #pragma unroll
    for (int rr = r0; rr < 32; rr += 8) {
        int n = n0 + rr;
        if (n < N) WT[(size_t)n*ldk + k0 + c] = __float2bfloat16(s[c][rr]);
    }
}

// ---------------- per-layer batched transpose: wq,wk,wv,wo,fw1,fw2 -> bf16 B^T ----------
__global__ __launch_bounds__(256)
void k_wt6(fp32p wq, fp32p wk, fp32p wv, fp32p wo, fp32p fw1, fp32p fw2,
           bf16* __restrict__ qkvT, bf16* __restrict__ woT,
           bf16* __restrict__ f1T, bf16* __restrict__ f2T)
{
    __shared__ float s[32][33];
    const int t = blockIdx.x;
    fp32p src; bf16* dst; int N, ldk, k0, n0;
    if (t < 1024) {
        int seg = t >> 8, local = t & 255;
        N = 512; ldk = 512;
        k0 = (local & 15) * 32; n0 = (local >> 4) * 32;
        if      (seg == 0) { src = wq; dst = qkvT; }
        else if (seg == 1) { src = wk; dst = qkvT + 512*512; }
        else if (seg == 2) { src = wv; dst = qkvT + 2*512*512; }
        else               { src = wo; dst = woT; }
    } else if (t < 2048) {
        int local = t - 1024;
        N = 2048; ldk = 512;
        k0 = (local & 15) * 32; n0 = (local >> 4) * 32;
        src = fw1; dst = f1T;
    } else {
        int local = t - 2048;
        N = 512; ldk = 2048;
        k0 = (local >> 4) * 32; n0 = (local & 15) * 32;
        src = fw2; dst = f2T;
    }
    const int c = threadIdx.x & 31, r0 = threadIdx.x >> 5;
    #pragma unroll
    for (int rr = r0; rr < 32; rr += 8)
        s[rr][c] = src[(size_t)(k0+rr)*N + n0 + c];
    __syncthreads();
    #pragma unroll
    for (int rr = r0; rr < 32; rr += 8)
        dst[(size_t)(n0+rr)*ldk + k0 + c] = __float2bfloat16(s[c][rr]);
}

// ---------------- LDS-tiled MFMA GEMM (m97 structure + 2-phase pipeline) ----------------
// C = epi(A @ B + bias); A bf16 (M x K) lda; BT bf16 (N x ldk) = B^T.
// Block = 256 threads (4 waves, 2x2 wave grid), tile BM x BN, BK=32.
// global_load_lds (16B) stages A/B tiles into double-buffered linear LDS; chunk-XOR
// swizzle on GLOBAL source + LDS READ (both-sides involution).
// One barrier per K-step: stage(k+1) issued before compute(k).
// BIAS: 0=none, 1=bias[], 3=segment-select of {bias,bias2,bias3} by col/512.
// SPLITV: blocks with bn>=1024 write transposed per-head VT[b][h][d][t] (QKV fusion).
template<int BM, int BN, int PRELU, int RESID, int BIAS, int OUTF32, int SPLITV>
__global__ __launch_bounds__(256)
void k_gemm(bf16p A, int lda,
            bf16p BT, int ldk,
            fp32p bias, fp32p bias2, fp32p bias3, size_t biasoff,
            fp32p alpha, size_t aidx,
            const float* __restrict__ resid,
            void* __restrict__ Cout, int ldc,
            bf16* __restrict__ VTout,
            int M, int N, int K)
{
    constexpr int MF = BM/32;   // m-fragments per wave
    constexpr int NF = BN/32;   // n-fragments per wave
    constexpr int AI = BM/64;   // A stage issues per wave
    constexpr int BI = BN/64;   // B stage issues per wave

    __shared__ __attribute__((aligned(16))) bf16 sA[2][BM*32];
    __shared__ __attribute__((aligned(16))) bf16 sB[2][BN*32];

    const int tid  = threadIdx.x;
    const int w    = tid >> 6;
    const int lane = tid & 63;
    const int qd   = lane >> 4;
    const int cl   = lane & 15;
    const int wr   = w >> 1;
    const int wc   = w & 1;
    const int bm   = blockIdx.y * BM;
    const int bn   = blockIdx.x * BN;

    const int sc = (lane & 3) ^ ((lane >> 3) & 3);    // source chunk (staging)
    const int rc = qd ^ ((cl >> 1) & 3);              // read chunk (fragments)

    const bf16* aG = A + (size_t)(bm + w*(BM/4) + (lane >> 2))*lda + sc*8;
    const bf16* bG[BI];
    #pragma unroll
    for (int i = 0; i < BI; ++i) {
        int rrow = min(bn + w*(BN/4) + i*16 + (lane >> 2), N-1);
        bG[i] = BT + (size_t)rrow*ldk + sc*8;
    }

    f32x4 acc[MF][NF] = {};

    auto stage = [&](int p, int k0){
        #pragma unroll
        for (int i = 0; i < AI; ++i)
            gload16(aG + (size_t)(i*16)*lda + k0, &sA[p][(w*(BM/4) + i*16)*32]);
        #pragma unroll
        for (int i = 0; i < BI; ++i)
            gload16(bG[i] + k0, &sB[p][(w*(BN/4) + i*16)*32]);
    };

    stage(0, 0);
    int p = 0;
    for (int k0 = 0; k0 < K; k0 += 32) {
        __syncthreads();
        if (k0 + 32 < K) stage(p^1, k0 + 32);
        bf16x8 aF[MF], bF[NF];
        #pragma unroll
        for (int mt = 0; mt < MF; ++mt)
            aF[mt] = *(const bf16x8*)(&sA[p][(wr*(BM/2) + mt*16 + cl)*32 + rc*8]);
        #pragma unroll
        for (int nt = 0; nt < NF; ++nt)
            bF[nt] = *(const bf16x8*)(&sB[p][(wc*(BN/2) + nt*16 + cl)*32 + rc*8]);
        #pragma unroll
        for (int mt = 0; mt < MF; ++mt)
            #pragma unroll
            for (int nt = 0; nt < NF; ++nt)
                acc[mt][nt] = __builtin_amdgcn_mfma_f32_16x16x32_bf16(aF[mt], bF[nt], acc[mt][nt], 0, 0, 0);
        p ^= 1;
    }

    if (SPLITV && bn >= 1024) {
        // V segment: write transposed VT[((b*8+h)*64+hd)*512 + t], 8B short4 stores
        #pragma unroll
        for (int nt = 0; nt < NF; ++nt) {
            int col = bn + wc*(BN/2) + nt*16 + cl;
            float bv = bias3[biasoff + (col & 511)];
            int hh = (col >> 6) & 7;
            int hd = col & 63;
            #pragma unroll
            for (int mt = 0; mt < MF; ++mt) {
                int row0 = bm + wr*(BM/2) + mt*16 + qd*4;
                int bb = row0 >> 9, t = row0 & 511;
                s16x4 v4;
                #pragma unroll
                for (int r = 0; r < 4; ++r) {
                    bf16 cb = __float2bfloat16(acc[mt][nt][r] + bv);
                    v4[r] = *reinterpret_cast<short*>(&cb);
                }
                *(s16x4*)(VTout + ((size_t)((bb*8 + hh)*64 + hd))*512 + t) = v4;
            }
        }
        return;
    }

    const float alp = PRELU ? alpha[aidx] : 0.f;
    fp32p bsel = bias;
    if (BIAS == 3) bsel = (bn < 512) ? bias : ((bn < 1024) ? bias2 : bias3);
    #pragma unroll
    for (int nt = 0; nt < NF; ++nt) {
        int col = bn + wc*(BN/2) + nt*16 + cl;
        if (col < N) {
            float bv = 0.f;
            if (BIAS == 1) bv = bsel[biasoff + col];
            if (BIAS == 3) bv = bsel[biasoff + (col & 511)];
            #pragma unroll
            for (int mt = 0; mt < MF; ++mt) {
                #pragma unroll
                for (int r = 0; r < 4; ++r) {
                    int row = bm + wr*(BM/2) + mt*16 + qd*4 + r;
                    float c = acc[mt][nt][r] + bv;
                    if (PRELU) c = (c >= 0.f) ? c : alp*c;
                    if (RESID) c += resid[(size_t)row*ldc + col];
                    if (OUTF32) ((float*)Cout)[(size_t)row*ldc + col] = c;
                    else ((bf16*)Cout)[(size_t)row*ldc + col] = __float2bfloat16(c);
                }
            }
        }
    }
}

// ---------------- LayerNorm: fp32 in -> bf16 out ----------------
__global__ __launch_bounds__(256)
void k_layernorm(const float* __restrict__ x, fp32p g, fp32p b, bf16* __restrict__ out){
    __shared__ float red[256];
    const int row = blockIdx.x, tid = threadIdx.x;
    const float* xr = x + (size_t)row*DMODEL;
    float x0 = xr[tid], x1 = xr[tid+256];
    red[tid] = x0 + x1; __syncthreads();
    for (int o = 128; o > 0; o >>= 1) { if (tid < o) red[tid] += red[tid+o]; __syncthreads(); }
    float mean = red[0] * (1.f/DMODEL);
    __syncthreads();
    float d0 = x0 - mean, d1 = x1 - mean;
    red[tid] = d0*d0 + d1*d1; __syncthreads();
    for (int o = 128; o > 0; o >>= 1) { if (tid < o) red[tid] += red[tid+o]; __syncthreads(); }
    float inv = rsqrtf(red[0]*(1.f/DMODEL) + 1e-6f);
    out[(size_t)row*DMODEL + tid]     = __float2bfloat16(d0*inv*g[tid]     + b[tid]);
    out[(size_t)row*DMODEL + tid+256] = __float2bfloat16(d1*inv*g[tid+256] + b[tid+256]);
}

// ---------------- relative embedding E: (EROWS, HD) bf16, zero-padded ----------------
__global__ __launch_bounds__(64)
void k_relemb(fp32p w1, fp32p b1, fp32p a, fp32p w2, fp32p b2, bf16* __restrict__ Ebf){
    __shared__ float sH[DMODEL];
    const int r = blockIdx.x, tid = threadIdx.x;
    if (r >= 2*TT - 1) { Ebf[(size_t)r*HD + tid] = __float2bfloat16(0.f); return; }
    const float dist = (float)(r - (TT-1));
    const float al = a[0];
    for (int d = tid; d < DMODEL; d += 64) {
        float hv = dist * w1[d] + b1[d];
        sH[d] = (hv >= 0.f) ? hv : al*hv;
    }
    __syncthreads();
    float acc = b2[tid];
    for (int d = 0; d < DMODEL; ++d) acc += sH[d] * w2[(size_t)d*HD + tid];
    Ebf[(size_t)r*HD + tid] = __float2bfloat16(acc);
}

// ---------------- MFMA flash attention with relative-position skew ----------------
// q,k row pitch qp (fused q|k buffer); V pre-transposed VT[b][h][d][t]; out pitch DMODEL.
// All LDS tiles 16B-aligned with chunk-XOR swizzles -> ds_read_b128 fragment loads.
__global__ __launch_bounds__(256)
void k_attn(bf16p q, bf16p k, bf16p VT, bf16p Ebf, bf16* __restrict__ o, int qp)
{
    __shared__ __attribute__((aligned(16))) bf16 sV[2][2][64*32]; // [buf][jhalf][d][chunk] 16KB
    __shared__ float sQE[4][16][100];                             // per-wave qe tile
    __shared__ __attribute__((aligned(16))) bf16 sP[4][16*64];    // per-wave P tile

    const int bid  = blockIdx.x;
    const int itile = bid & 7;
    const int h    = (bid >> 3) & 7;
    const int b    = bid >> 6;
    const int tid  = threadIdx.x;
    const int w    = tid >> 6;
    const int lane = tid & 63;
    const int qd   = lane >> 4;
    const int cl   = lane & 15;

    const int I = itile*64 + w*16;
    const size_t bh = ((size_t)b*TT)*qp + (size_t)h*HD;
    const size_t boff = ((size_t)b*TT)*DMODEL + (size_t)h*HD;

    // V^T staging: thread -> (d=tid>>2, chunk=tid&3), swizzled global source chunk
    const int srow = tid >> 2, schunk = tid & 3;
    const int ssc = schunk ^ ((srow >> 1) & 3);
    const bf16* vtb = VT + ((size_t)((b*8 + h)*64 + srow))*512 + ssc*8;
    const int ldsoff = srow*32 + schunk*8;
    const int rc = qd ^ ((cl >> 1) & 3);    // fragment read chunk

    bf16x8 qa0, qa1;
    {
        const bf16* qrow = q + bh + (size_t)(I + cl)*qp;
        qa0 = *(const bf16x8*)(qrow + qd*8);
        qa1 = *(const bf16x8*)(qrow + 32 + qd*8);
    }

    f32x4 Oacc[4] = {};
    float m_i[4], l_i[4];
    #pragma unroll
    for (int r = 0; r < 4; ++r) { m_i[r] = -1e30f; l_i[r] = 0.f; }
    const float scale = 0.125f;

    gload16(vtb,      &sV[0][0][ldsoff]);
    gload16(vtb + 32, &sV[0][1][ldsoff]);
    int p = 0;

    for (int J = 0; J < TT; J += 64) {
        // ---- QK^T from global (L2-hot K) ----
        f32x4 S[4];
        #pragma unroll
        for (int js = 0; js < 4; ++js) {
            const bf16* krow = k + bh + (size_t)(J + js*16 + cl)*qp;
            bf16x8 kb0 = *(const bf16x8*)(krow + qd*8);
            bf16x8 kb1 = *(const bf16x8*)(krow + 32 + qd*8);
            f32x4 acc = {};
            acc = __builtin_amdgcn_mfma_f32_16x16x32_bf16(qa0, kb0, acc, 0, 0, 0);
            acc = __builtin_amdgcn_mfma_f32_16x16x32_bf16(qa1, kb1, acc, 0, 0, 0);
            S[js] = acc;
        }

        // ---- QE (per-wave LDS, 2-way banks) ----
        const int rbase = J - I + 496;
        #pragma unroll
        for (int nt = 0; nt < 6; ++nt) {
            const bf16* erow = Ebf + (size_t)(rbase + nt*16 + cl)*HD;
            bf16x8 eb0 = *(const bf16x8*)(erow + qd*8);
            bf16x8 eb1 = *(const bf16x8*)(erow + 32 + qd*8);
            f32x4 acc = {};
            acc = __builtin_amdgcn_mfma_f32_16x16x32_bf16(qa0, eb0, acc, 0, 0, 0);
            acc = __builtin_amdgcn_mfma_f32_16x16x32_bf16(qa1, eb1, acc, 0, 0, 0);
            #pragma unroll
            for (int r = 0; r < 4; ++r)
                sQE[w][qd*4 + r][nt*16 + cl] = acc[r];
        }

        // ---- skew add + online softmax ----
        float mnew[4];
        #pragma unroll
        for (int r = 0; r < 4; ++r) mnew[r] = m_i[r];
        #pragma unroll
        for (int js = 0; js < 4; ++js) {
            #pragma unroll
            for (int r = 0; r < 4; ++r) {
                int idx = js*16 + cl - (qd*4 + r) + 15;
                float s = S[js][r] + sQE[w][qd*4 + r][idx];
                S[js][r] = s;
                mnew[r] = fmaxf(mnew[r], s);
            }
        }
        #pragma unroll
        for (int r = 0; r < 4; ++r) {
            float mv = mnew[r];
            mv = fmaxf(mv, __shfl_xor(mv, 1));
            mv = fmaxf(mv, __shfl_xor(mv, 2));
            mv = fmaxf(mv, __shfl_xor(mv, 4));
            mv = fmaxf(mv, __shfl_xor(mv, 8));
            mnew[r] = mv;
        }
        float alpha[4], rsum[4];
        #pragma unroll
        for (int r = 0; r < 4; ++r) {
            alpha[r] = __expf((m_i[r] - mnew[r]) * scale);
            m_i[r] = mnew[r];
            rsum[r] = 0.f;
        }
        // P -> per-wave LDS [16][64], chunk ^ (row&7) swizzle
        #pragma unroll
        for (int js = 0; js < 4; ++js) {
            #pragma unroll
            for (int r = 0; r < 4; ++r) {
                float pv = __expf((S[js][r] - m_i[r]) * scale);
                rsum[r] += pv;
                int prow = qd*4 + r;
                int pcol = ((js*2 + (cl >> 3)) ^ (prow & 7))*8 + (cl & 7);
                sP[w][prow*64 + pcol] = __float2bfloat16(pv);
            }
        }
        #pragma unroll
        for (int r = 0; r < 4; ++r) {
            float sv = rsum[r];
            sv += __shfl_xor(sv, 1);
            sv += __shfl_xor(sv, 2);
            sv += __shfl_xor(sv, 4);
            sv += __shfl_xor(sv, 8);
            l_i[r] = l_i[r]*alpha[r] + sv;
        }

        // P fragments: aligned b128 with the same involution
        bf16x8 pa0, pa1;
        {
            const int c0 = qd ^ (cl & 7);
            const bf16* pb = &sP[w][cl*64];
            pa0 = *(const bf16x8*)(pb + c0*8);
            pa1 = *(const bf16x8*)(pb + (c0 ^ 4)*8);
        }

        __syncthreads();                       // sV[p] staged & prior reads drained
        if (J + 64 < TT) {                     // prefetch next V tile under PV
            gload16(vtb + J + 64, &sV[p^1][0][ldsoff]);
            gload16(vtb + J + 96, &sV[p^1][1][ldsoff]);
        }

        // ---- PV: aligned b128 V^T fragments ----
        #pragma unroll
        for (int nt = 0; nt < 4; ++nt) {
            #pragma unroll
            for (int r = 0; r < 4; ++r) Oacc[nt][r] *= alpha[r];
            bf16x8 vb0 = *(const bf16x8*)(&sV[p][0][(nt*16 + cl)*32 + rc*8]);
            bf16x8 vb1 = *(const bf16x8*)(&sV[p][1][(nt*16 + cl)*32 + rc*8]);
            Oacc[nt] = __builtin_amdgcn_mfma_f32_16x16x32_bf16(pa0, vb0, Oacc[nt], 0, 0, 0);
            Oacc[nt] = __builtin_amdgcn_mfma_f32_16x16x32_bf16(pa1, vb1, Oacc[nt], 0, 0, 0);
        }
        p ^= 1;
    }

    #pragma unroll
    for (int nt = 0; nt < 4; ++nt) {
        #pragma unroll
        for (int r = 0; r < 4; ++r) {
            int row = qd*4 + r;
            float val = Oacc[nt][r] / l_i[r];
            o[boff + (size_t)(I + row)*DMODEL + nt*16 + cl] = __float2bfloat16(val);
        }
    }
}

// ---------------- output split + sigmoid (fp32 out) ----------------
__global__ __launch_bounds__(256)
void k_out(const float* __restrict__ y, float* __restrict__ out){
    int idx = blockIdx.x*256 + threadIdx.x;
    if (idx >= MTOK*73) return;
    int row = idx / 73, c = idx - row*73;
    float val = y[idx];
    if (c < DOF) out[(size_t)row*DOF + c] = val;
    else out[(size_t)MTOK*DOF + row*4 + (c-DOF)] = 1.f/(1.f + expf(-val));
}

extern "C" void kernel_launch(void* const* d_in, const int* in_sizes, int n_in,
                              void* d_out, int out_size, void* d_ws, size_t ws_size,
                              hipStream_t stream)
{
    fp32p x      = (fp32p)d_in[0];
    fp32p mask   = (fp32p)d_in[1];
    fp32p enc_w1 = (fp32p)d_in[2];
    fp32p enc_b1 = (fp32p)d_in[3];
    fp32p enc_a1 = (fp32p)d_in[4];
    fp32p enc_w2 = (fp32p)d_in[5];
    fp32p enc_b2 = (fp32p)d_in[6];
    fp32p enc_a2 = (fp32p)d_in[7];
    fp32p rel_w1 = (fp32p)d_in[8];
    fp32p rel_b1 = (fp32p)d_in[9];
    fp32p rel_a  = (fp32p)d_in[10];
    fp32p rel_w2 = (fp32p)d_in[11];
    fp32p rel_b2 = (fp32p)d_in[12];
    fp32p ln_g   = (fp32p)d_in[13];
    fp32p ln_b   = (fp32p)d_in[14];
    fp32p wq     = (fp32p)d_in[15];
    fp32p bq     = (fp32p)d_in[16];
    fp32p wk     = (fp32p)d_in[17];
    fp32p bk     = (fp32p)d_in[18];
    fp32p wv     = (fp32p)d_in[19];
    fp32p bv     = (fp32p)d_in[20];
    fp32p wo     = (fp32p)d_in[21];
    fp32p bo     = (fp32p)d_in[22];
    fp32p fw1    = (fp32p)d_in[23];
    fp32p fb1    = (fp32p)d_in[24];
    fp32p fa     = (fp32p)d_in[25];
    fp32p fw2    = (fp32p)d_in[26];
    fp32p fb2    = (fp32p)d_in[27];
    fp32p dec_w1 = (fp32p)d_in[28];
    fp32p dec_b1 = (fp32p)d_in[29];
    fp32p dec_a  = (fp32p)d_in[30];
    fp32p dec_w2 = (fp32p)d_in[31];
    fp32p dec_b2 = (fp32p)d_in[32];

    char* wsb = (char*)d_ws;
    bf16*  Ebf  = (bf16*)(wsb + E_OFF);
    float* h    = (float*)(wsb + H_OFF);
    bf16*  hn   = (bf16*)(wsb + HN_OFF);
    bf16*  qkb  = (bf16*)(wsb + QKV_OFF);             // 4096 x 1024 bf16 (q|k fused)
    bf16*  VTb  = qkb + (size_t)MTOK*QKP;             // 64bh x 64d x 512t bf16 (4MB)
    bf16*  mid  = qkb;                      // ffn mid 4096 x 2048 bf16 (aliases qk+VT)
    bf16*  cat  = qkb;                      // encoder scratch (pitch CATP)
    bf16*  hb   = qkb;                      // decoder bf16 cast of h
    float* y    = (float*)qkb;              // decoder logits fp32

    // transposed bf16 weights (per-layer reuse; enc/dec alias the same region)
    bf16* qkvT = (bf16*)(wsb + WT_OFF);          // 1536 x 512  (wq^T | wk^T | wv^T)
    bf16* woT  = qkvT + 3*512*512;               // 512 x 512
    bf16* f1T  = woT  + 512*512;                 // 2048 x 512
    bf16* f2T  = f1T  + 2048*512;                // 512 x 2048
    bf16* enc1T = qkvT;                          // 512 x 160 (zero-padded K)
    bf16* enc2T = qkvT + 512*160;                // 512 x 512
    bf16* dec1T = qkvT;                          // 512 x 512
    bf16* dec2T = qkvT + 512*512;                // 73 x 512

    dim3 g512(8, 32);      // N=512: BM=128 BN=64  -> 256 blocks
    dim3 gQKV(12, 32);     // N=1536: BM=128 BN=128 -> 384 blocks
    dim3 gF1(16, 32);      // N=2048: BM=128 BN=128 -> 512 blocks

    // encoder weight transposes + encoder
    k_wt<<<dim3(5,16), 256, 0, stream>>>(enc_w1, 2*DOF, DMODEL, enc1T, CATP);   // Kpad=160
    k_wt<<<dim3(16,16), 256, 0, stream>>>(enc_w2, DMODEL, DMODEL, enc2T, DMODEL);
    k_concat<<<(MTOK*CATP+255)/256, 256, 0, stream>>>(x, mask, cat);
    k_gemm<128,64,1,0,1,0,0><<<g512,256,0,stream>>>(cat, CATP, enc1T, CATP, enc_b1, nullptr, nullptr, 0, enc_a1, 0, nullptr, hn, DMODEL, nullptr, MTOK, DMODEL, CATP);
    k_gemm<128,64,1,0,1,1,0><<<g512,256,0,stream>>>(hn, DMODEL, enc2T, DMODEL, enc_b2, nullptr, nullptr, 0, enc_a2, 0, nullptr, h, DMODEL, nullptr, MTOK, DMODEL, DMODEL);
    k_relemb<<<EROWS, 64, 0, stream>>>(rel_w1, rel_b1, rel_a, rel_w2, rel_b2, Ebf);

    for (int l = 0; l < NL; ++l) {
        size_t oW  = (size_t)l*DMODEL*DMODEL;
        size_t oB  = (size_t)l*DMODEL;
        size_t oF1 = (size_t)l*DMODEL*DFF;
        size_t oBF1= (size_t)l*DFF;
        size_t oF2 = (size_t)l*DFF*DMODEL;

        k_wt6<<<3072, 256, 0, stream>>>(wq+oW, wk+oW, wv+oW, wo+oW, fw1+oF1, fw2+oF2,
                                        qkvT, woT, f1T, f2T);
        k_layernorm<<<MTOK, 256, 0, stream>>>(h, ln_g, ln_b, hn);
        // fused QKV: N=1536; q|k -> qkb (pitch 1024), v -> VTb transposed
        k_gemm<128,128,0,0,3,0,1><<<gQKV,256,0,stream>>>(hn, DMODEL, qkvT, DMODEL, bq, bk, bv, oB, nullptr, 0, nullptr, qkb, QKP, VTb, MTOK, 1536, DMODEL);
        k_attn<<<BB*NH*(TT/64), 256, 0, stream>>>(qkb, qkb + 512, VTb, Ebf, hn, QKP);
        k_gemm<128,64,0,1,1,1,0><<<g512,256,0,stream>>>(hn, DMODEL, woT, DMODEL, bo, nullptr, nullptr, oB, nullptr, 0, h, h, DMODEL, nullptr, MTOK, DMODEL, DMODEL);
        k_layernorm<<<MTOK, 256, 0, stream>>>(h, ln_g, ln_b, hn);
        // fused FFN: f1 full N=2048 -> mid; f2 full K=2048 -> h (+resid)
        k_gemm<128,128,1,0,1,0,0><<<gF1,256,0,stream>>>(hn, DMODEL, f1T, DMODEL, fb1, nullptr, nullptr, oBF1, fa, (size_t)l, nullptr, mid, DFF, nullptr, MTOK, DFF, DMODEL);
        k_gemm<128,64,0,1,1,1,0><<<g512,256,0,stream>>>(mid, DFF, f2T, DFF, fb2, nullptr, nullptr, oB, nullptr, 0, h, h, DMODEL, nullptr, MTOK, DMODEL, DFF);
    }

    // decoder weight transposes + decoder
    k_wt<<<dim3(16,16), 256, 0, stream>>>(dec_w1, DMODEL, DMODEL, dec1T, DMODEL);
    k_wt<<<dim3(16,3), 256, 0, stream>>>(dec_w2, DMODEL, DOF+4, dec2T, DMODEL);
    k_cast<<<(MTOK*DMODEL+255)/256, 256, 0, stream>>>(h, hb);
    k_gemm<128,64,1,0,1,0,0><<<g512,256,0,stream>>>(hb, DMODEL, dec1T, DMODEL, dec_b1, nullptr, nullptr, 0, dec_a, 0, nullptr, hn, DMODEL, nullptr, MTOK, DMODEL, DMODEL);
    {
        dim3 g2(2, 32);   // N=73: BN=64 -> 2 col tiles
        k_gemm<128,64,0,0,1,1,0><<<g2,256,0,stream>>>(hn, DMODEL, dec2T, DMODEL, dec_b2, nullptr, nullptr, 0, nullptr, 0, nullptr, y, DOF+4, nullptr, MTOK, DOF+4, DMODEL);
    }
    k_out<<<(MTOK*73+255)/256, 256, 0, stream>>>(y, (float*)d_out);
}

// Round 5
// 1107.729 us; speedup vs baseline: 1.5902x; 1.0745x over previous
//
#include <hip/hip_runtime.h>
#include <hip/hip_bf16.h>

#define DOF 69
#define NL 6
#define NH 8
#define DMODEL 512
#define DFF 2048
#define HD 64
#define BB 8
#define TT 512
#define MTOK (BB*TT)   // 4096
#define EROWS 1040     // 2T-1 = 1023, padded
#define CATP 160       // padded concat pitch (K=138 rounded to 32)
#define QKP 1024       // fused q|k row pitch (v split out transposed)

// workspace layout (bytes) — 34.5 MB total
#define E_OFF     4096u
#define H_OFF     (512u*1024u)
#define HN_OFF    (H_OFF + 8u*1024u*1024u)
#define QKV_OFF   (HN_OFF + 4u*1024u*1024u)      // 16 MB region: qk(8MB)+VT(4MB) / mid(16MB) / scratch
#define WT_OFF    (QKV_OFF + 16u*1024u*1024u)    // 6 MB of bf16 B^T weights (per-layer reuse)

typedef const float* fp32p;
typedef __hip_bfloat16 bf16;
typedef const bf16* bf16p;
typedef __attribute__((ext_vector_type(8))) short bf16x8;  // 8 bf16 (4 VGPRs)
typedef __attribute__((ext_vector_type(4))) short s16x4;   // 4 bf16 (8B store)
typedef __attribute__((ext_vector_type(4))) float f32x4;   // 4 fp32 acc

typedef __attribute__((address_space(1))) const void as1_cvoid;
typedef __attribute__((address_space(3))) void       as3_void;

__device__ __forceinline__ void gload16(const bf16* g, const bf16* l){
    __builtin_amdgcn_global_load_lds((as1_cvoid*)g, (as3_void*)l, 16, 0, 0);
}

__device__ __forceinline__ float b2f(bf16 x){ return __bfloat162float(x); }

// ---------------- concat(x, mask) fp32 -> bf16, zero-padded to pitch CATP ----------------
__global__ __launch_bounds__(256)
void k_concat(fp32p x, fp32p mask, bf16* __restrict__ out){
    int idx = blockIdx.x*256 + threadIdx.x;
    if (idx >= MTOK*CATP) return;
    int row = idx / CATP, c = idx - row*CATP;
    float v = 0.f;
    if (c < DOF) v = x[(size_t)row*DOF + c];
    else if (c < 2*DOF) v = mask[(size_t)row*DOF + (c - DOF)];
    out[idx] = __float2bfloat16(v);
}

// ---------------- cast fp32 -> bf16 ----------------
__global__ __launch_bounds__(256)
void k_cast(const float* __restrict__ in, bf16* __restrict__ out){
    int idx = blockIdx.x*256 + threadIdx.x;
    if (idx >= MTOK*DMODEL) return;
    out[idx] = __float2bfloat16(in[idx]);
}

// ---------------- generic weight transpose-cast: W fp32 (K x N) -> WT bf16 (N x ldk) ----
__global__ __launch_bounds__(256)
void k_wt(fp32p W, int K, int N, bf16* __restrict__ WT, int ldk)
{
    __shared__ float s[32][33];
    const int k0 = blockIdx.x*32, n0 = blockIdx.y*32;
    const int c = threadIdx.x & 31, r0 = threadIdx.x >> 5;
    #pragma unroll
    for (int rr = r0; rr < 32; rr += 8) {
        int k = k0 + rr, n = n0 + c;
        s[rr][c] = (k < K && n < N) ? W[(size_t)k*N + n] : 0.f;
    }
    __syncthreads();
    #pragma unroll
    for (int rr = r0; rr < 32; rr += 8) {
        int n = n0 + rr;
        if (n < N) WT[(size_t)n*ldk + k0 + c] = __float2bfloat16(s[c][rr]);
    }
}

// ---------------- per-layer batched transpose: wq,wk,wv,wo,fw1,fw2 -> bf16 B^T ----------
__global__ __launch_bounds__(256)
void k_wt6(fp32p wq, fp32p wk, fp32p wv, fp32p wo, fp32p fw1, fp32p fw2,
           bf16* __restrict__ qkvT, bf16* __restrict__ woT,
           bf16* __restrict__ f1T, bf16* __restrict__ f2T)
{
    __shared__ float s[32][33];
    const int t = blockIdx.x;
    fp32p src; bf16* dst; int N, ldk, k0, n0;
    if (t < 1024) {
        int seg = t >> 8, local = t & 255;
        N = 512; ldk = 512;
        k0 = (local & 15) * 32; n0 = (local >> 4) * 32;
        if      (seg == 0) { src = wq; dst = qkvT; }
        else if (seg == 1) { src = wk; dst = qkvT + 512*512; }
        else if (seg == 2) { src = wv; dst = qkvT + 2*512*512; }
        else               { src = wo; dst = woT; }
    } else if (t < 2048) {
        int local = t - 1024;
        N = 2048; ldk = 512;
        k0 = (local & 15) * 32; n0 = (local >> 4) * 32;
        src = fw1; dst = f1T;
    } else {
        int local = t - 2048;
        N = 512; ldk = 2048;
        k0 = (local >> 4) * 32; n0 = (local & 15) * 32;
        src = fw2; dst = f2T;
    }
    const int c = threadIdx.x & 31, r0 = threadIdx.x >> 5;
    #pragma unroll
    for (int rr = r0; rr < 32; rr += 8)
        s[rr][c] = src[(size_t)(k0+rr)*N + n0 + c];
    __syncthreads();
    #pragma unroll
    for (int rr = r0; rr < 32; rr += 8)
        dst[(size_t)(n0+rr)*ldk + k0 + c] = __float2bfloat16(s[c][rr]);
}

// ---------------- LDS-tiled MFMA GEMM (m97 structure + 2-phase pipeline) ----------------
// C = epi(A @ B + bias); A bf16 (M x K) lda; BT bf16 (N x ldk) = B^T.
// Block = 256 threads (4 waves, 2x2 wave grid), tile BM x BN, BK=32.
// global_load_lds (16B) stages A/B tiles into double-buffered linear LDS; chunk-XOR
// swizzle on GLOBAL source + LDS READ (both-sides involution).
// One barrier per K-step: stage(k+1) issued before compute(k).
// XCD-aware chunked block swizzle (T1/m204): each XCD owns contiguous x-rows of the
// grid -> every A-panel is fetched by exactly one XCD's L2.
// BIAS: 0=none, 1=bias[], 3=segment-select of {bias,bias2,bias3} by col/512.
// SPLITV: blocks with bn>=1024 write transposed per-head VT[b][h][d][t] (QKV fusion).
template<int BM, int BN, int PRELU, int RESID, int BIAS, int OUTF32, int SPLITV>
__global__ __launch_bounds__(256)
void k_gemm(bf16p A, int lda,
            bf16p BT, int ldk,
            fp32p bias, fp32p bias2, fp32p bias3, size_t biasoff,
            fp32p alpha, size_t aidx,
            const float* __restrict__ resid,
            void* __restrict__ Cout, int ldc,
            bf16* __restrict__ VTout,
            int M, int N, int K)
{
    constexpr int MF = BM/32;   // m-fragments per wave
    constexpr int NF = BN/32;   // n-fragments per wave
    constexpr int AI = BM/64;   // A stage issues per wave
    constexpr int BI = BN/64;   // B stage issues per wave

    __shared__ __attribute__((aligned(16))) bf16 sA[2][BM*32];
    __shared__ __attribute__((aligned(16))) bf16 sB[2][BN*32];

    // XCD-aware bijective swizzle (m204): xcd = bid&7 keeps HW round-robin mapping,
    // each XCD gets a contiguous chunk of the x-major grid order.
    int bx, by;
    {
        const int gx  = gridDim.x;
        const int nwg = gx * gridDim.y;
        const int bid = blockIdx.y * gx + blockIdx.x;
        const int qq = nwg >> 3, rr = nwg & 7;
        const int xcd = bid & 7, pos = bid >> 3;
        const int nb = (xcd < rr) ? (xcd*(qq+1) + pos) : (rr*(qq+1) + (xcd-rr)*qq + pos);
        bx = nb % gx; by = nb / gx;
    }

    const int tid  = threadIdx.x;
    const int w    = tid >> 6;
    const int lane = tid & 63;
    const int qd   = lane >> 4;
    const int cl   = lane & 15;
    const int wr   = w >> 1;
    const int wc   = w & 1;
    const int bm   = by * BM;
    const int bn   = bx * BN;

    const int sc = (lane & 3) ^ ((lane >> 3) & 3);    // source chunk (staging)
    const int rc = qd ^ ((cl >> 1) & 3);              // read chunk (fragments)

    const bf16* aG = A + (size_t)(bm + w*(BM/4) + (lane >> 2))*lda + sc*8;
    const bf16* bG[BI];
    #pragma unroll
    for (int i = 0; i < BI; ++i) {
        int rrow = min(bn + w*(BN/4) + i*16 + (lane >> 2), N-1);
        bG[i] = BT + (size_t)rrow*ldk + sc*8;
    }

    f32x4 acc[MF][NF] = {};

    auto stage = [&](int p, int k0){
        #pragma unroll
        for (int i = 0; i < AI; ++i)
            gload16(aG + (size_t)(i*16)*lda + k0, &sA[p][(w*(BM/4) + i*16)*32]);
        #pragma unroll
        for (int i = 0; i < BI; ++i)
            gload16(bG[i] + k0, &sB[p][(w*(BN/4) + i*16)*32]);
    };

    stage(0, 0);
    int p = 0;
    for (int k0 = 0; k0 < K; k0 += 32) {
        __syncthreads();
        if (k0 + 32 < K) stage(p^1, k0 + 32);
        bf16x8 aF[MF], bF[NF];
        #pragma unroll
        for (int mt = 0; mt < MF; ++mt)
            aF[mt] = *(const bf16x8*)(&sA[p][(wr*(BM/2) + mt*16 + cl)*32 + rc*8]);
        #pragma unroll
        for (int nt = 0; nt < NF; ++nt)
            bF[nt] = *(const bf16x8*)(&sB[p][(wc*(BN/2) + nt*16 + cl)*32 + rc*8]);
        #pragma unroll
        for (int mt = 0; mt < MF; ++mt)
            #pragma unroll
            for (int nt = 0; nt < NF; ++nt)
                acc[mt][nt] = __builtin_amdgcn_mfma_f32_16x16x32_bf16(aF[mt], bF[nt], acc[mt][nt], 0, 0, 0);
        p ^= 1;
    }

    if (SPLITV && bn >= 1024) {
        // V segment: write transposed VT[((b*8+h)*64+hd)*512 + t], 8B short4 stores
        #pragma unroll
        for (int nt = 0; nt < NF; ++nt) {
            int col = bn + wc*(BN/2) + nt*16 + cl;
            float bv = bias3[biasoff + (col & 511)];
            int hh = (col >> 6) & 7;
            int hd = col & 63;
            #pragma unroll
            for (int mt = 0; mt < MF; ++mt) {
                int row0 = bm + wr*(BM/2) + mt*16 + qd*4;
                int bb = row0 >> 9, t = row0 & 511;
                s16x4 v4;
                #pragma unroll
                for (int r = 0; r < 4; ++r) {
                    bf16 cb = __float2bfloat16(acc[mt][nt][r] + bv);
                    v4[r] = *reinterpret_cast<short*>(&cb);
                }
                *(s16x4*)(VTout + ((size_t)((bb*8 + hh)*64 + hd))*512 + t) = v4;
            }
        }
        return;
    }

    const float alp = PRELU ? alpha[aidx] : 0.f;
    fp32p bsel = bias;
    if (BIAS == 3) bsel = (bn < 512) ? bias : ((bn < 1024) ? bias2 : bias3);
    #pragma unroll
    for (int nt = 0; nt < NF; ++nt) {
        int col = bn + wc*(BN/2) + nt*16 + cl;
        if (col < N) {
            float bv = 0.f;
            if (BIAS == 1) bv = bsel[biasoff + col];
            if (BIAS == 3) bv = bsel[biasoff + (col & 511)];
            #pragma unroll
            for (int mt = 0; mt < MF; ++mt) {
                #pragma unroll
                for (int r = 0; r < 4; ++r) {
                    int row = bm + wr*(BM/2) + mt*16 + qd*4 + r;
                    float c = acc[mt][nt][r] + bv;
                    if (PRELU) c = (c >= 0.f) ? c : alp*c;
                    if (RESID) c += resid[(size_t)row*ldc + col];
                    if (OUTF32) ((float*)Cout)[(size_t)row*ldc + col] = c;
                    else ((bf16*)Cout)[(size_t)row*ldc + col] = __float2bfloat16(c);
                }
            }
        }
    }
}

// ---------------- LayerNorm: fp32 in -> bf16 out ----------------
__global__ __launch_bounds__(256)
void k_layernorm(const float* __restrict__ x, fp32p g, fp32p b, bf16* __restrict__ out){
    __shared__ float red[256];
    const int row = blockIdx.x, tid = threadIdx.x;
    const float* xr = x + (size_t)row*DMODEL;
    float x0 = xr[tid], x1 = xr[tid+256];
    red[tid] = x0 + x1; __syncthreads();
    for (int o = 128; o > 0; o >>= 1) { if (tid < o) red[tid] += red[tid+o]; __syncthreads(); }
    float mean = red[0] * (1.f/DMODEL);
    __syncthreads();
    float d0 = x0 - mean, d1 = x1 - mean;
    red[tid] = d0*d0 + d1*d1; __syncthreads();
    for (int o = 128; o > 0; o >>= 1) { if (tid < o) red[tid] += red[tid+o]; __syncthreads(); }
    float inv = rsqrtf(red[0]*(1.f/DMODEL) + 1e-6f);
    out[(size_t)row*DMODEL + tid]     = __float2bfloat16(d0*inv*g[tid]     + b[tid]);
    out[(size_t)row*DMODEL + tid+256] = __float2bfloat16(d1*inv*g[tid+256] + b[tid+256]);
}

// ---------------- relative embedding E: (EROWS, HD) bf16, zero-padded ----------------
__global__ __launch_bounds__(64)
void k_relemb(fp32p w1, fp32p b1, fp32p a, fp32p w2, fp32p b2, bf16* __restrict__ Ebf){
    __shared__ float sH[DMODEL];
    const int r = blockIdx.x, tid = threadIdx.x;
    if (r >= 2*TT - 1) { Ebf[(size_t)r*HD + tid] = __float2bfloat16(0.f); return; }
    const float dist = (float)(r - (TT-1));
    const float al = a[0];
    for (int d = tid; d < DMODEL; d += 64) {
        float hv = dist * w1[d] + b1[d];
        sH[d] = (hv >= 0.f) ? hv : al*hv;
    }
    __syncthreads();
    float acc = b2[tid];
    for (int d = 0; d < DMODEL; ++d) acc += sH[d] * w2[(size_t)d*HD + tid];
    Ebf[(size_t)r*HD + tid] = __float2bfloat16(acc);
}

// ---------------- MFMA flash attention with relative-position skew ----------------
// q,k row pitch qp (fused q|k buffer); V pre-transposed VT[b][h][d][t]; out pitch DMODEL.
// All LDS tiles 16B-aligned with chunk-XOR swizzles -> ds_read_b128 fragment loads.
// XCD-aware bid decode: itile in HIGH bits so all 8 i-tiles of one (b,h) share
// bid mod 8 -> same XCD -> K/VT tiles fetched once per XCD L2 (not 8x from HBM).
__global__ __launch_bounds__(256)
void k_attn(bf16p q, bf16p k, bf16p VT, bf16p Ebf, bf16* __restrict__ o, int qp)
{
    __shared__ __attribute__((aligned(16))) bf16 sV[2][2][64*32]; // [buf][jhalf][d][chunk] 16KB
    __shared__ float sQE[4][16][100];                             // per-wave qe tile
    __shared__ __attribute__((aligned(16))) bf16 sP[4][16*64];    // per-wave P tile

    const int bid  = blockIdx.x;
    const int itile = bid >> 6;        // high bits: same-(b,h) group stays on one XCD
    const int h    = bid & 7;
    const int b    = (bid >> 3) & 7;
    const int tid  = threadIdx.x;
    const int w    = tid >> 6;
    const int lane = tid & 63;
    const int qd   = lane >> 4;
    const int cl   = lane & 15;

    const int I = itile*64 + w*16;
    const size_t bh = ((size_t)b*TT)*qp + (size_t)h*HD;
    const size_t boff = ((size_t)b*TT)*DMODEL + (size_t)h*HD;

    // V^T staging: thread -> (d=tid>>2, chunk=tid&3), swizzled global source chunk
    const int srow = tid >> 2, schunk = tid & 3;
    const int ssc = schunk ^ ((srow >> 1) & 3);
    const bf16* vtb = VT + ((size_t)((b*8 + h)*64 + srow))*512 + ssc*8;
    const int ldsoff = srow*32 + schunk*8;
    const int rc = qd ^ ((cl >> 1) & 3);    // fragment read chunk

    bf16x8 qa0, qa1;
    {
        const bf16* qrow = q + bh + (size_t)(I + cl)*qp;
        qa0 = *(const bf16x8*)(qrow + qd*8);
        qa1 = *(const bf16x8*)(qrow + 32 + qd*8);
    }

    f32x4 Oacc[4] = {};
    float m_i[4], l_i[4];
    #pragma unroll
    for (int r = 0; r < 4; ++r) { m_i[r] = -1e30f; l_i[r] = 0.f; }
    const float scale = 0.125f;

    gload16(vtb,      &sV[0][0][ldsoff]);
    gload16(vtb + 32, &sV[0][1][ldsoff]);
    int p = 0;

    for (int J = 0; J < TT; J += 64) {
        // ---- QK^T from global (L2-hot K) ----
        f32x4 S[4];
        #pragma unroll
        for (int js = 0; js < 4; ++js) {
            const bf16* krow = k + bh + (size_t)(J + js*16 + cl)*qp;
            bf16x8 kb0 = *(const bf16x8*)(krow + qd*8);
            bf16x8 kb1 = *(const bf16x8*)(krow + 32 + qd*8);
            f32x4 acc = {};
            acc = __builtin_amdgcn_mfma_f32_16x16x32_bf16(qa0, kb0, acc, 0, 0, 0);
            acc = __builtin_amdgcn_mfma_f32_16x16x32_bf16(qa1, kb1, acc, 0, 0, 0);
            S[js] = acc;
        }

        // ---- QE (per-wave LDS, 2-way banks) ----
        const int rbase = J - I + 496;
        #pragma unroll
        for (int nt = 0; nt < 6; ++nt) {
            const bf16* erow = Ebf + (size_t)(rbase + nt*16 + cl)*HD;
            bf16x8 eb0 = *(const bf16x8*)(erow + qd*8);
            bf16x8 eb1 = *(const bf16x8*)(erow + 32 + qd*8);
            f32x4 acc = {};
            acc = __builtin_amdgcn_mfma_f32_16x16x32_bf16(qa0, eb0, acc, 0, 0, 0);
            acc = __builtin_amdgcn_mfma_f32_16x16x32_bf16(qa1, eb1, acc, 0, 0, 0);
            #pragma unroll
            for (int r = 0; r < 4; ++r)
                sQE[w][qd*4 + r][nt*16 + cl] = acc[r];
        }

        // ---- skew add + online softmax ----
        float mnew[4];
        #pragma unroll
        for (int r = 0; r < 4; ++r) mnew[r] = m_i[r];
        #pragma unroll
        for (int js = 0; js < 4; ++js) {
            #pragma unroll
            for (int r = 0; r < 4; ++r) {
                int idx = js*16 + cl - (qd*4 + r) + 15;
                float s = S[js][r] + sQE[w][qd*4 + r][idx];
                S[js][r] = s;
                mnew[r] = fmaxf(mnew[r], s);
            }
        }
        #pragma unroll
        for (int r = 0; r < 4; ++r) {
            float mv = mnew[r];
            mv = fmaxf(mv, __shfl_xor(mv, 1));
            mv = fmaxf(mv, __shfl_xor(mv, 2));
            mv = fmaxf(mv, __shfl_xor(mv, 4));
            mv = fmaxf(mv, __shfl_xor(mv, 8));
            mnew[r] = mv;
        }
        float alpha[4], rsum[4];
        #pragma unroll
        for (int r = 0; r < 4; ++r) {
            alpha[r] = __expf((m_i[r] - mnew[r]) * scale);
            m_i[r] = mnew[r];
            rsum[r] = 0.f;
        }
        // P -> per-wave LDS [16][64], chunk ^ (row&7) swizzle
        #pragma unroll
        for (int js = 0; js < 4; ++js) {
            #pragma unroll
            for (int r = 0; r < 4; ++r) {
                float pv = __expf((S[js][r] - m_i[r]) * scale);
                rsum[r] += pv;
                int prow = qd*4 + r;
                int pcol = ((js*2 + (cl >> 3)) ^ (prow & 7))*8 + (cl & 7);
                sP[w][prow*64 + pcol] = __float2bfloat16(pv);
            }
        }
        #pragma unroll
        for (int r = 0; r < 4; ++r) {
            float sv = rsum[r];
            sv += __shfl_xor(sv, 1);
            sv += __shfl_xor(sv, 2);
            sv += __shfl_xor(sv, 4);
            sv += __shfl_xor(sv, 8);
            l_i[r] = l_i[r]*alpha[r] + sv;
        }

        // P fragments: aligned b128 with the same involution
        bf16x8 pa0, pa1;
        {
            const int c0 = qd ^ (cl & 7);
            const bf16* pb = &sP[w][cl*64];
            pa0 = *(const bf16x8*)(pb + c0*8);
            pa1 = *(const bf16x8*)(pb + (c0 ^ 4)*8);
        }

        __syncthreads();                       // sV[p] staged & prior reads drained
        if (J + 64 < TT) {                     // prefetch next V tile under PV
            gload16(vtb + J + 64, &sV[p^1][0][ldsoff]);
            gload16(vtb + J + 96, &sV[p^1][1][ldsoff]);
        }

        // ---- PV: aligned b128 V^T fragments ----
        #pragma unroll
        for (int nt = 0; nt < 4; ++nt) {
            #pragma unroll
            for (int r = 0; r < 4; ++r) Oacc[nt][r] *= alpha[r];
            bf16x8 vb0 = *(const bf16x8*)(&sV[p][0][(nt*16 + cl)*32 + rc*8]);
            bf16x8 vb1 = *(const bf16x8*)(&sV[p][1][(nt*16 + cl)*32 + rc*8]);
            Oacc[nt] = __builtin_amdgcn_mfma_f32_16x16x32_bf16(pa0, vb0, Oacc[nt], 0, 0, 0);
            Oacc[nt] = __builtin_amdgcn_mfma_f32_16x16x32_bf16(pa1, vb1, Oacc[nt], 0, 0, 0);
        }
        p ^= 1;
    }

    #pragma unroll
    for (int nt = 0; nt < 4; ++nt) {
        #pragma unroll
        for (int r = 0; r < 4; ++r) {
            int row = qd*4 + r;
            float val = Oacc[nt][r] / l_i[r];
            o[boff + (size_t)(I + row)*DMODEL + nt*16 + cl] = __float2bfloat16(val);
        }
    }
}

// ---------------- output split + sigmoid (fp32 out) ----------------
__global__ __launch_bounds__(256)
void k_out(const float* __restrict__ y, float* __restrict__ out){
    int idx = blockIdx.x*256 + threadIdx.x;
    if (idx >= MTOK*73) return;
    int row = idx / 73, c = idx - row*73;
    float val = y[idx];
    if (c < DOF) out[(size_t)row*DOF + c] = val;
    else out[(size_t)MTOK*DOF + row*4 + (c-DOF)] = 1.f/(1.f + expf(-val));
}

extern "C" void kernel_launch(void* const* d_in, const int* in_sizes, int n_in,
                              void* d_out, int out_size, void* d_ws, size_t ws_size,
                              hipStream_t stream)
{
    fp32p x      = (fp32p)d_in[0];
    fp32p mask   = (fp32p)d_in[1];
    fp32p enc_w1 = (fp32p)d_in[2];
    fp32p enc_b1 = (fp32p)d_in[3];
    fp32p enc_a1 = (fp32p)d_in[4];
    fp32p enc_w2 = (fp32p)d_in[5];
    fp32p enc_b2 = (fp32p)d_in[6];
    fp32p enc_a2 = (fp32p)d_in[7];
    fp32p rel_w1 = (fp32p)d_in[8];
    fp32p rel_b1 = (fp32p)d_in[9];
    fp32p rel_a  = (fp32p)d_in[10];
    fp32p rel_w2 = (fp32p)d_in[11];
    fp32p rel_b2 = (fp32p)d_in[12];
    fp32p ln_g   = (fp32p)d_in[13];
    fp32p ln_b   = (fp32p)d_in[14];
    fp32p wq     = (fp32p)d_in[15];
    fp32p bq     = (fp32p)d_in[16];
    fp32p wk     = (fp32p)d_in[17];
    fp32p bk     = (fp32p)d_in[18];
    fp32p wv     = (fp32p)d_in[19];
    fp32p bv     = (fp32p)d_in[20];
    fp32p wo     = (fp32p)d_in[21];
    fp32p bo     = (fp32p)d_in[22];
    fp32p fw1    = (fp32p)d_in[23];
    fp32p fb1    = (fp32p)d_in[24];
    fp32p fa     = (fp32p)d_in[25];
    fp32p fw2    = (fp32p)d_in[26];
    fp32p fb2    = (fp32p)d_in[27];
    fp32p dec_w1 = (fp32p)d_in[28];
    fp32p dec_b1 = (fp32p)d_in[29];
    fp32p dec_a  = (fp32p)d_in[30];
    fp32p dec_w2 = (fp32p)d_in[31];
    fp32p dec_b2 = (fp32p)d_in[32];

    char* wsb = (char*)d_ws;
    bf16*  Ebf  = (bf16*)(wsb + E_OFF);
    float* h    = (float*)(wsb + H_OFF);
    bf16*  hn   = (bf16*)(wsb + HN_OFF);
    bf16*  qkb  = (bf16*)(wsb + QKV_OFF);             // 4096 x 1024 bf16 (q|k fused)
    bf16*  VTb  = qkb + (size_t)MTOK*QKP;             // 64bh x 64d x 512t bf16 (4MB)
    bf16*  mid  = qkb;                      // ffn mid 4096 x 2048 bf16 (aliases qk+VT)
    bf16*  cat  = qkb;                      // encoder scratch (pitch CATP)
    bf16*  hb   = qkb;                      // decoder bf16 cast of h
    float* y    = (float*)qkb;              // decoder logits fp32

    // transposed bf16 weights (per-layer reuse; enc/dec alias the same region)
    bf16* qkvT = (bf16*)(wsb + WT_OFF);          // 1536 x 512  (wq^T | wk^T | wv^T)
    bf16* woT  = qkvT + 3*512*512;               // 512 x 512
    bf16* f1T  = woT  + 512*512;                 // 2048 x 512
    bf16* f2T  = f1T  + 2048*512;                // 512 x 2048
    bf16* enc1T = qkvT;                          // 512 x 160 (zero-padded K)
    bf16* enc2T = qkvT + 512*160;                // 512 x 512
    bf16* dec1T = qkvT;                          // 512 x 512
    bf16* dec2T = qkvT + 512*512;                // 73 x 512

    dim3 g512(8, 32);      // N=512: BM=128 BN=64  -> 256 blocks
    dim3 gQKV(12, 32);     // N=1536: BM=128 BN=128 -> 384 blocks
    dim3 gF1(16, 32);      // N=2048: BM=128 BN=128 -> 512 blocks

    // encoder weight transposes + encoder
    k_wt<<<dim3(5,16), 256, 0, stream>>>(enc_w1, 2*DOF, DMODEL, enc1T, CATP);   // Kpad=160
    k_wt<<<dim3(16,16), 256, 0, stream>>>(enc_w2, DMODEL, DMODEL, enc2T, DMODEL);
    k_concat<<<(MTOK*CATP+255)/256, 256, 0, stream>>>(x, mask, cat);
    k_gemm<128,64,1,0,1,0,0><<<g512,256,0,stream>>>(cat, CATP, enc1T, CATP, enc_b1, nullptr, nullptr, 0, enc_a1, 0, nullptr, hn, DMODEL, nullptr, MTOK, DMODEL, CATP);
    k_gemm<128,64,1,0,1,1,0><<<g512,256,0,stream>>>(hn, DMODEL, enc2T, DMODEL, enc_b2, nullptr, nullptr, 0, enc_a2, 0, nullptr, h, DMODEL, nullptr, MTOK, DMODEL, DMODEL);
    k_relemb<<<EROWS, 64, 0, stream>>>(rel_w1, rel_b1, rel_a, rel_w2, rel_b2, Ebf);

    for (int l = 0; l < NL; ++l) {
        size_t oW  = (size_t)l*DMODEL*DMODEL;
        size_t oB  = (size_t)l*DMODEL;
        size_t oF1 = (size_t)l*DMODEL*DFF;
        size_t oBF1= (size_t)l*DFF;
        size_t oF2 = (size_t)l*DFF*DMODEL;

        k_wt6<<<3072, 256, 0, stream>>>(wq+oW, wk+oW, wv+oW, wo+oW, fw1+oF1, fw2+oF2,
                                        qkvT, woT, f1T, f2T);
        k_layernorm<<<MTOK, 256, 0, stream>>>(h, ln_g, ln_b, hn);
        // fused QKV: N=1536; q|k -> qkb (pitch 1024), v -> VTb transposed
        k_gemm<128,128,0,0,3,0,1><<<gQKV,256,0,stream>>>(hn, DMODEL, qkvT, DMODEL, bq, bk, bv, oB, nullptr, 0, nullptr, qkb, QKP, VTb, MTOK, 1536, DMODEL);
        k_attn<<<BB*NH*(TT/64), 256, 0, stream>>>(qkb, qkb + 512, VTb, Ebf, hn, QKP);
        k_gemm<128,64,0,1,1,1,0><<<g512,256,0,stream>>>(hn, DMODEL, woT, DMODEL, bo, nullptr, nullptr, oB, nullptr, 0, h, h, DMODEL, nullptr, MTOK, DMODEL, DMODEL);
        k_layernorm<<<MTOK, 256, 0, stream>>>(h, ln_g, ln_b, hn);
        // fused FFN: f1 full N=2048 -> mid; f2 full K=2048 -> h (+resid)
        k_gemm<128,128,1,0,1,0,0><<<gF1,256,0,stream>>>(hn, DMODEL, f1T, DMODEL, fb1, nullptr, nullptr, oBF1, fa, (size_t)l, nullptr, mid, DFF, nullptr, MTOK, DFF, DMODEL);
        k_gemm<128,64,0,1,1,1,0><<<g512,256,0,stream>>>(mid, DFF, f2T, DFF, fb2, nullptr, nullptr, oB, nullptr, 0, h, h, DMODEL, nullptr, MTOK, DMODEL, DFF);
    }

    // decoder weight transposes + decoder
    k_wt<<<dim3(16,16), 256, 0, stream>>>(dec_w1, DMODEL, DMODEL, dec1T, DMODEL);
    k_wt<<<dim3(16,3), 256, 0, stream>>>(dec_w2, DMODEL, DOF+4, dec2T, DMODEL);
    k_cast<<<(MTOK*DMODEL+255)/256, 256, 0, stream>>>(h, hb);
    k_gemm<128,64,1,0,1,0,0><<<g512,256,0,stream>>>(hb, DMODEL, dec1T, DMODEL, dec_b1, nullptr, nullptr, 0, dec_a, 0, nullptr, hn, DMODEL, nullptr, MTOK, DMODEL, DMODEL);
    {
        dim3 g2(2, 32);   // N=73: BN=64 -> 2 col tiles
        k_gemm<128,64,0,0,1,1,0><<<g2,256,0,stream>>>(hn, DMODEL, dec2T, DMODEL, dec_b2, nullptr, nullptr, 0, nullptr, 0, nullptr, y, DOF+4, nullptr, MTOK, DOF+4, DMODEL);
    }
    k_out<<<(MTOK*73+255)/256, 256, 0, stream>>>(y, (float*)d_out);
}

// Round 6
// 1033.886 us; speedup vs baseline: 1.7038x; 1.0714x over previous
//
#include <hip/hip_runtime.h>
#include <hip/hip_bf16.h>

#define DOF 69
#define NL 6
#define NH 8
#define DMODEL 512
#define DFF 2048
#define HD 64
#define BB 8
#define TT 512
#define MTOK (BB*TT)   // 4096
#define EROWS 1040     // 2T-1 = 1023, padded
#define CATP 192       // padded concat pitch (K=138 rounded to 64)
#define QKP 1024       // fused q|k row pitch (v split out transposed)

// workspace layout (bytes) — 34.5 MB total
#define E_OFF     4096u
#define H_OFF     (512u*1024u)
#define HN_OFF    (H_OFF + 8u*1024u*1024u)
#define QKV_OFF   (HN_OFF + 4u*1024u*1024u)      // 16 MB region: qk(8MB)+VT(4MB) / mid(16MB) / scratch
#define WT_OFF    (QKV_OFF + 16u*1024u*1024u)    // 6 MB of bf16 B^T weights (per-layer reuse)

typedef const float* fp32p;
typedef __hip_bfloat16 bf16;
typedef const bf16* bf16p;
typedef __attribute__((ext_vector_type(8))) short bf16x8;  // 8 bf16 (4 VGPRs)
typedef __attribute__((ext_vector_type(4))) short s16x4;   // 4 bf16 (8B store)
typedef __attribute__((ext_vector_type(4))) float f32x4;   // 4 fp32 acc

typedef __attribute__((address_space(1))) const void as1_cvoid;
typedef __attribute__((address_space(3))) void       as3_void;

__device__ __forceinline__ void gload16(const bf16* g, const bf16* l){
    __builtin_amdgcn_global_load_lds((as1_cvoid*)g, (as3_void*)l, 16, 0, 0);
}

__device__ __forceinline__ float b2f(bf16 x){ return __bfloat162float(x); }

// ---------------- concat(x, mask) fp32 -> bf16, zero-padded to pitch CATP ----------------
__global__ __launch_bounds__(256)
void k_concat(fp32p x, fp32p mask, bf16* __restrict__ out){
    int idx = blockIdx.x*256 + threadIdx.x;
    if (idx >= MTOK*CATP) return;
    int row = idx / CATP, c = idx - row*CATP;
    float v = 0.f;
    if (c < DOF) v = x[(size_t)row*DOF + c];
    else if (c < 2*DOF) v = mask[(size_t)row*DOF + (c - DOF)];
    out[idx] = __float2bfloat16(v);
}

// ---------------- cast fp32 -> bf16 ----------------
__global__ __launch_bounds__(256)
void k_cast(const float* __restrict__ in, bf16* __restrict__ out){
    int idx = blockIdx.x*256 + threadIdx.x;
    if (idx >= MTOK*DMODEL) return;
    out[idx] = __float2bfloat16(in[idx]);
}

// ---------------- generic weight transpose-cast: W fp32 (K x N) -> WT bf16 (N x ldk) ----
__global__ __launch_bounds__(256)
void k_wt(fp32p W, int K, int N, bf16* __restrict__ WT, int ldk)
{
    __shared__ float s[32][33];
    const int k0 = blockIdx.x*32, n0 = blockIdx.y*32;
    const int c = threadIdx.x & 31, r0 = threadIdx.x >> 5;
    #pragma unroll
    for (int rr = r0; rr < 32; rr += 8) {
        int k = k0 + rr, n = n0 + c;
        s[rr][c] = (k < K && n < N) ? W[(size_t)k*N + n] : 0.f;
    }
    __syncthreads();
    #pragma unroll
    for (int rr = r0; rr < 32; rr += 8) {
        int n = n0 + rr;
        if (n < N) WT[(size_t)n*ldk + k0 + c] = __float2bfloat16(s[c][rr]);
    }
}

// ---------------- per-layer batched transpose: wq,wk,wv,wo,fw1,fw2 -> bf16 B^T ----------
__global__ __launch_bounds__(256)
void k_wt6(fp32p wq, fp32p wk, fp32p wv, fp32p wo, fp32p fw1, fp32p fw2,
           bf16* __restrict__ qkvT, bf16* __restrict__ woT,
           bf16* __restrict__ f1T, bf16* __restrict__ f2T)
{
    __shared__ float s[32][33];
    const int t = blockIdx.x;
    fp32p src; bf16* dst; int N, ldk, k0, n0;
    if (t < 1024) {
        int seg = t >> 8, local = t & 255;
        N = 512; ldk = 512;
        k0 = (local & 15) * 32; n0 = (local >> 4) * 32;
        if      (seg == 0) { src = wq; dst = qkvT; }
        else if (seg == 1) { src = wk; dst = qkvT + 512*512; }
        else if (seg == 2) { src = wv; dst = qkvT + 2*512*512; }
        else               { src = wo; dst = woT; }
    } else if (t < 2048) {
        int local = t - 1024;
        N = 2048; ldk = 512;
        k0 = (local & 15) * 32; n0 = (local >> 4) * 32;
        src = fw1; dst = f1T;
    } else {
        int local = t - 2048;
        N = 512; ldk = 2048;
        k0 = (local >> 4) * 32; n0 = (local & 15) * 32;
        src = fw2; dst = f2T;
    }
    const int c = threadIdx.x & 31, r0 = threadIdx.x >> 5;
    #pragma unroll
    for (int rr = r0; rr < 32; rr += 8)
        s[rr][c] = src[(size_t)(k0+rr)*N + n0 + c];
    __syncthreads();
    #pragma unroll
    for (int rr = r0; rr < 32; rr += 8)
        dst[(size_t)(n0+rr)*ldk + k0 + c] = __float2bfloat16(s[c][rr]);
}

// ---------------- LDS-tiled MFMA GEMM (BK=64, 2-phase pipeline) ----------------
// C = epi(A @ B + bias); A bf16 (M x K) lda; BT bf16 (N x ldk) = B^T.
// Block = 256 threads (4 waves, 2x2 wave grid), tile BM x BN, BK=64 (one barrier per
// 64-K slab -> half the vmcnt drains vs BK=32, 16 MFMA/wave per barrier).
// global_load_lds (16B) stages into double-buffered linear LDS; 8-chunk XOR swizzle
// (chunk ^ row&7) applied on GLOBAL source and LDS READ (both-sides involution).
// XCD-aware chunked block swizzle (T1/m204). Requires K%64==0, M%BM==0.
// BIAS: 0=none, 1=bias[], 3=segment-select of {bias,bias2,bias3} by col/512.
// SPLITV: blocks with bn>=1024 write transposed per-head VT[b][h][d][t] (QKV fusion).
template<int BM, int BN, int PRELU, int RESID, int BIAS, int OUTF32, int SPLITV>
__global__ __launch_bounds__(256)
void k_gemm(bf16p A, int lda,
            bf16p BT, int ldk,
            fp32p bias, fp32p bias2, fp32p bias3, size_t biasoff,
            fp32p alpha, size_t aidx,
            const float* __restrict__ resid,
            void* __restrict__ Cout, int ldc,
            bf16* __restrict__ VTout,
            int M, int N, int K)
{
    constexpr int MF = BM/32;   // m-fragments per wave
    constexpr int NF = BN/32;   // n-fragments per wave
    constexpr int AI = BM/32;   // A stage issues per wave (8 rows x 128B each)
    constexpr int BI = BN/32;   // B stage issues per wave

    __shared__ __attribute__((aligned(16))) bf16 sA[2][BM*64];
    __shared__ __attribute__((aligned(16))) bf16 sB[2][BN*64];

    // XCD-aware bijective swizzle (m204): xcd = bid&7 keeps HW round-robin mapping,
    // each XCD gets a contiguous chunk of the x-major grid order.
    int bx, by;
    {
        const int gx  = gridDim.x;
        const int nwg = gx * gridDim.y;
        const int bid = blockIdx.y * gx + blockIdx.x;
        const int qq = nwg >> 3, rr = nwg & 7;
        const int xcd = bid & 7, pos = bid >> 3;
        const int nb = (xcd < rr) ? (xcd*(qq+1) + pos) : (rr*(qq+1) + (xcd-rr)*qq + pos);
        bx = nb % gx; by = nb / gx;
    }

    const int tid  = threadIdx.x;
    const int w    = tid >> 6;
    const int lane = tid & 63;
    const int qd   = lane >> 4;
    const int cl   = lane & 15;
    const int wr   = w >> 1;
    const int wc   = w & 1;
    const int bm   = by * BM;
    const int bn   = bx * BN;

    // staging: lane -> (row = lane>>3 within 8-row group, chunk = lane&7 of 8x16B row)
    // source chunk = chunk ^ (row&7) so LDS stays linear while reads unswizzle.
    const int ssc = (lane & 7) ^ ((lane >> 3) & 7);

    const bf16* aG = A + (size_t)(bm + w*(BM/4) + (lane >> 3))*lda + ssc*8;
    const bf16* bG[BI];
    #pragma unroll
    for (int i = 0; i < BI; ++i) {
        int rrow = min(bn + w*(BN/4) + i*8 + (lane >> 3), N-1);
        bG[i] = BT + (size_t)rrow*ldk + ssc*8;
    }

    f32x4 acc[MF][NF] = {};

    auto stage = [&](int p, int k0){
        #pragma unroll
        for (int i = 0; i < AI; ++i)
            gload16(aG + (size_t)(i*8)*lda + k0, &sA[p][(w*(BM/4) + i*8)*64]);
        #pragma unroll
        for (int i = 0; i < BI; ++i)
            gload16(bG[i] + k0, &sB[p][(w*(BN/4) + i*8)*64]);
    };

    stage(0, 0);
    int p = 0;
    for (int k0 = 0; k0 < K; k0 += 64) {
        __syncthreads();                       // drains vmcnt: buf[p] ready
        if (k0 + 64 < K) stage(p^1, k0 + 64);  // issue next slab under compute
        #pragma unroll
        for (int ks = 0; ks < 2; ++ks) {
            const int rcc = ks*4 + qd;         // chunk of this k-sub-slice
            bf16x8 aF[MF], bF[NF];
            #pragma unroll
            for (int mt = 0; mt < MF; ++mt) {
                int row = wr*(BM/2) + mt*16 + cl;
                aF[mt] = *(const bf16x8*)(&sA[p][row*64 + ((rcc ^ (cl & 7))*8)]);
            }
            #pragma unroll
            for (int nt = 0; nt < NF; ++nt) {
                int row = wc*(BN/2) + nt*16 + cl;
                bF[nt] = *(const bf16x8*)(&sB[p][row*64 + ((rcc ^ (cl & 7))*8)]);
            }
            #pragma unroll
            for (int mt = 0; mt < MF; ++mt)
                #pragma unroll
                for (int nt = 0; nt < NF; ++nt)
                    acc[mt][nt] = __builtin_amdgcn_mfma_f32_16x16x32_bf16(aF[mt], bF[nt], acc[mt][nt], 0, 0, 0);
        }
        p ^= 1;
    }

    if (SPLITV && bn >= 1024) {
        // V segment: write transposed VT[((b*8+h)*64+hd)*512 + t], 8B short4 stores
        #pragma unroll
        for (int nt = 0; nt < NF; ++nt) {
            int col = bn + wc*(BN/2) + nt*16 + cl;
            float bv = bias3[biasoff + (col & 511)];
            int hh = (col >> 6) & 7;
            int hd = col & 63;
            #pragma unroll
            for (int mt = 0; mt < MF; ++mt) {
                int row0 = bm + wr*(BM/2) + mt*16 + qd*4;
                int bb = row0 >> 9, t = row0 & 511;
                s16x4 v4;
                #pragma unroll
                for (int r = 0; r < 4; ++r) {
                    bf16 cb = __float2bfloat16(acc[mt][nt][r] + bv);
                    v4[r] = *reinterpret_cast<short*>(&cb);
                }
                *(s16x4*)(VTout + ((size_t)((bb*8 + hh)*64 + hd))*512 + t) = v4;
            }
        }
        return;
    }

    const float alp = PRELU ? alpha[aidx] : 0.f;
    fp32p bsel = bias;
    if (BIAS == 3) bsel = (bn < 512) ? bias : ((bn < 1024) ? bias2 : bias3);
    #pragma unroll
    for (int nt = 0; nt < NF; ++nt) {
        int col = bn + wc*(BN/2) + nt*16 + cl;
        if (col < N) {
            float bv = 0.f;
            if (BIAS == 1) bv = bsel[biasoff + col];
            if (BIAS == 3) bv = bsel[biasoff + (col & 511)];
            #pragma unroll
            for (int mt = 0; mt < MF; ++mt) {
                #pragma unroll
                for (int r = 0; r < 4; ++r) {
                    int row = bm + wr*(BM/2) + mt*16 + qd*4 + r;
                    float c = acc[mt][nt][r] + bv;
                    if (PRELU) c = (c >= 0.f) ? c : alp*c;
                    if (RESID) c += resid[(size_t)row*ldc + col];
                    if (OUTF32) ((float*)Cout)[(size_t)row*ldc + col] = c;
                    else ((bf16*)Cout)[(size_t)row*ldc + col] = __float2bfloat16(c);
                }
            }
        }
    }
}

// ---------------- LayerNorm: fp32 in -> bf16 out ----------------
__global__ __launch_bounds__(256)
void k_layernorm(const float* __restrict__ x, fp32p g, fp32p b, bf16* __restrict__ out){
    __shared__ float red[256];
    const int row = blockIdx.x, tid = threadIdx.x;
    const float* xr = x + (size_t)row*DMODEL;
    float x0 = xr[tid], x1 = xr[tid+256];
    red[tid] = x0 + x1; __syncthreads();
    for (int o = 128; o > 0; o >>= 1) { if (tid < o) red[tid] += red[tid+o]; __syncthreads(); }
    float mean = red[0] * (1.f/DMODEL);
    __syncthreads();
    float d0 = x0 - mean, d1 = x1 - mean;
    red[tid] = d0*d0 + d1*d1; __syncthreads();
    for (int o = 128; o > 0; o >>= 1) { if (tid < o) red[tid] += red[tid+o]; __syncthreads(); }
    float inv = rsqrtf(red[0]*(1.f/DMODEL) + 1e-6f);
    out[(size_t)row*DMODEL + tid]     = __float2bfloat16(d0*inv*g[tid]     + b[tid]);
    out[(size_t)row*DMODEL + tid+256] = __float2bfloat16(d1*inv*g[tid+256] + b[tid+256]);
}

// ---------------- relative embedding E: (EROWS, HD) bf16, zero-padded ----------------
__global__ __launch_bounds__(64)
void k_relemb(fp32p w1, fp32p b1, fp32p a, fp32p w2, fp32p b2, bf16* __restrict__ Ebf){
    __shared__ float sH[DMODEL];
    const int r = blockIdx.x, tid = threadIdx.x;
    if (r >= 2*TT - 1) { Ebf[(size_t)r*HD + tid] = __float2bfloat16(0.f); return; }
    const float dist = (float)(r - (TT-1));
    const float al = a[0];
    for (int d = tid; d < DMODEL; d += 64) {
        float hv = dist * w1[d] + b1[d];
        sH[d] = (hv >= 0.f) ? hv : al*hv;
    }
    __syncthreads();
    float acc = b2[tid];
    for (int d = 0; d < DMODEL; ++d) acc += sH[d] * w2[(size_t)d*HD + tid];
    Ebf[(size_t)r*HD + tid] = __float2bfloat16(acc);
}

// ---------------- MFMA flash attention with relative-position skew ----------------
// q,k row pitch qp (fused q|k buffer); V pre-transposed VT[b][h][d][t]; out pitch DMODEL.
// All LDS tiles 16B-aligned with chunk-XOR swizzles -> ds_read_b128 fragment loads.
// XCD-aware bid decode (itile in high bits): K/VT tiles fetched once per XCD L2.
// K and E fragments register-prefetched one J-tile ahead (issued after the barrier,
// fly under PV+softmax). Row-sum via 2 MFMAs against a ones-fragment (no shuffles).
__global__ __launch_bounds__(256)
void k_attn(bf16p q, bf16p k, bf16p VT, bf16p Ebf, bf16* __restrict__ o, int qp)
{
    __shared__ __attribute__((aligned(16))) bf16 sV[2][2][64*32]; // [buf][jhalf][d][chunk] 16KB
    __shared__ float sQE[4][16][100];                             // per-wave qe tile
    __shared__ __attribute__((aligned(16))) bf16 sP[4][16*64];    // per-wave P tile

    const int bid  = blockIdx.x;
    const int itile = bid >> 6;        // high bits: same-(b,h) group stays on one XCD
    const int h    = bid & 7;
    const int b    = (bid >> 3) & 7;
    const int tid  = threadIdx.x;
    const int w    = tid >> 6;
    const int lane = tid & 63;
    const int qd   = lane >> 4;
    const int cl   = lane & 15;

    const int I = itile*64 + w*16;
    const size_t bh = ((size_t)b*TT)*qp + (size_t)h*HD;
    const size_t boff = ((size_t)b*TT)*DMODEL + (size_t)h*HD;

    // V^T staging: thread -> (d=tid>>2, chunk=tid&3), swizzled global source chunk
    const int srow = tid >> 2, schunk = tid & 3;
    const int ssc = schunk ^ ((srow >> 1) & 3);
    const bf16* vtb = VT + ((size_t)((b*8 + h)*64 + srow))*512 + ssc*8;
    const int ldsoff = srow*32 + schunk*8;
    const int rc = qd ^ ((cl >> 1) & 3);    // fragment read chunk

    bf16x8 qa0, qa1, ones;
    {
        const bf16* qrow = q + bh + (size_t)(I + cl)*qp;
        qa0 = *(const bf16x8*)(qrow + qd*8);
        qa1 = *(const bf16x8*)(qrow + 32 + qd*8);
    }
    #pragma unroll
    for (int e = 0; e < 8; ++e) ((short*)&ones)[e] = 0x3F80;   // bf16 1.0

    f32x4 Oacc[4] = {};
    float m_i[4], l_i[4];
    #pragma unroll
    for (int r = 0; r < 4; ++r) { m_i[r] = -1e30f; l_i[r] = 0.f; }
    const float scale = 0.125f;

    // register-prefetched K and E fragments for the current J-tile
    bf16x8 kreg[8], ereg[12];
    auto loadKE = [&](int J){
        #pragma unroll
        for (int js = 0; js < 4; ++js) {
            const bf16* krow = k + bh + (size_t)(J + js*16 + cl)*qp;
            kreg[js*2]   = *(const bf16x8*)(krow + qd*8);
            kreg[js*2+1] = *(const bf16x8*)(krow + 32 + qd*8);
        }
        const int rb = J - I + 496;
        #pragma unroll
        for (int nt = 0; nt < 6; ++nt) {
            const bf16* erow = Ebf + (size_t)(rb + nt*16 + cl)*HD;
            ereg[nt*2]   = *(const bf16x8*)(erow + qd*8);
            ereg[nt*2+1] = *(const bf16x8*)(erow + 32 + qd*8);
        }
    };

    loadKE(0);
    gload16(vtb,      &sV[0][0][ldsoff]);
    gload16(vtb + 32, &sV[0][1][ldsoff]);
    int p = 0;

    for (int J = 0; J < TT; J += 64) {
        // ---- QK^T from prefetched registers ----
        f32x4 S[4];
        #pragma unroll
        for (int js = 0; js < 4; ++js) {
            f32x4 acc = {};
            acc = __builtin_amdgcn_mfma_f32_16x16x32_bf16(qa0, kreg[js*2],   acc, 0, 0, 0);
            acc = __builtin_amdgcn_mfma_f32_16x16x32_bf16(qa1, kreg[js*2+1], acc, 0, 0, 0);
            S[js] = acc;
        }

        // ---- QE from prefetched registers (per-wave LDS, 2-way banks) ----
        #pragma unroll
        for (int nt = 0; nt < 6; ++nt) {
            f32x4 acc = {};
            acc = __builtin_amdgcn_mfma_f32_16x16x32_bf16(qa0, ereg[nt*2],   acc, 0, 0, 0);
            acc = __builtin_amdgcn_mfma_f32_16x16x32_bf16(qa1, ereg[nt*2+1], acc, 0, 0, 0);
            #pragma unroll
            for (int r = 0; r < 4; ++r)
                sQE[w][qd*4 + r][nt*16 + cl] = acc[r];
        }

        // ---- skew add + online softmax ----
        float mnew[4];
        #pragma unroll
        for (int r = 0; r < 4; ++r) mnew[r] = m_i[r];
        #pragma unroll
        for (int js = 0; js < 4; ++js) {
            #pragma unroll
            for (int r = 0; r < 4; ++r) {
                int idx = js*16 + cl - (qd*4 + r) + 15;
                float s = S[js][r] + sQE[w][qd*4 + r][idx];
                S[js][r] = s;
                mnew[r] = fmaxf(mnew[r], s);
            }
        }
        #pragma unroll
        for (int r = 0; r < 4; ++r) {
            float mv = mnew[r];
            mv = fmaxf(mv, __shfl_xor(mv, 1));
            mv = fmaxf(mv, __shfl_xor(mv, 2));
            mv = fmaxf(mv, __shfl_xor(mv, 4));
            mv = fmaxf(mv, __shfl_xor(mv, 8));
            mnew[r] = mv;
        }
        float alpha[4];
        #pragma unroll
        for (int r = 0; r < 4; ++r) {
            alpha[r] = __expf((m_i[r] - mnew[r]) * scale);
            m_i[r] = mnew[r];
        }
        // P -> per-wave LDS [16][64], chunk ^ (row&7) swizzle
        #pragma unroll
        for (int js = 0; js < 4; ++js) {
            #pragma unroll
            for (int r = 0; r < 4; ++r) {
                float pv = __expf((S[js][r] - m_i[r]) * scale);
                int prow = qd*4 + r;
                int pcol = ((js*2 + (cl >> 3)) ^ (prow & 7))*8 + (cl & 7);
                sP[w][prow*64 + pcol] = __float2bfloat16(pv);
            }
        }

        // P fragments: aligned b128 with the same involution
        bf16x8 pa0, pa1;
        {
            const int c0 = qd ^ (cl & 7);
            const bf16* pb = &sP[w][cl*64];
            pa0 = *(const bf16x8*)(pb + c0*8);
            pa1 = *(const bf16x8*)(pb + (c0 ^ 4)*8);
        }

        // row-sum of P via MFMA against ones: every lane's acc[r] = sum_k P[row][k]
        {
            f32x4 lacc = {};
            lacc = __builtin_amdgcn_mfma_f32_16x16x32_bf16(pa0, ones, lacc, 0, 0, 0);
            lacc = __builtin_amdgcn_mfma_f32_16x16x32_bf16(pa1, ones, lacc, 0, 0, 0);
            #pragma unroll
            for (int r = 0; r < 4; ++r) l_i[r] = l_i[r]*alpha[r] + lacc[r];
        }

        __syncthreads();                       // sV[p] staged & prior reads drained
        if (J + 64 < TT) {                     // prefetch next V tile + K/E regs under PV
            gload16(vtb + J + 64, &sV[p^1][0][ldsoff]);
            gload16(vtb + J + 96, &sV[p^1][1][ldsoff]);
            loadKE(J + 64);
        }

        // ---- PV: aligned b128 V^T fragments ----
        #pragma unroll
        for (int nt = 0; nt < 4; ++nt) {
            #pragma unroll
            for (int r = 0; r < 4; ++r) Oacc[nt][r] *= alpha[r];
            bf16x8 vb0 = *(const bf16x8*)(&sV[p][0][(nt*16 + cl)*32 + rc*8]);
            bf16x8 vb1 = *(const bf16x8*)(&sV[p][1][(nt*16 + cl)*32 + rc*8]);
            Oacc[nt] = __builtin_amdgcn_mfma_f32_16x16x32_bf16(pa0, vb0, Oacc[nt], 0, 0, 0);
            Oacc[nt] = __builtin_amdgcn_mfma_f32_16x16x32_bf16(pa1, vb1, Oacc[nt], 0, 0, 0);
        }
        p ^= 1;
    }

    #pragma unroll
    for (int nt = 0; nt < 4; ++nt) {
        #pragma unroll
        for (int r = 0; r < 4; ++r) {
            int row = qd*4 + r;
            float val = Oacc[nt][r] / l_i[r];
            o[boff + (size_t)(I + row)*DMODEL + nt*16 + cl] = __float2bfloat16(val);
        }
    }
}

// ---------------- output split + sigmoid (fp32 out) ----------------
__global__ __launch_bounds__(256)
void k_out(const float* __restrict__ y, float* __restrict__ out){
    int idx = blockIdx.x*256 + threadIdx.x;
    if (idx >= MTOK*73) return;
    int row = idx / 73, c = idx - row*73;
    float val = y[idx];
    if (c < DOF) out[(size_t)row*DOF + c] = val;
    else out[(size_t)MTOK*DOF + row*4 + (c-DOF)] = 1.f/(1.f + expf(-val));
}

extern "C" void kernel_launch(void* const* d_in, const int* in_sizes, int n_in,
                              void* d_out, int out_size, void* d_ws, size_t ws_size,
                              hipStream_t stream)
{
    fp32p x      = (fp32p)d_in[0];
    fp32p mask   = (fp32p)d_in[1];
    fp32p enc_w1 = (fp32p)d_in[2];
    fp32p enc_b1 = (fp32p)d_in[3];
    fp32p enc_a1 = (fp32p)d_in[4];
    fp32p enc_w2 = (fp32p)d_in[5];
    fp32p enc_b2 = (fp32p)d_in[6];
    fp32p enc_a2 = (fp32p)d_in[7];
    fp32p rel_w1 = (fp32p)d_in[8];
    fp32p rel_b1 = (fp32p)d_in[9];
    fp32p rel_a  = (fp32p)d_in[10];
    fp32p rel_w2 = (fp32p)d_in[11];
    fp32p rel_b2 = (fp32p)d_in[12];
    fp32p ln_g   = (fp32p)d_in[13];
    fp32p ln_b   = (fp32p)d_in[14];
    fp32p wq     = (fp32p)d_in[15];
    fp32p bq     = (fp32p)d_in[16];
    fp32p wk     = (fp32p)d_in[17];
    fp32p bk     = (fp32p)d_in[18];
    fp32p wv     = (fp32p)d_in[19];
    fp32p bv     = (fp32p)d_in[20];
    fp32p wo     = (fp32p)d_in[21];
    fp32p bo     = (fp32p)d_in[22];
    fp32p fw1    = (fp32p)d_in[23];
    fp32p fb1    = (fp32p)d_in[24];
    fp32p fa     = (fp32p)d_in[25];
    fp32p fw2    = (fp32p)d_in[26];
    fp32p fb2    = (fp32p)d_in[27];
    fp32p dec_w1 = (fp32p)d_in[28];
    fp32p dec_b1 = (fp32p)d_in[29];
    fp32p dec_a  = (fp32p)d_in[30];
    fp32p dec_w2 = (fp32p)d_in[31];
    fp32p dec_b2 = (fp32p)d_in[32];

    char* wsb = (char*)d_ws;
    bf16*  Ebf  = (bf16*)(wsb + E_OFF);
    float* h    = (float*)(wsb + H_OFF);
    bf16*  hn   = (bf16*)(wsb + HN_OFF);
    bf16*  qkb  = (bf16*)(wsb + QKV_OFF);             // 4096 x 1024 bf16 (q|k fused)
    bf16*  VTb  = qkb + (size_t)MTOK*QKP;             // 64bh x 64d x 512t bf16 (4MB)
    bf16*  mid  = qkb;                      // ffn mid 4096 x 2048 bf16 (aliases qk+VT)
    bf16*  cat  = qkb;                      // encoder scratch (pitch CATP)
    bf16*  hb   = qkb;                      // decoder bf16 cast of h
    float* y    = (float*)qkb;              // decoder logits fp32

    // transposed bf16 weights (per-layer reuse; enc/dec alias the same region)
    bf16* qkvT = (bf16*)(wsb + WT_OFF);          // 1536 x 512  (wq^T | wk^T | wv^T)
    bf16* woT  = qkvT + 3*512*512;               // 512 x 512
    bf16* f1T  = woT  + 512*512;                 // 2048 x 512
    bf16* f2T  = f1T  + 2048*512;                // 512 x 2048
    bf16* enc1T = qkvT;                          // 512 x 192 (zero-padded K)
    bf16* enc2T = qkvT + 512*192;                // 512 x 512
    bf16* dec1T = qkvT;                          // 512 x 512
    bf16* dec2T = qkvT + 512*512;                // 73 x 512

    dim3 g512(8, 32);      // N=512: BM=128 BN=64  -> 256 blocks
    dim3 gQKV(12, 32);     // N=1536: BM=128 BN=128 -> 384 blocks
    dim3 gF1(16, 32);      // N=2048: BM=128 BN=128 -> 512 blocks

    // encoder weight transposes + encoder
    k_wt<<<dim3(6,16), 256, 0, stream>>>(enc_w1, 2*DOF, DMODEL, enc1T, CATP);   // Kpad=192
    k_wt<<<dim3(16,16), 256, 0, stream>>>(enc_w2, DMODEL, DMODEL, enc2T, DMODEL);
    k_concat<<<(MTOK*CATP+255)/256, 256, 0, stream>>>(x, mask, cat);
    k_gemm<128,64,1,0,1,0,0><<<g512,256,0,stream>>>(cat, CATP, enc1T, CATP, enc_b1, nullptr, nullptr, 0, enc_a1, 0, nullptr, hn, DMODEL, nullptr, MTOK, DMODEL, CATP);
    k_gemm<128,64,1,0,1,1,0><<<g512,256,0,stream>>>(hn, DMODEL, enc2T, DMODEL, enc_b2, nullptr, nullptr, 0, enc_a2, 0, nullptr, h, DMODEL, nullptr, MTOK, DMODEL, DMODEL);
    k_relemb<<<EROWS, 64, 0, stream>>>(rel_w1, rel_b1, rel_a, rel_w2, rel_b2, Ebf);

    for (int l = 0; l < NL; ++l) {
        size_t oW  = (size_t)l*DMODEL*DMODEL;
        size_t oB  = (size_t)l*DMODEL;
        size_t oF1 = (size_t)l*DMODEL*DFF;
        size_t oBF1= (size_t)l*DFF;
        size_t oF2 = (size_t)l*DFF*DMODEL;

        k_wt6<<<3072, 256, 0, stream>>>(wq+oW, wk+oW, wv+oW, wo+oW, fw1+oF1, fw2+oF2,
                                        qkvT, woT, f1T, f2T);
        k_layernorm<<<MTOK, 256, 0, stream>>>(h, ln_g, ln_b, hn);
        // fused QKV: N=1536; q|k -> qkb (pitch 1024), v -> VTb transposed
        k_gemm<128,128,0,0,3,0,1><<<gQKV,256,0,stream>>>(hn, DMODEL, qkvT, DMODEL, bq, bk, bv, oB, nullptr, 0, nullptr, qkb, QKP, VTb, MTOK, 1536, DMODEL);
        k_attn<<<BB*NH*(TT/64), 256, 0, stream>>>(qkb, qkb + 512, VTb, Ebf, hn, QKP);
        k_gemm<128,64,0,1,1,1,0><<<g512,256,0,stream>>>(hn, DMODEL, woT, DMODEL, bo, nullptr, nullptr, oB, nullptr, 0, h, h, DMODEL, nullptr, MTOK, DMODEL, DMODEL);
        k_layernorm<<<MTOK, 256, 0, stream>>>(h, ln_g, ln_b, hn);
        // fused FFN: f1 full N=2048 -> mid; f2 full K=2048 -> h (+resid)
        k_gemm<128,128,1,0,1,0,0><<<gF1,256,0,stream>>>(hn, DMODEL, f1T, DMODEL, fb1, nullptr, nullptr, oBF1, fa, (size_t)l, nullptr, mid, DFF, nullptr, MTOK, DFF, DMODEL);
        k_gemm<128,64,0,1,1,1,0><<<g512,256,0,stream>>>(mid, DFF, f2T, DFF, fb2, nullptr, nullptr, oB, nullptr, 0, h, h, DMODEL, nullptr, MTOK, DMODEL, DFF);
    }

    // decoder weight transposes + decoder
    k_wt<<<dim3(16,16), 256, 0, stream>>>(dec_w1, DMODEL, DMODEL, dec1T, DMODEL);
    k_wt<<<dim3(16,3), 256, 0, stream>>>(dec_w2, DMODEL, DOF+4, dec2T, DMODEL);
    k_cast<<<(MTOK*DMODEL+255)/256, 256, 0, stream>>>(h, hb);
    k_gemm<128,64,1,0,1,0,0><<<g512,256,0,stream>>>(hb, DMODEL, dec1T, DMODEL, dec_b1, nullptr, nullptr, 0, dec_a, 0, nullptr, hn, DMODEL, nullptr, MTOK, DMODEL, DMODEL);
    {
        dim3 g2(2, 32);   // N=73: BN=64 -> 2 col tiles
        k_gemm<128,64,0,0,1,1,0><<<g2,256,0,stream>>>(hn, DMODEL, dec2T, DMODEL, dec_b2, nullptr, nullptr, 0, nullptr, 0, nullptr, y, DOF+4, nullptr, MTOK, DOF+4, DMODEL);
    }
    k_out<<<(MTOK*73+255)/256, 256, 0, stream>>>(y, (float*)d_out);
}

// Round 7
// 929.773 us; speedup vs baseline: 1.8946x; 1.1120x over previous
//
#include <hip/hip_runtime.h>
#include <hip/hip_bf16.h>

#define DOF 69
#define NL 6
#define NH 8
#define DMODEL 512
#define DFF 2048
#define HD 64
#define BB 8
#define TT 512
#define MTOK (BB*TT)   // 4096
#define EROWS 1040     // 2T-1 = 1023, padded
#define CATP 192       // padded concat pitch (K=138 rounded to 64)
#define QKP 1024       // fused q|k row pitch (v split out transposed)

// workspace layout (bytes) — 34.5 MB total
#define E_OFF     4096u
#define H_OFF     (512u*1024u)
#define HN_OFF    (H_OFF + 8u*1024u*1024u)
#define QKV_OFF   (HN_OFF + 4u*1024u*1024u)      // 16 MB region: qk(8MB)+VT(4MB) / mid(16MB) / scratch
#define WT_OFF    (QKV_OFF + 16u*1024u*1024u)    // 6 MB of bf16 B^T weights (per-layer reuse)

typedef const float* fp32p;
typedef __hip_bfloat16 bf16;
typedef const bf16* bf16p;
typedef __attribute__((ext_vector_type(8))) short bf16x8;  // 8 bf16 (4 VGPRs)
typedef __attribute__((ext_vector_type(4))) short s16x4;   // 4 bf16 (8B store)
typedef __attribute__((ext_vector_type(4))) float f32x4;   // 4 fp32 acc

typedef __attribute__((address_space(1))) const void as1_cvoid;
typedef __attribute__((address_space(3))) void       as3_void;

__device__ __forceinline__ void gload16(const bf16* g, const bf16* l){
    __builtin_amdgcn_global_load_lds((as1_cvoid*)g, (as3_void*)l, 16, 0, 0);
}

__device__ __forceinline__ float b2f(bf16 x){ return __bfloat162float(x); }

// ---------------- concat(x, mask) fp32 -> bf16, zero-padded to pitch CATP ----------------
__global__ __launch_bounds__(256)
void k_concat(fp32p x, fp32p mask, bf16* __restrict__ out){
    int idx = blockIdx.x*256 + threadIdx.x;
    if (idx >= MTOK*CATP) return;
    int row = idx / CATP, c = idx - row*CATP;
    float v = 0.f;
    if (c < DOF) v = x[(size_t)row*DOF + c];
    else if (c < 2*DOF) v = mask[(size_t)row*DOF + (c - DOF)];
    out[idx] = __float2bfloat16(v);
}

// ---------------- cast fp32 -> bf16 ----------------
__global__ __launch_bounds__(256)
void k_cast(const float* __restrict__ in, bf16* __restrict__ out){
    int idx = blockIdx.x*256 + threadIdx.x;
    if (idx >= MTOK*DMODEL) return;
    out[idx] = __float2bfloat16(in[idx]);
}

// ---------------- generic weight transpose-cast: W fp32 (K x N) -> WT bf16 (N x ldk) ----
__global__ __launch_bounds__(256)
void k_wt(fp32p W, int K, int N, bf16* __restrict__ WT, int ldk)
{
    __shared__ float s[32][33];
    const int k0 = blockIdx.x*32, n0 = blockIdx.y*32;
    const int c = threadIdx.x & 31, r0 = threadIdx.x >> 5;
    #pragma unroll
    for (int rr = r0; rr < 32; rr += 8) {
        int k = k0 + rr, n = n0 + c;
        s[rr][c] = (k < K && n < N) ? W[(size_t)k*N + n] : 0.f;
    }
    __syncthreads();
    #pragma unroll
    for (int rr = r0; rr < 32; rr += 8) {
        int n = n0 + rr;
        if (n < N) WT[(size_t)n*ldk + k0 + c] = __float2bfloat16(s[c][rr]);
    }
}

// ---------------- per-layer batched transpose: wq,wk,wv,wo,fw1,fw2 -> bf16 B^T ----------
__global__ __launch_bounds__(256)
void k_wt6(fp32p wq, fp32p wk, fp32p wv, fp32p wo, fp32p fw1, fp32p fw2,
           bf16* __restrict__ qkvT, bf16* __restrict__ woT,
           bf16* __restrict__ f1T, bf16* __restrict__ f2T)
{
    __shared__ float s[32][33];
    const int t = blockIdx.x;
    fp32p src; bf16* dst; int N, ldk, k0, n0;
    if (t < 1024) {
        int seg = t >> 8, local = t & 255;
        N = 512; ldk = 512;
        k0 = (local & 15) * 32; n0 = (local >> 4) * 32;
        if      (seg == 0) { src = wq; dst = qkvT; }
        else if (seg == 1) { src = wk; dst = qkvT + 512*512; }
        else if (seg == 2) { src = wv; dst = qkvT + 2*512*512; }
        else               { src = wo; dst = woT; }
    } else if (t < 2048) {
        int local = t - 1024;
        N = 2048; ldk = 512;
        k0 = (local & 15) * 32; n0 = (local >> 4) * 32;
        src = fw1; dst = f1T;
    } else {
        int local = t - 2048;
        N = 512; ldk = 2048;
        k0 = (local >> 4) * 32; n0 = (local & 15) * 32;
        src = fw2; dst = f2T;
    }
    const int c = threadIdx.x & 31, r0 = threadIdx.x >> 5;
    #pragma unroll
    for (int rr = r0; rr < 32; rr += 8)
        s[rr][c] = src[(size_t)(k0+rr)*N + n0 + c];
    __syncthreads();
    #pragma unroll
    for (int rr = r0; rr < 32; rr += 8)
        dst[(size_t)(n0+rr)*ldk + k0 + c] = __float2bfloat16(s[c][rr]);
}

// ---------------- LDS-tiled MFMA GEMM (BK=64, 2-phase pipeline) ----------------
// C = epi(A @ B + bias); A bf16 (M x K) lda; BT bf16 (N x ldk) = B^T.
// Block = 256 threads (4 waves, 2x2 wave grid), tile BM x BN, BK=64 (one barrier per
// 64-K slab -> half the vmcnt drains vs BK=32, 16 MFMA/wave per barrier).
// global_load_lds (16B) stages into double-buffered linear LDS; 8-chunk XOR swizzle
// (chunk ^ row&7) applied on GLOBAL source and LDS READ (both-sides involution).
// XCD-aware chunked block swizzle (T1/m204). Requires K%64==0, M%BM==0.
// BIAS: 0=none, 1=bias[], 3=segment-select of {bias,bias2,bias3} by col/512.
// SPLITV: blocks with bn>=1024 write transposed per-head VT[b][h][d][t] (QKV fusion).
template<int BM, int BN, int PRELU, int RESID, int BIAS, int OUTF32, int SPLITV>
__global__ __launch_bounds__(256)
void k_gemm(bf16p A, int lda,
            bf16p BT, int ldk,
            fp32p bias, fp32p bias2, fp32p bias3, size_t biasoff,
            fp32p alpha, size_t aidx,
            const float* __restrict__ resid,
            void* __restrict__ Cout, int ldc,
            bf16* __restrict__ VTout,
            int M, int N, int K)
{
    constexpr int MF = BM/32;   // m-fragments per wave
    constexpr int NF = BN/32;   // n-fragments per wave
    constexpr int AI = BM/32;   // A stage issues per wave (8 rows x 128B each)
    constexpr int BI = BN/32;   // B stage issues per wave

    __shared__ __attribute__((aligned(16))) bf16 sA[2][BM*64];
    __shared__ __attribute__((aligned(16))) bf16 sB[2][BN*64];

    // XCD-aware bijective swizzle (m204): xcd = bid&7 keeps HW round-robin mapping,
    // each XCD gets a contiguous chunk of the x-major grid order.
    int bx, by;
    {
        const int gx  = gridDim.x;
        const int nwg = gx * gridDim.y;
        const int bid = blockIdx.y * gx + blockIdx.x;
        const int qq = nwg >> 3, rr = nwg & 7;
        const int xcd = bid & 7, pos = bid >> 3;
        const int nb = (xcd < rr) ? (xcd*(qq+1) + pos) : (rr*(qq+1) + (xcd-rr)*qq + pos);
        bx = nb % gx; by = nb / gx;
    }

    const int tid  = threadIdx.x;
    const int w    = tid >> 6;
    const int lane = tid & 63;
    const int qd   = lane >> 4;
    const int cl   = lane & 15;
    const int wr   = w >> 1;
    const int wc   = w & 1;
    const int bm   = by * BM;
    const int bn   = bx * BN;

    // staging: lane -> (row = lane>>3 within 8-row group, chunk = lane&7 of 8x16B row)
    // source chunk = chunk ^ (row&7) so LDS stays linear while reads unswizzle.
    const int ssc = (lane & 7) ^ ((lane >> 3) & 7);

    const bf16* aG = A + (size_t)(bm + w*(BM/4) + (lane >> 3))*lda + ssc*8;
    const bf16* bG[BI];
    #pragma unroll
    for (int i = 0; i < BI; ++i) {
        int rrow = min(bn + w*(BN/4) + i*8 + (lane >> 3), N-1);
        bG[i] = BT + (size_t)rrow*ldk + ssc*8;
    }

    f32x4 acc[MF][NF] = {};

    auto stage = [&](int p, int k0){
        #pragma unroll
        for (int i = 0; i < AI; ++i)
            gload16(aG + (size_t)(i*8)*lda + k0, &sA[p][(w*(BM/4) + i*8)*64]);
        #pragma unroll
        for (int i = 0; i < BI; ++i)
            gload16(bG[i] + k0, &sB[p][(w*(BN/4) + i*8)*64]);
    };

    stage(0, 0);
    int p = 0;
    for (int k0 = 0; k0 < K; k0 += 64) {
        __syncthreads();                       // drains vmcnt: buf[p] ready
        if (k0 + 64 < K) stage(p^1, k0 + 64);  // issue next slab under compute
        #pragma unroll
        for (int ks = 0; ks < 2; ++ks) {
            const int rcc = ks*4 + qd;         // chunk of this k-sub-slice
            bf16x8 aF[MF], bF[NF];
            #pragma unroll
            for (int mt = 0; mt < MF; ++mt) {
                int row = wr*(BM/2) + mt*16 + cl;
                aF[mt] = *(const bf16x8*)(&sA[p][row*64 + ((rcc ^ (cl & 7))*8)]);
            }
            #pragma unroll
            for (int nt = 0; nt < NF; ++nt) {
                int row = wc*(BN/2) + nt*16 + cl;
                bF[nt] = *(const bf16x8*)(&sB[p][row*64 + ((rcc ^ (cl & 7))*8)]);
            }
            #pragma unroll
            for (int mt = 0; mt < MF; ++mt)
                #pragma unroll
                for (int nt = 0; nt < NF; ++nt)
                    acc[mt][nt] = __builtin_amdgcn_mfma_f32_16x16x32_bf16(aF[mt], bF[nt], acc[mt][nt], 0, 0, 0);
        }
        p ^= 1;
    }

    if (SPLITV && bn >= 1024) {
        // V segment: write transposed VT[((b*8+h)*64+hd)*512 + t], 8B short4 stores
        #pragma unroll
        for (int nt = 0; nt < NF; ++nt) {
            int col = bn + wc*(BN/2) + nt*16 + cl;
            float bv = bias3[biasoff + (col & 511)];
            int hh = (col >> 6) & 7;
            int hd = col & 63;
            #pragma unroll
            for (int mt = 0; mt < MF; ++mt) {
                int row0 = bm + wr*(BM/2) + mt*16 + qd*4;
                int bb = row0 >> 9, t = row0 & 511;
                s16x4 v4;
                #pragma unroll
                for (int r = 0; r < 4; ++r) {
                    bf16 cb = __float2bfloat16(acc[mt][nt][r] + bv);
                    v4[r] = *reinterpret_cast<short*>(&cb);
                }
                *(s16x4*)(VTout + ((size_t)((bb*8 + hh)*64 + hd))*512 + t) = v4;
            }
        }
        return;
    }

    const float alp = PRELU ? alpha[aidx] : 0.f;
    fp32p bsel = bias;
    if (BIAS == 3) bsel = (bn < 512) ? bias : ((bn < 1024) ? bias2 : bias3);
    #pragma unroll
    for (int nt = 0; nt < NF; ++nt) {
        int col = bn + wc*(BN/2) + nt*16 + cl;
        if (col < N) {
            float bv = 0.f;
            if (BIAS == 1) bv = bsel[biasoff + col];
            if (BIAS == 3) bv = bsel[biasoff + (col & 511)];
            #pragma unroll
            for (int mt = 0; mt < MF; ++mt) {
                #pragma unroll
                for (int r = 0; r < 4; ++r) {
                    int row = bm + wr*(BM/2) + mt*16 + qd*4 + r;
                    float c = acc[mt][nt][r] + bv;
                    if (PRELU) c = (c >= 0.f) ? c : alp*c;
                    if (RESID) c += resid[(size_t)row*ldc + col];
                    if (OUTF32) ((float*)Cout)[(size_t)row*ldc + col] = c;
                    else ((bf16*)Cout)[(size_t)row*ldc + col] = __float2bfloat16(c);
                }
            }
        }
    }
}

// ---------------- LayerNorm: fp32 in -> bf16 out ----------------
__global__ __launch_bounds__(256)
void k_layernorm(const float* __restrict__ x, fp32p g, fp32p b, bf16* __restrict__ out){
    __shared__ float red[256];
    const int row = blockIdx.x, tid = threadIdx.x;
    const float* xr = x + (size_t)row*DMODEL;
    float x0 = xr[tid], x1 = xr[tid+256];
    red[tid] = x0 + x1; __syncthreads();
    for (int o = 128; o > 0; o >>= 1) { if (tid < o) red[tid] += red[tid+o]; __syncthreads(); }
    float mean = red[0] * (1.f/DMODEL);
    __syncthreads();
    float d0 = x0 - mean, d1 = x1 - mean;
    red[tid] = d0*d0 + d1*d1; __syncthreads();
    for (int o = 128; o > 0; o >>= 1) { if (tid < o) red[tid] += red[tid+o]; __syncthreads(); }
    float inv = rsqrtf(red[0]*(1.f/DMODEL) + 1e-6f);
    out[(size_t)row*DMODEL + tid]     = __float2bfloat16(d0*inv*g[tid]     + b[tid]);
    out[(size_t)row*DMODEL + tid+256] = __float2bfloat16(d1*inv*g[tid+256] + b[tid+256]);
}

// ---------------- relative embedding E: (EROWS, HD) bf16, zero-padded ----------------
__global__ __launch_bounds__(64)
void k_relemb(fp32p w1, fp32p b1, fp32p a, fp32p w2, fp32p b2, bf16* __restrict__ Ebf){
    __shared__ float sH[DMODEL];
    const int r = blockIdx.x, tid = threadIdx.x;
    if (r >= 2*TT - 1) { Ebf[(size_t)r*HD + tid] = __float2bfloat16(0.f); return; }
    const float dist = (float)(r - (TT-1));
    const float al = a[0];
    for (int d = tid; d < DMODEL; d += 64) {
        float hv = dist * w1[d] + b1[d];
        sH[d] = (hv >= 0.f) ? hv : al*hv;
    }
    __syncthreads();
    float acc = b2[tid];
    for (int d = 0; d < DMODEL; ++d) acc += sH[d] * w2[(size_t)d*HD + tid];
    Ebf[(size_t)r*HD + tid] = __float2bfloat16(acc);
}

// ---------------- MFMA flash attention with relative-position skew ----------------
// 512 threads = 8 waves; each wave owns 16 q-rows, block owns 128 (grid = 256 = 1/CU).
// Per J-tile the BLOCK stages K (8KB), V^T (8KB) and the 208-row E window (26KB) via
// coalesced global_load_lds into double buffers (8-chunk XOR swizzle, identical to the
// GEMM's), one iteration ahead. Kills the 4x wave-redundant, 64-line-per-instr K/E
// global loads that dominated (L2 line traffic per J-tile ~300KB -> ~43KB).
// One barrier per J-tile. Row-sum via MFMA-with-ones. XCD-aware bid decode.
__global__ __launch_bounds__(512)
void k_attn(bf16p q, bf16p k, bf16p VT, bf16p Ebf, bf16* __restrict__ o, int qp)
{
    __shared__ __attribute__((aligned(16))) bf16 sK[2][64*64];    // 16 KB
    __shared__ __attribute__((aligned(16))) bf16 sV[2][64*64];    // 16 KB
    __shared__ __attribute__((aligned(16))) bf16 sE[2][208*64];   // 52 KB
    __shared__ float sQE[8][16][100];                             // 50 KB
    __shared__ __attribute__((aligned(16))) bf16 sP[8][16*64];    // 16 KB

    const int bid = blockIdx.x;
    const int it2 = bid >> 6;          // 0..3 in high bits: same-(b,h) group on one XCD
    const int h   = bid & 7;
    const int b   = (bid >> 3) & 7;
    const int tid = threadIdx.x;
    const int w   = tid >> 6;          // 0..7
    const int lane= tid & 63;
    const int qd  = lane >> 4;
    const int cl  = lane & 15;

    const int I = it2*128 + w*16;
    const size_t bh   = ((size_t)b*TT)*qp + (size_t)h*HD;
    const size_t boff = ((size_t)b*TT)*DMODEL + (size_t)h*HD;

    // staging: thread -> (row = tid>>3 in 0..63, chunk = tid&7); source chunk XOR'd so
    // LDS dest stays linear (base + tid*16B) while b128 reads unswizzle (rule #21).
    const int srow = tid >> 3, sch = tid & 7;
    const int ssc  = sch ^ (srow & 7);
    const int ldso = srow*64 + sch*8;              // == tid*16 bytes, linear
    const bf16* kg = k  + bh + (size_t)srow*qp + ssc*8;
    const bf16* vg = VT + ((size_t)((b*8 + h)*64 + srow))*512 + ssc*8;
    const int ebase0 = 384 - it2*128;              // E window base = J + ebase0

    auto stage = [&](int p, int J){
        gload16(kg + (size_t)J*qp, &sK[p][ldso]);
        gload16(vg + J,            &sV[p][ldso]);
        const bf16* eg = Ebf + (size_t)(J + ebase0 + srow)*HD + ssc*8;
        gload16(eg,          &sE[p][ldso]);
        gload16(eg + 64*HD,  &sE[p][ldso + 64*64]);
        gload16(eg + 128*HD, &sE[p][ldso + 128*64]);
        if (tid < 128) gload16(eg + 192*HD, &sE[p][ldso + 192*64]);   // rows 192..207
    };

    bf16x8 qa0, qa1, ones;
    {
        const bf16* qrow = q + bh + (size_t)(I + cl)*qp;
        qa0 = *(const bf16x8*)(qrow + qd*8);
        qa1 = *(const bf16x8*)(qrow + 32 + qd*8);
    }
    #pragma unroll
    for (int e = 0; e < 8; ++e) ((short*)&ones)[e] = 0x3F80;   // bf16 1.0

    f32x4 Oacc[4] = {};
    float m_i[4], l_i[4];
    #pragma unroll
    for (int r = 0; r < 4; ++r) { m_i[r] = -1e30f; l_i[r] = 0.f; }
    const float scale = 0.125f;

    // fragment read positions (shared by sK/sE/sV/sP: row&7 == cl&7 everywhere)
    const int c0 = (qd ^ (cl & 7))*8;
    const int c1 = ((qd ^ (cl & 7)) ^ 4)*8;
    const int erow0 = 112 - w*16;       // wave's E-window offset within block window

    stage(0, 0);
    int p = 0;

    for (int J = 0; J < TT; J += 64) {
        __syncthreads();                       // buf[p] staged (vmcnt drained) & prev reads done
        if (J + 64 < TT) stage(p^1, J + 64);   // next tile flies under this iteration

        // ---- QK^T from sK ----
        f32x4 S[4];
        #pragma unroll
        for (int js = 0; js < 4; ++js) {
            const bf16* kr = &sK[p][(js*16 + cl)*64];
            bf16x8 kb0 = *(const bf16x8*)(kr + c0);
            bf16x8 kb1 = *(const bf16x8*)(kr + c1);
            f32x4 acc = {};
            acc = __builtin_amdgcn_mfma_f32_16x16x32_bf16(qa0, kb0, acc, 0, 0, 0);
            acc = __builtin_amdgcn_mfma_f32_16x16x32_bf16(qa1, kb1, acc, 0, 0, 0);
            S[js] = acc;
        }

        // ---- QE from sE ----
        #pragma unroll
        for (int nt = 0; nt < 6; ++nt) {
            const bf16* er = &sE[p][(erow0 + nt*16 + cl)*64];
            bf16x8 eb0 = *(const bf16x8*)(er + c0);
            bf16x8 eb1 = *(const bf16x8*)(er + c1);
            f32x4 acc = {};
            acc = __builtin_amdgcn_mfma_f32_16x16x32_bf16(qa0, eb0, acc, 0, 0, 0);
            acc = __builtin_amdgcn_mfma_f32_16x16x32_bf16(qa1, eb1, acc, 0, 0, 0);
            #pragma unroll
            for (int r = 0; r < 4; ++r)
                sQE[w][qd*4 + r][nt*16 + cl] = acc[r];
        }

        // ---- skew add + online softmax ----
        float mnew[4];
        #pragma unroll
        for (int r = 0; r < 4; ++r) mnew[r] = m_i[r];
        #pragma unroll
        for (int js = 0; js < 4; ++js) {
            #pragma unroll
            for (int r = 0; r < 4; ++r) {
                int idx = js*16 + cl - (qd*4 + r) + 15;
                float s = S[js][r] + sQE[w][qd*4 + r][idx];
                S[js][r] = s;
                mnew[r] = fmaxf(mnew[r], s);
            }
        }
        #pragma unroll
        for (int r = 0; r < 4; ++r) {
            float mv = mnew[r];
            mv = fmaxf(mv, __shfl_xor(mv, 1));
            mv = fmaxf(mv, __shfl_xor(mv, 2));
            mv = fmaxf(mv, __shfl_xor(mv, 4));
            mv = fmaxf(mv, __shfl_xor(mv, 8));
            mnew[r] = mv;
        }
        float alpha[4];
        #pragma unroll
        for (int r = 0; r < 4; ++r) {
            alpha[r] = __expf((m_i[r] - mnew[r]) * scale);
            m_i[r] = mnew[r];
        }
        // P -> per-wave LDS [16][64], chunk ^ (row&7) swizzle
        #pragma unroll
        for (int js = 0; js < 4; ++js) {
            #pragma unroll
            for (int r = 0; r < 4; ++r) {
                float pv = __expf((S[js][r] - m_i[r]) * scale);
                int prow = qd*4 + r;
                int pcol = ((js*2 + (cl >> 3)) ^ (prow & 7))*8 + (cl & 7);
                sP[w][prow*64 + pcol] = __float2bfloat16(pv);
            }
        }

        // P fragments: aligned b128 with the same involution
        bf16x8 pa0, pa1;
        {
            const bf16* pb = &sP[w][cl*64];
            pa0 = *(const bf16x8*)(pb + c0);
            pa1 = *(const bf16x8*)(pb + c1);
        }

        // row-sum of P via MFMA against ones: lane's acc[r] = sum_k P[row][k]
        {
            f32x4 lacc = {};
            lacc = __builtin_amdgcn_mfma_f32_16x16x32_bf16(pa0, ones, lacc, 0, 0, 0);
            lacc = __builtin_amdgcn_mfma_f32_16x16x32_bf16(pa1, ones, lacc, 0, 0, 0);
            #pragma unroll
            for (int r = 0; r < 4; ++r) l_i[r] = l_i[r]*alpha[r] + lacc[r];
        }

        // ---- PV from sV ----
        #pragma unroll
        for (int nt = 0; nt < 4; ++nt) {
            #pragma unroll
            for (int r = 0; r < 4; ++r) Oacc[nt][r] *= alpha[r];
            const bf16* vr = &sV[p][(nt*16 + cl)*64];
            bf16x8 vb0 = *(const bf16x8*)(vr + c0);
            bf16x8 vb1 = *(const bf16x8*)(vr + c1);
            Oacc[nt] = __builtin_amdgcn_mfma_f32_16x16x32_bf16(pa0, vb0, Oacc[nt], 0, 0, 0);
            Oacc[nt] = __builtin_amdgcn_mfma_f32_16x16x32_bf16(pa1, vb1, Oacc[nt], 0, 0, 0);
        }
        p ^= 1;
    }

    #pragma unroll
    for (int nt = 0; nt < 4; ++nt) {
        #pragma unroll
        for (int r = 0; r < 4; ++r) {
            int row = qd*4 + r;
            float val = Oacc[nt][r] / l_i[r];
            o[boff + (size_t)(I + row)*DMODEL + nt*16 + cl] = __float2bfloat16(val);
        }
    }
}

// ---------------- output split + sigmoid (fp32 out) ----------------
__global__ __launch_bounds__(256)
void k_out(const float* __restrict__ y, float* __restrict__ out){
    int idx = blockIdx.x*256 + threadIdx.x;
    if (idx >= MTOK*73) return;
    int row = idx / 73, c = idx - row*73;
    float val = y[idx];
    if (c < DOF) out[(size_t)row*DOF + c] = val;
    else out[(size_t)MTOK*DOF + row*4 + (c-DOF)] = 1.f/(1.f + expf(-val));
}

extern "C" void kernel_launch(void* const* d_in, const int* in_sizes, int n_in,
                              void* d_out, int out_size, void* d_ws, size_t ws_size,
                              hipStream_t stream)
{
    fp32p x      = (fp32p)d_in[0];
    fp32p mask   = (fp32p)d_in[1];
    fp32p enc_w1 = (fp32p)d_in[2];
    fp32p enc_b1 = (fp32p)d_in[3];
    fp32p enc_a1 = (fp32p)d_in[4];
    fp32p enc_w2 = (fp32p)d_in[5];
    fp32p enc_b2 = (fp32p)d_in[6];
    fp32p enc_a2 = (fp32p)d_in[7];
    fp32p rel_w1 = (fp32p)d_in[8];
    fp32p rel_b1 = (fp32p)d_in[9];
    fp32p rel_a  = (fp32p)d_in[10];
    fp32p rel_w2 = (fp32p)d_in[11];
    fp32p rel_b2 = (fp32p)d_in[12];
    fp32p ln_g   = (fp32p)d_in[13];
    fp32p ln_b   = (fp32p)d_in[14];
    fp32p wq     = (fp32p)d_in[15];
    fp32p bq     = (fp32p)d_in[16];
    fp32p wk     = (fp32p)d_in[17];
    fp32p bk     = (fp32p)d_in[18];
    fp32p wv     = (fp32p)d_in[19];
    fp32p bv     = (fp32p)d_in[20];
    fp32p wo     = (fp32p)d_in[21];
    fp32p bo     = (fp32p)d_in[22];
    fp32p fw1    = (fp32p)d_in[23];
    fp32p fb1    = (fp32p)d_in[24];
    fp32p fa     = (fp32p)d_in[25];
    fp32p fw2    = (fp32p)d_in[26];
    fp32p fb2    = (fp32p)d_in[27];
    fp32p dec_w1 = (fp32p)d_in[28];
    fp32p dec_b1 = (fp32p)d_in[29];
    fp32p dec_a  = (fp32p)d_in[30];
    fp32p dec_w2 = (fp32p)d_in[31];
    fp32p dec_b2 = (fp32p)d_in[32];

    char* wsb = (char*)d_ws;
    bf16*  Ebf  = (bf16*)(wsb + E_OFF);
    float* h    = (float*)(wsb + H_OFF);
    bf16*  hn   = (bf16*)(wsb + HN_OFF);
    bf16*  qkb  = (bf16*)(wsb + QKV_OFF);             // 4096 x 1024 bf16 (q|k fused)
    bf16*  VTb  = qkb + (size_t)MTOK*QKP;             // 64bh x 64d x 512t bf16 (4MB)
    bf16*  mid  = qkb;                      // ffn mid 4096 x 2048 bf16 (aliases qk+VT)
    bf16*  cat  = qkb;                      // encoder scratch (pitch CATP)
    bf16*  hb   = qkb;                      // decoder bf16 cast of h
    float* y    = (float*)qkb;              // decoder logits fp32

    // transposed bf16 weights (per-layer reuse; enc/dec alias the same region)
    bf16* qkvT = (bf16*)(wsb + WT_OFF);          // 1536 x 512  (wq^T | wk^T | wv^T)
    bf16* woT  = qkvT + 3*512*512;               // 512 x 512
    bf16* f1T  = woT  + 512*512;                 // 2048 x 512
    bf16* f2T  = f1T  + 2048*512;                // 512 x 2048
    bf16* enc1T = qkvT;                          // 512 x 192 (zero-padded K)
    bf16* enc2T = qkvT + 512*192;                // 512 x 512
    bf16* dec1T = qkvT;                          // 512 x 512
    bf16* dec2T = qkvT + 512*512;                // 73 x 512

    dim3 g512(8, 32);      // N=512: BM=128 BN=64  -> 256 blocks
    dim3 gQKV(12, 32);     // N=1536: BM=128 BN=128 -> 384 blocks
    dim3 gF1(16, 32);      // N=2048: BM=128 BN=128 -> 512 blocks

    // encoder weight transposes + encoder
    k_wt<<<dim3(6,16), 256, 0, stream>>>(enc_w1, 2*DOF, DMODEL, enc1T, CATP);   // Kpad=192
    k_wt<<<dim3(16,16), 256, 0, stream>>>(enc_w2, DMODEL, DMODEL, enc2T, DMODEL);
    k_concat<<<(MTOK*CATP+255)/256, 256, 0, stream>>>(x, mask, cat);
    k_gemm<128,64,1,0,1,0,0><<<g512,256,0,stream>>>(cat, CATP, enc1T, CATP, enc_b1, nullptr, nullptr, 0, enc_a1, 0, nullptr, hn, DMODEL, nullptr, MTOK, DMODEL, CATP);
    k_gemm<128,64,1,0,1,1,0><<<g512,256,0,stream>>>(hn, DMODEL, enc2T, DMODEL, enc_b2, nullptr, nullptr, 0, enc_a2, 0, nullptr, h, DMODEL, nullptr, MTOK, DMODEL, DMODEL);
    k_relemb<<<EROWS, 64, 0, stream>>>(rel_w1, rel_b1, rel_a, rel_w2, rel_b2, Ebf);

    for (int l = 0; l < NL; ++l) {
        size_t oW  = (size_t)l*DMODEL*DMODEL;
        size_t oB  = (size_t)l*DMODEL;
        size_t oF1 = (size_t)l*DMODEL*DFF;
        size_t oBF1= (size_t)l*DFF;
        size_t oF2 = (size_t)l*DFF*DMODEL;

        k_wt6<<<3072, 256, 0, stream>>>(wq+oW, wk+oW, wv+oW, wo+oW, fw1+oF1, fw2+oF2,
                                        qkvT, woT, f1T, f2T);
        k_layernorm<<<MTOK, 256, 0, stream>>>(h, ln_g, ln_b, hn);
        // fused QKV: N=1536; q|k -> qkb (pitch 1024), v -> VTb transposed
        k_gemm<128,128,0,0,3,0,1><<<gQKV,256,0,stream>>>(hn, DMODEL, qkvT, DMODEL, bq, bk, bv, oB, nullptr, 0, nullptr, qkb, QKP, VTb, MTOK, 1536, DMODEL);
        k_attn<<<BB*NH*(TT/128), 512, 0, stream>>>(qkb, qkb + 512, VTb, Ebf, hn, QKP);
        k_gemm<128,64,0,1,1,1,0><<<g512,256,0,stream>>>(hn, DMODEL, woT, DMODEL, bo, nullptr, nullptr, oB, nullptr, 0, h, h, DMODEL, nullptr, MTOK, DMODEL, DMODEL);
        k_layernorm<<<MTOK, 256, 0, stream>>>(h, ln_g, ln_b, hn);
        // fused FFN: f1 full N=2048 -> mid; f2 full K=2048 -> h (+resid)
        k_gemm<128,128,1,0,1,0,0><<<gF1,256,0,stream>>>(hn, DMODEL, f1T, DMODEL, fb1, nullptr, nullptr, oBF1, fa, (size_t)l, nullptr, mid, DFF, nullptr, MTOK, DFF, DMODEL);
        k_gemm<128,64,0,1,1,1,0><<<g512,256,0,stream>>>(mid, DFF, f2T, DFF, fb2, nullptr, nullptr, oB, nullptr, 0, h, h, DMODEL, nullptr, MTOK, DMODEL, DFF);
    }

    // decoder weight transposes + decoder
    k_wt<<<dim3(16,16), 256, 0, stream>>>(dec_w1, DMODEL, DMODEL, dec1T, DMODEL);
    k_wt<<<dim3(16,3), 256, 0, stream>>>(dec_w2, DMODEL, DOF+4, dec2T, DMODEL);
    k_cast<<<(MTOK*DMODEL+255)/256, 256, 0, stream>>>(h, hb);
    k_gemm<128,64,1,0,1,0,0><<<g512,256,0,stream>>>(hb, DMODEL, dec1T, DMODEL, dec_b1, nullptr, nullptr, 0, dec_a, 0, nullptr, hn, DMODEL, nullptr, MTOK, DMODEL, DMODEL);
    {
        dim3 g2(2, 32);   // N=73: BN=64 -> 2 col tiles
        k_gemm<128,64,0,0,1,1,0><<<g2,256,0,stream>>>(hn, DMODEL, dec2T, DMODEL, dec_b2, nullptr, nullptr, 0, nullptr, 0, nullptr, y, DOF+4, nullptr, MTOK, DOF+4, DMODEL);
    }
    k_out<<<(MTOK*73+255)/256, 256, 0, stream>>>(y, (float*)d_out);
}

// Round 8
// 845.888 us; speedup vs baseline: 2.0825x; 1.0992x over previous
//
#include <hip/hip_runtime.h>
#include <hip/hip_bf16.h>

#define DOF 69
#define NL 6
#define NH 8
#define DMODEL 512
#define DFF 2048
#define HD 64
#define BB 8
#define TT 512
#define MTOK (BB*TT)   // 4096
#define EROWS 1040     // 2T-1 = 1023, padded
#define CATP 192       // padded concat pitch (K=138 rounded to 64)
#define QKP 1024       // fused q|k row pitch (v split out transposed)

// workspace layout (bytes) — ~68 MB total (harness ws >= 256 MB per fill traces)
#define E_OFF     4096u
#define H_OFF     (512u*1024u)
#define HN_OFF    (H_OFF + 8u*1024u*1024u)
#define QKV_OFF   (HN_OFF + 4u*1024u*1024u)      // 16 MB region: qk(8MB)+VT(4MB) / mid(16MB) / scratch
#define WT_OFF    (QKV_OFF + 16u*1024u*1024u)    // 36 MB: 6 layers of bf16 B^T weights
#define LWT_ELEMS 3145728u                       // per-layer bf16 elems (qkv|wo|f1|f2)

typedef const float* fp32p;
typedef __hip_bfloat16 bf16;
typedef const bf16* bf16p;
typedef __attribute__((ext_vector_type(8))) short bf16x8;  // 8 bf16 (4 VGPRs)
typedef __attribute__((ext_vector_type(4))) short s16x4;   // 4 bf16 (8B store)
typedef __attribute__((ext_vector_type(4))) float f32x4;   // 4 fp32 acc

typedef __attribute__((address_space(1))) const void as1_cvoid;
typedef __attribute__((address_space(3))) void       as3_void;

__device__ __forceinline__ void gload16(const bf16* g, const bf16* l){
    __builtin_amdgcn_global_load_lds((as1_cvoid*)g, (as3_void*)l, 16, 0, 0);
}

__device__ __forceinline__ float b2f(bf16 x){ return __bfloat162float(x); }

// ---------------- concat(x, mask) fp32 -> bf16, zero-padded to pitch CATP ----------------
__global__ __launch_bounds__(256)
void k_concat(fp32p x, fp32p mask, bf16* __restrict__ out){
    int idx = blockIdx.x*256 + threadIdx.x;
    if (idx >= MTOK*CATP) return;
    int row = idx / CATP, c = idx - row*CATP;
    float v = 0.f;
    if (c < DOF) v = x[(size_t)row*DOF + c];
    else if (c < 2*DOF) v = mask[(size_t)row*DOF + (c - DOF)];
    out[idx] = __float2bfloat16(v);
}

// ---------------- cast fp32 -> bf16 ----------------
__global__ __launch_bounds__(256)
void k_cast(const float* __restrict__ in, bf16* __restrict__ out){
    int idx = blockIdx.x*256 + threadIdx.x;
    if (idx >= MTOK*DMODEL) return;
    out[idx] = __float2bfloat16(in[idx]);
}

// ---------------- ALL weight transposes (6 layers + enc + dec) in ONE dispatch ----------
// blocks [0,18432): layer tiles (3072/layer): [0,1024)=qkv+wo, [1024,2048)=fw1,
// [2048,3072)=fw2. blocks [18432,19088): enc1(96) enc2(256) dec1(256) dec2(48), guarded.
__global__ __launch_bounds__(256)
void k_wtall(fp32p wq, fp32p wk, fp32p wv, fp32p wo, fp32p fw1, fp32p fw2,
             fp32p enc_w1, fp32p enc_w2, fp32p dec_w1, fp32p dec_w2,
             bf16* __restrict__ lwt, bf16* __restrict__ ed)
{
    __shared__ float s[32][33];
    const int t = blockIdx.x;
    const int c = threadIdx.x & 31, r0 = threadIdx.x >> 5;

    if (t < 18432) {
        const int l = t / 3072, u = t - l*3072;
        bf16* base = lwt + (size_t)l*LWT_ELEMS;
        fp32p src; bf16* dst; int N, ldk, k0, n0;
        if (u < 1024) {
            int seg = u >> 8, local = u & 255;
            N = 512; ldk = 512;
            k0 = (local & 15) * 32; n0 = (local >> 4) * 32;
            size_t oW = (size_t)l*512*512;
            if      (seg == 0) { src = wq + oW; dst = base; }
            else if (seg == 1) { src = wk + oW; dst = base + 262144; }
            else if (seg == 2) { src = wv + oW; dst = base + 524288; }
            else               { src = wo + oW; dst = base + 786432; }
        } else if (u < 2048) {
            int local = u - 1024;
            N = 2048; ldk = 512;
            k0 = (local & 15) * 32; n0 = (local >> 4) * 32;
            src = fw1 + (size_t)l*512*2048; dst = base + 1048576;
        } else {
            int local = u - 2048;
            N = 512; ldk = 2048;
            k0 = (local >> 4) * 32; n0 = (local & 15) * 32;
            src = fw2 + (size_t)l*2048*512; dst = base + 2097152;
        }
        #pragma unroll
        for (int rr = r0; rr < 32; rr += 8)
            s[rr][c] = src[(size_t)(k0+rr)*N + n0 + c];
        __syncthreads();
        #pragma unroll
        for (int rr = r0; rr < 32; rr += 8)
            dst[(size_t)(n0+rr)*ldk + k0 + c] = __float2bfloat16(s[c][rr]);
        return;
    }

    // guarded tail: enc/dec
    int t2 = t - 18432;
    fp32p src; bf16* dst; int K, N, ldk, k0, n0;
    if (t2 < 96)       { src = enc_w1; dst = ed;          K = 2*DOF; N = 512; ldk = CATP; k0 = (t2 % 6)*32;  n0 = (t2 / 6)*32; }
    else if (t2 < 352) { int lx = t2 - 96;  src = enc_w2; dst = ed + 512*CATP;          K = 512; N = 512; ldk = 512; k0 = (lx & 15)*32; n0 = (lx >> 4)*32; }
    else if (t2 < 608) { int lx = t2 - 352; src = dec_w1; dst = ed + 512*CATP + 262144; K = 512; N = 512; ldk = 512; k0 = (lx & 15)*32; n0 = (lx >> 4)*32; }
    else               { int lx = t2 - 608; src = dec_w2; dst = ed + 512*CATP + 524288; K = 512; N = DOF+4; ldk = 512; k0 = (lx & 15)*32; n0 = (lx >> 4)*32; }
    #pragma unroll
    for (int rr = r0; rr < 32; rr += 8) {
        int k = k0 + rr, n = n0 + c;
        s[rr][c] = (k < K && n < N) ? src[(size_t)k*N + n] : 0.f;
    }
    __syncthreads();
    #pragma unroll
    for (int rr = r0; rr < 32; rr += 8) {
        int n = n0 + rr;
        if (n < N) dst[(size_t)n*ldk + k0 + c] = __float2bfloat16(s[c][rr]);
    }
}

// ---------------- LDS-tiled MFMA GEMM (BK=64, 2-phase pipeline) ----------------
// C = epi(A @ B + bias); A bf16 (M x K) lda; BT bf16 (N x ldk) = B^T.
// Block = 256 threads (4 waves, 2x2 wave grid), tile BM x BN, BK=64.
// BM=64 tiles -> 2-3 blocks/CU so partner-block waves hide the per-slab barrier
// drain (m114 mechanism; 1 blk/CU was the round-7 bottleneck).
// global_load_lds (16B) stages into double-buffered linear LDS; 8-chunk XOR swizzle
// (chunk ^ row&7) applied on GLOBAL source and LDS READ (both-sides involution).
// XCD-aware chunked block swizzle (T1/m204). Requires K%64==0, M%BM==0.
// BIAS: 0=none, 1=bias[], 3=segment-select of {bias,bias2,bias3} by col/512.
// SPLITV: blocks with bn>=1024 write transposed per-head VT[b][h][d][t] (QKV fusion).
template<int BM, int BN, int PRELU, int RESID, int BIAS, int OUTF32, int SPLITV>
__global__ __launch_bounds__(256)
void k_gemm(bf16p A, int lda,
            bf16p BT, int ldk,
            fp32p bias, fp32p bias2, fp32p bias3, size_t biasoff,
            fp32p alpha, size_t aidx,
            const float* __restrict__ resid,
            void* __restrict__ Cout, int ldc,
            bf16* __restrict__ VTout,
            int M, int N, int K)
{
    constexpr int MF = BM/32;   // m-fragments per wave
    constexpr int NF = BN/32;   // n-fragments per wave
    constexpr int AI = BM/32;   // A stage issues per wave (8 rows x 128B each)
    constexpr int BI = BN/32;   // B stage issues per wave

    __shared__ __attribute__((aligned(16))) bf16 sA[2][BM*64];
    __shared__ __attribute__((aligned(16))) bf16 sB[2][BN*64];

    // XCD-aware bijective swizzle (m204)
    int bx, by;
    {
        const int gx  = gridDim.x;
        const int nwg = gx * gridDim.y;
        const int bid = blockIdx.y * gx + blockIdx.x;
        const int qq = nwg >> 3, rr = nwg & 7;
        const int xcd = bid & 7, pos = bid >> 3;
        const int nb = (xcd < rr) ? (xcd*(qq+1) + pos) : (rr*(qq+1) + (xcd-rr)*qq + pos);
        bx = nb % gx; by = nb / gx;
    }

    const int tid  = threadIdx.x;
    const int w    = tid >> 6;
    const int lane = tid & 63;
    const int qd   = lane >> 4;
    const int cl   = lane & 15;
    const int wr   = w >> 1;
    const int wc   = w & 1;
    const int bm   = by * BM;
    const int bn   = bx * BN;

    // staging: lane -> (row = lane>>3 within 8-row group, chunk = lane&7 of 8x16B row)
    const int ssc = (lane & 7) ^ ((lane >> 3) & 7);

    const bf16* aG = A + (size_t)(bm + w*(BM/4) + (lane >> 3))*lda + ssc*8;
    const bf16* bG[BI];
    #pragma unroll
    for (int i = 0; i < BI; ++i) {
        int rrow = min(bn + w*(BN/4) + i*8 + (lane >> 3), N-1);
        bG[i] = BT + (size_t)rrow*ldk + ssc*8;
    }

    f32x4 acc[MF][NF] = {};

    auto stage = [&](int p, int k0){
        #pragma unroll
        for (int i = 0; i < AI; ++i)
            gload16(aG + (size_t)(i*8)*lda + k0, &sA[p][(w*(BM/4) + i*8)*64]);
        #pragma unroll
        for (int i = 0; i < BI; ++i)
            gload16(bG[i] + k0, &sB[p][(w*(BN/4) + i*8)*64]);
    };

    stage(0, 0);
    int p = 0;
    for (int k0 = 0; k0 < K; k0 += 64) {
        __syncthreads();                       // drains vmcnt: buf[p] ready
        if (k0 + 64 < K) stage(p^1, k0 + 64);  // issue next slab under compute
        #pragma unroll
        for (int ks = 0; ks < 2; ++ks) {
            const int rcc = ks*4 + qd;         // chunk of this k-sub-slice
            bf16x8 aF[MF], bF[NF];
            #pragma unroll
            for (int mt = 0; mt < MF; ++mt) {
                int row = wr*(BM/2) + mt*16 + cl;
                aF[mt] = *(const bf16x8*)(&sA[p][row*64 + ((rcc ^ (cl & 7))*8)]);
            }
            #pragma unroll
            for (int nt = 0; nt < NF; ++nt) {
                int row = wc*(BN/2) + nt*16 + cl;
                bF[nt] = *(const bf16x8*)(&sB[p][row*64 + ((rcc ^ (cl & 7))*8)]);
            }
            #pragma unroll
            for (int mt = 0; mt < MF; ++mt)
                #pragma unroll
                for (int nt = 0; nt < NF; ++nt)
                    acc[mt][nt] = __builtin_amdgcn_mfma_f32_16x16x32_bf16(aF[mt], bF[nt], acc[mt][nt], 0, 0, 0);
        }
        p ^= 1;
    }

    if (SPLITV && bn >= 1024) {
        // V segment: write transposed VT[((b*8+h)*64+hd)*512 + t], 8B short4 stores
        #pragma unroll
        for (int nt = 0; nt < NF; ++nt) {
            int col = bn + wc*(BN/2) + nt*16 + cl;
            float bv = bias3[biasoff + (col & 511)];
            int hh = (col >> 6) & 7;
            int hd = col & 63;
            #pragma unroll
            for (int mt = 0; mt < MF; ++mt) {
                int row0 = bm + wr*(BM/2) + mt*16 + qd*4;
                int bb = row0 >> 9, t = row0 & 511;
                s16x4 v4;
                #pragma unroll
                for (int r = 0; r < 4; ++r) {
                    bf16 cb = __float2bfloat16(acc[mt][nt][r] + bv);
                    v4[r] = *reinterpret_cast<short*>(&cb);
                }
                *(s16x4*)(VTout + ((size_t)((bb*8 + hh)*64 + hd))*512 + t) = v4;
            }
        }
        return;
    }

    const float alp = PRELU ? alpha[aidx] : 0.f;
    fp32p bsel = bias;
    if (BIAS == 3) bsel = (bn < 512) ? bias : ((bn < 1024) ? bias2 : bias3);
    #pragma unroll
    for (int nt = 0; nt < NF; ++nt) {
        int col = bn + wc*(BN/2) + nt*16 + cl;
        if (col < N) {
            float bv = 0.f;
            if (BIAS == 1) bv = bsel[biasoff + col];
            if (BIAS == 3) bv = bsel[biasoff + (col & 511)];
            #pragma unroll
            for (int mt = 0; mt < MF; ++mt) {
                #pragma unroll
                for (int r = 0; r < 4; ++r) {
                    int row = bm + wr*(BM/2) + mt*16 + qd*4 + r;
                    float c = acc[mt][nt][r] + bv;
                    if (PRELU) c = (c >= 0.f) ? c : alp*c;
                    if (RESID) c += resid[(size_t)row*ldc + col];
                    if (OUTF32) ((float*)Cout)[(size_t)row*ldc + col] = c;
                    else ((bf16*)Cout)[(size_t)row*ldc + col] = __float2bfloat16(c);
                }
            }
        }
    }
}

// ---------------- LayerNorm: fp32 in -> bf16 out (shuffle reduce, 1 barrier) ----------
__global__ __launch_bounds__(256)
void k_layernorm(const float* __restrict__ x, fp32p g, fp32p b, bf16* __restrict__ out){
    __shared__ float part[8];
    const int row = blockIdx.x, tid = threadIdx.x;
    const int w = tid >> 6, lane = tid & 63;
    const float* xr = x + (size_t)row*DMODEL;
    float x0 = xr[tid], x1 = xr[tid+256];
    float s = x0 + x1, s2 = x0*x0 + x1*x1;
    #pragma unroll
    for (int o = 1; o < 64; o <<= 1) {
        s  += __shfl_xor(s,  o);
        s2 += __shfl_xor(s2, o);
    }
    if (lane == 0) { part[w] = s; part[4+w] = s2; }
    __syncthreads();
    float ts  = part[0] + part[1] + part[2] + part[3];
    float ts2 = part[4] + part[5] + part[6] + part[7];
    float mean = ts * (1.f/DMODEL);
    float var  = ts2 * (1.f/DMODEL) - mean*mean;
    float inv  = rsqrtf(var + 1e-6f);
    out[(size_t)row*DMODEL + tid]     = __float2bfloat16((x0 - mean)*inv*g[tid]     + b[tid]);
    out[(size_t)row*DMODEL + tid+256] = __float2bfloat16((x1 - mean)*inv*g[tid+256] + b[tid+256]);
}

// ---------------- relative embedding E: (EROWS, HD) bf16, zero-padded ----------------
__global__ __launch_bounds__(64)
void k_relemb(fp32p w1, fp32p b1, fp32p a, fp32p w2, fp32p b2, bf16* __restrict__ Ebf){
    __shared__ float sH[DMODEL];
    const int r = blockIdx.x, tid = threadIdx.x;
    if (r >= 2*TT - 1) { Ebf[(size_t)r*HD + tid] = __float2bfloat16(0.f); return; }
    const float dist = (float)(r - (TT-1));
    const float al = a[0];
    for (int d = tid; d < DMODEL; d += 64) {
        float hv = dist * w1[d] + b1[d];
        sH[d] = (hv >= 0.f) ? hv : al*hv;
    }
    __syncthreads();
    float acc = b2[tid];
    for (int d = 0; d < DMODEL; ++d) acc += sH[d] * w2[(size_t)d*HD + tid];
    Ebf[(size_t)r*HD + tid] = __float2bfloat16(acc);
}

// ---------------- MFMA flash attention with relative-position skew ----------------
// 512 threads = 8 waves; each wave owns 16 q-rows, block owns 128 (grid = 256 = 1/CU).
// Per J-tile the BLOCK stages K (8KB), V^T (8KB) and the 208-row E window (26KB) via
// coalesced global_load_lds into double buffers (8-chunk XOR swizzle), one iteration
// ahead. One barrier per J-tile. Row-sum via MFMA-with-ones. XCD-aware bid decode.
__global__ __launch_bounds__(512)
void k_attn(bf16p q, bf16p k, bf16p VT, bf16p Ebf, bf16* __restrict__ o, int qp)
{
    __shared__ __attribute__((aligned(16))) bf16 sK[2][64*64];    // 16 KB
    __shared__ __attribute__((aligned(16))) bf16 sV[2][64*64];    // 16 KB
    __shared__ __attribute__((aligned(16))) bf16 sE[2][208*64];   // 52 KB
    __shared__ float sQE[8][16][100];                             // 50 KB
    __shared__ __attribute__((aligned(16))) bf16 sP[8][16*64];    // 16 KB

    const int bid = blockIdx.x;
    const int it2 = bid >> 6;          // 0..3 in high bits: same-(b,h) group on one XCD
    const int h   = bid & 7;
    const int b   = (bid >> 3) & 7;
    const int tid = threadIdx.x;
    const int w   = tid >> 6;          // 0..7
    const int lane= tid & 63;
    const int qd  = lane >> 4;
    const int cl  = lane & 15;

    const int I = it2*128 + w*16;
    const size_t bh   = ((size_t)b*TT)*qp + (size_t)h*HD;
    const size_t boff = ((size_t)b*TT)*DMODEL + (size_t)h*HD;

    const int srow = tid >> 3, sch = tid & 7;
    const int ssc  = sch ^ (srow & 7);
    const int ldso = srow*64 + sch*8;              // == tid*16 bytes, linear
    const bf16* kg = k  + bh + (size_t)srow*qp + ssc*8;
    const bf16* vg = VT + ((size_t)((b*8 + h)*64 + srow))*512 + ssc*8;
    const int ebase0 = 384 - it2*128;              // E window base = J + ebase0

    auto stage = [&](int p, int J){
        gload16(kg + (size_t)J*qp, &sK[p][ldso]);
        gload16(vg + J,            &sV[p][ldso]);
        const bf16* eg = Ebf + (size_t)(J + ebase0 + srow)*HD + ssc*8;
        gload16(eg,          &sE[p][ldso]);
        gload16(eg + 64*HD,  &sE[p][ldso + 64*64]);
        gload16(eg + 128*HD, &sE[p][ldso + 128*64]);
        if (tid < 128) gload16(eg + 192*HD, &sE[p][ldso + 192*64]);   // rows 192..207
    };

    bf16x8 qa0, qa1, ones;
    {
        const bf16* qrow = q + bh + (size_t)(I + cl)*qp;
        qa0 = *(const bf16x8*)(qrow + qd*8);
        qa1 = *(const bf16x8*)(qrow + 32 + qd*8);
    }
    #pragma unroll
    for (int e = 0; e < 8; ++e) ((short*)&ones)[e] = 0x3F80;   // bf16 1.0

    f32x4 Oacc[4] = {};
    float m_i[4], l_i[4];
    #pragma unroll
    for (int r = 0; r < 4; ++r) { m_i[r] = -1e30f; l_i[r] = 0.f; }
    const float scale = 0.125f;

    const int c0 = (qd ^ (cl & 7))*8;
    const int c1 = ((qd ^ (cl & 7)) ^ 4)*8;
    const int erow0 = 112 - w*16;       // wave's E-window offset within block window

    stage(0, 0);
    int p = 0;

    for (int J = 0; J < TT; J += 64) {
        __syncthreads();                       // buf[p] staged & prev reads done
        if (J + 64 < TT) stage(p^1, J + 64);   // next tile flies under this iteration

        // ---- QK^T from sK ----
        f32x4 S[4];
        #pragma unroll
        for (int js = 0; js < 4; ++js) {
            const bf16* kr = &sK[p][(js*16 + cl)*64];
            bf16x8 kb0 = *(const bf16x8*)(kr + c0);
            bf16x8 kb1 = *(const bf16x8*)(kr + c1);
            f32x4 acc = {};
            acc = __builtin_amdgcn_mfma_f32_16x16x32_bf16(qa0, kb0, acc, 0, 0, 0);
            acc = __builtin_amdgcn_mfma_f32_16x16x32_bf16(qa1, kb1, acc, 0, 0, 0);
            S[js] = acc;
        }

        // ---- QE from sE ----
        #pragma unroll
        for (int nt = 0; nt < 6; ++nt) {
            const bf16* er = &sE[p][(erow0 + nt*16 + cl)*64];
            bf16x8 eb0 = *(const bf16x8*)(er + c0);
            bf16x8 eb1 = *(const bf16x8*)(er + c1);
            f32x4 acc = {};
            acc = __builtin_amdgcn_mfma_f32_16x16x32_bf16(qa0, eb0, acc, 0, 0, 0);
            acc = __builtin_amdgcn_mfma_f32_16x16x32_bf16(qa1, eb1, acc, 0, 0, 0);
            #pragma unroll
            for (int r = 0; r < 4; ++r)
                sQE[w][qd*4 + r][nt*16 + cl] = acc[r];
        }

        // ---- skew add + online softmax ----
        float mnew[4];
        #pragma unroll
        for (int r = 0; r < 4; ++r) mnew[r] = m_i[r];
        #pragma unroll
        for (int js = 0; js < 4; ++js) {
            #pragma unroll
            for (int r = 0; r < 4; ++r) {
                int idx = js*16 + cl - (qd*4 + r) + 15;
                float s = S[js][r] + sQE[w][qd*4 + r][idx];
                S[js][r] = s;
                mnew[r] = fmaxf(mnew[r], s);
            }
        }
        #pragma unroll
        for (int r = 0; r < 4; ++r) {
            float mv = mnew[r];
            mv = fmaxf(mv, __shfl_xor(mv, 1));
            mv = fmaxf(mv, __shfl_xor(mv, 2));
            mv = fmaxf(mv, __shfl_xor(mv, 4));
            mv = fmaxf(mv, __shfl_xor(mv, 8));
            mnew[r] = mv;
        }
        float alpha[4];
        #pragma unroll
        for (int r = 0; r < 4; ++r) {
            alpha[r] = __expf((m_i[r] - mnew[r]) * scale);
            m_i[r] = mnew[r];
        }
        // P -> per-wave LDS [16][64], chunk ^ (row&7) swizzle
        #pragma unroll
        for (int js = 0; js < 4; ++js) {
            #pragma unroll
            for (int r = 0; r < 4; ++r) {
                float pv = __expf((S[js][r] - m_i[r]) * scale);
                int prow = qd*4 + r;
                int pcol = ((js*2 + (cl >> 3)) ^ (prow & 7))*8 + (cl & 7);
                sP[w][prow*64 + pcol] = __float2bfloat16(pv);
            }
        }

        // P fragments: aligned b128 with the same involution
        bf16x8 pa0, pa1;
        {
            const bf16* pb = &sP[w][cl*64];
            pa0 = *(const bf16x8*)(pb + c0);
            pa1 = *(const bf16x8*)(pb + c1);
        }

        // row-sum of P via MFMA against ones
        {
            f32x4 lacc = {};
            lacc = __builtin_amdgcn_mfma_f32_16x16x32_bf16(pa0, ones, lacc, 0, 0, 0);
            lacc = __builtin_amdgcn_mfma_f32_16x16x32_bf16(pa1, ones, lacc, 0, 0, 0);
            #pragma unroll
            for (int r = 0; r < 4; ++r) l_i[r] = l_i[r]*alpha[r] + lacc[r];
        }

        // ---- PV from sV ----
        #pragma unroll
        for (int nt = 0; nt < 4; ++nt) {
            #pragma unroll
            for (int r = 0; r < 4; ++r) Oacc[nt][r] *= alpha[r];
            const bf16* vr = &sV[p][(nt*16 + cl)*64];
            bf16x8 vb0 = *(const bf16x8*)(vr + c0);
            bf16x8 vb1 = *(const bf16x8*)(vr + c1);
            Oacc[nt] = __builtin_amdgcn_mfma_f32_16x16x32_bf16(pa0, vb0, Oacc[nt], 0, 0, 0);
            Oacc[nt] = __builtin_amdgcn_mfma_f32_16x16x32_bf16(pa1, vb1, Oacc[nt], 0, 0, 0);
        }
        p ^= 1;
    }

    #pragma unroll
    for (int nt = 0; nt < 4; ++nt) {
        #pragma unroll
        for (int r = 0; r < 4; ++r) {
            int row = qd*4 + r;
            float val = Oacc[nt][r] / l_i[r];
            o[boff + (size_t)(I + row)*DMODEL + nt*16 + cl] = __float2bfloat16(val);
        }
    }
}

// ---------------- output split + sigmoid (fp32 out) ----------------
__global__ __launch_bounds__(256)
void k_out(const float* __restrict__ y, float* __restrict__ out){
    int idx = blockIdx.x*256 + threadIdx.x;
    if (idx >= MTOK*73) return;
    int row = idx / 73, c = idx - row*73;
    float val = y[idx];
    if (c < DOF) out[(size_t)row*DOF + c] = val;
    else out[(size_t)MTOK*DOF + row*4 + (c-DOF)] = 1.f/(1.f + expf(-val));
}

extern "C" void kernel_launch(void* const* d_in, const int* in_sizes, int n_in,
                              void* d_out, int out_size, void* d_ws, size_t ws_size,
                              hipStream_t stream)
{
    fp32p x      = (fp32p)d_in[0];
    fp32p mask   = (fp32p)d_in[1];
    fp32p enc_w1 = (fp32p)d_in[2];
    fp32p enc_b1 = (fp32p)d_in[3];
    fp32p enc_a1 = (fp32p)d_in[4];
    fp32p enc_w2 = (fp32p)d_in[5];
    fp32p enc_b2 = (fp32p)d_in[6];
    fp32p enc_a2 = (fp32p)d_in[7];
    fp32p rel_w1 = (fp32p)d_in[8];
    fp32p rel_b1 = (fp32p)d_in[9];
    fp32p rel_a  = (fp32p)d_in[10];
    fp32p rel_w2 = (fp32p)d_in[11];
    fp32p rel_b2 = (fp32p)d_in[12];
    fp32p ln_g   = (fp32p)d_in[13];
    fp32p ln_b   = (fp32p)d_in[14];
    fp32p wq     = (fp32p)d_in[15];
    fp32p bq     = (fp32p)d_in[16];
    fp32p wk     = (fp32p)d_in[17];
    fp32p bk     = (fp32p)d_in[18];
    fp32p wv     = (fp32p)d_in[19];
    fp32p bv     = (fp32p)d_in[20];
    fp32p wo     = (fp32p)d_in[21];
    fp32p bo     = (fp32p)d_in[22];
    fp32p fw1    = (fp32p)d_in[23];
    fp32p fb1    = (fp32p)d_in[24];
    fp32p fa     = (fp32p)d_in[25];
    fp32p fw2    = (fp32p)d_in[26];
    fp32p fb2    = (fp32p)d_in[27];
    fp32p dec_w1 = (fp32p)d_in[28];
    fp32p dec_b1 = (fp32p)d_in[29];
    fp32p dec_a  = (fp32p)d_in[30];
    fp32p dec_w2 = (fp32p)d_in[31];
    fp32p dec_b2 = (fp32p)d_in[32];

    char* wsb = (char*)d_ws;
    bf16*  Ebf  = (bf16*)(wsb + E_OFF);
    float* h    = (float*)(wsb + H_OFF);
    bf16*  hn   = (bf16*)(wsb + HN_OFF);
    bf16*  qkb  = (bf16*)(wsb + QKV_OFF);             // 4096 x 1024 bf16 (q|k fused)
    bf16*  VTb  = qkb + (size_t)MTOK*QKP;             // 64bh x 64d x 512t bf16 (4MB)
    bf16*  mid  = qkb;                      // ffn mid 4096 x 2048 bf16 (aliases qk+VT)
    bf16*  cat  = qkb;                      // encoder scratch (pitch CATP)
    bf16*  hb   = qkb;                      // decoder bf16 cast of h
    float* y    = (float*)qkb;              // decoder logits fp32

    // transposed bf16 weights: 6 layers upfront + enc/dec tail region
    bf16* lwt = (bf16*)(wsb + WT_OFF);               // 6 x LWT_ELEMS
    bf16* ed  = lwt + 6*LWT_ELEMS;                   // enc1|enc2|dec1|dec2
    bf16* enc1T = ed;                                // 512 x 192 (zero-padded K)
    bf16* enc2T = ed + 512*CATP;                     // 512 x 512
    bf16* dec1T = enc2T + 262144;                    // 512 x 512
    bf16* dec2T = dec1T + 262144;                    // 73 x 512

    dim3 g512(8, 64);      // N=512: BM=64 BN=64  -> 512 blocks (2/CU)
    dim3 gQKV(12, 64);     // N=1536: BM=64 BN=128 -> 768 blocks (3/CU)
    dim3 gF1(16, 64);      // N=2048: BM=64 BN=128 -> 1024 blocks

    // ALL weight transposes in one dispatch, then encoder
    k_wtall<<<19088, 256, 0, stream>>>(wq, wk, wv, wo, fw1, fw2,
                                       enc_w1, enc_w2, dec_w1, dec_w2, lwt, ed);
    k_concat<<<(MTOK*CATP+255)/256, 256, 0, stream>>>(x, mask, cat);
    k_gemm<64,64,1,0,1,0,0><<<g512,256,0,stream>>>(cat, CATP, enc1T, CATP, enc_b1, nullptr, nullptr, 0, enc_a1, 0, nullptr, hn, DMODEL, nullptr, MTOK, DMODEL, CATP);
    k_gemm<64,64,1,0,1,1,0><<<g512,256,0,stream>>>(hn, DMODEL, enc2T, DMODEL, enc_b2, nullptr, nullptr, 0, enc_a2, 0, nullptr, h, DMODEL, nullptr, MTOK, DMODEL, DMODEL);
    k_relemb<<<EROWS, 64, 0, stream>>>(rel_w1, rel_b1, rel_a, rel_w2, rel_b2, Ebf);

    for (int l = 0; l < NL; ++l) {
        size_t oB  = (size_t)l*DMODEL;
        size_t oBF1= (size_t)l*DFF;
        bf16* Lw = lwt + (size_t)l*LWT_ELEMS;

        k_layernorm<<<MTOK, 256, 0, stream>>>(h, ln_g, ln_b, hn);
        // fused QKV: N=1536; q|k -> qkb (pitch 1024), v -> VTb transposed
        k_gemm<64,128,0,0,3,0,1><<<gQKV,256,0,stream>>>(hn, DMODEL, Lw, DMODEL, bq, bk, bv, oB, nullptr, 0, nullptr, qkb, QKP, VTb, MTOK, 1536, DMODEL);
        k_attn<<<BB*NH*(TT/128), 512, 0, stream>>>(qkb, qkb + 512, VTb, Ebf, hn, QKP);
        k_gemm<64,64,0,1,1,1,0><<<g512,256,0,stream>>>(hn, DMODEL, Lw + 786432, DMODEL, bo, nullptr, nullptr, oB, nullptr, 0, h, h, DMODEL, nullptr, MTOK, DMODEL, DMODEL);
        k_layernorm<<<MTOK, 256, 0, stream>>>(h, ln_g, ln_b, hn);
        // fused FFN: f1 full N=2048 -> mid; f2 full K=2048 -> h (+resid)
        k_gemm<64,128,1,0,1,0,0><<<gF1,256,0,stream>>>(hn, DMODEL, Lw + 1048576, DMODEL, fb1, nullptr, nullptr, oBF1, fa, (size_t)l, nullptr, mid, DFF, nullptr, MTOK, DFF, DMODEL);
        k_gemm<64,64,0,1,1,1,0><<<g512,256,0,stream>>>(mid, DFF, Lw + 2097152, DFF, fb2, nullptr, nullptr, oB, nullptr, 0, h, h, DMODEL, nullptr, MTOK, DMODEL, DFF);
    }

    // decoder
    k_cast<<<(MTOK*DMODEL+255)/256, 256, 0, stream>>>(h, hb);
    k_gemm<64,64,1,0,1,0,0><<<g512,256,0,stream>>>(hb, DMODEL, dec1T, DMODEL, dec_b1, nullptr, nullptr, 0, dec_a, 0, nullptr, hn, DMODEL, nullptr, MTOK, DMODEL, DMODEL);
    {
        dim3 g2(2, 64);   // N=73: BN=64 -> 2 col tiles, BM=64 -> 128 blocks
        k_gemm<64,64,0,0,1,1,0><<<g2,256,0,stream>>>(hn, DMODEL, dec2T, DMODEL, dec_b2, nullptr, nullptr, 0, nullptr, 0, nullptr, y, DOF+4, nullptr, MTOK, DOF+4, DMODEL);
    }
    k_out<<<(MTOK*73+255)/256, 256, 0, stream>>>(y, (float*)d_out);
}